// Round 4
// baseline (1844.082 us; speedup 1.0000x reference)
//
#include <hip/hip_runtime.h>

typedef float f32x4 __attribute__((ext_vector_type(4)));
typedef float f32x2 __attribute__((ext_vector_type(2)));
typedef short short8 __attribute__((ext_vector_type(8)));
typedef uint  uint2v __attribute__((ext_vector_type(2)));

#define NN 4096
#define HB 32               // half batch
#define FD 66
#define ROW_U 1056          // uint words per node row per plane (2112 bf16 values)
#define XSWU 4325376u       // uints per plane level (NN*ROW_U)
#define KP 352              // padded K (330 real)
#define KSTEPS 11

__device__ __forceinline__ ushort f2bf(float f){ uint i = __float_as_uint(f); return (ushort)((i + 0x7fffu + ((i >> 16) & 1u)) >> 16); }
__device__ __forceinline__ float bf2f(ushort u){ return __uint_as_float((uint)u << 16); }
__device__ __forceinline__ float lo_f(uint w){ return __uint_as_float(w << 16); }
__device__ __forceinline__ float hi_f(uint w){ return __uint_as_float(w & 0xffff0000u); }
__device__ __forceinline__ uint pkhi2(float a, float b){ return (uint)f2bf(a) | ((uint)f2bf(b) << 16); }
__device__ __forceinline__ uint pklo2(float a, float b){
    ushort ha = f2bf(a), hb = f2bf(b);
    return (uint)f2bf(a - bf2f(ha)) | ((uint)f2bf(b - bf2f(hb)) << 16);
}
__device__ __forceinline__ float sigm(float x){ return 1.0f / (1.0f + __expf(-x)); }
__device__ __forceinline__ float tanh_fast(float x){
    x = fminf(20.0f, fmaxf(-20.0f, x));
    float t = __expf(-2.0f * x);
    return (1.0f - t) / (1.0f + t);
}

// ---------------- zero scratch (cnt+fill), graph-capture-safe ---------------
__global__ void zero_k(int* __restrict__ p){ p[blockIdx.x * 256 + threadIdx.x] = 0; }

// ------- weight transform: Wt_hi/lo[o][k], k = m*66+f, bf16 hi/lo split -----
__global__ void wtbuild_k(const float* __restrict__ Wru, const float* __restrict__ Wc,
                          ushort* __restrict__ ru_hi, ushort* __restrict__ ru_lo,
                          ushort* __restrict__ c_hi,  ushort* __restrict__ c_lo)
{
    int idx = blockIdx.x * 256 + threadIdx.x;   // 192*352 exact
    float w = 0.0f;
    if (idx < 128 * KP) {
        int o = idx / KP, k = idx - o * KP;
        if (k < 330) { int m = k / FD, f = k - m * FD; w = Wru[(size_t)(f * 5 + m) * 128 + o]; }
        ushort hi = f2bf(w);
        ushort lo = f2bf(w - bf2f(hi));
        ru_hi[(size_t)o * KP + k] = hi;
        ru_lo[(size_t)o * KP + k] = lo;
    } else {
        int j = idx - 128 * KP;
        int o = j / KP, k = j - o * KP;
        if (k < 330) { int m = k / FD, f = k - m * FD; w = Wc[(size_t)(f * 5 + m) * 64 + o]; }
        ushort hi = f2bf(w);
        ushort lo = f2bf(w - bf2f(hi));
        c_hi[(size_t)o * KP + k] = hi;
        c_lo[(size_t)o * KP + k] = lo;
    }
}

// ---------------- CSR build ------------------------------------------------
__global__ void count_k(const int* __restrict__ rows, int* __restrict__ cnt)
{
    int i = blockIdx.x * 256 + threadIdx.x;     // 2*65536 exact
    int s = i >> 16;
    atomicAdd(&cnt[(s << 12) + rows[i]], 1);
}

__global__ __launch_bounds__(1024) void scan_k(const int* __restrict__ cnt, int* __restrict__ rp)
{
    int s = blockIdx.x;
    const int* c = cnt + (s << 12);
    int* r = rp + s * 4097;
    __shared__ int sd[1024];
    int tid = threadIdx.x;
    int i0 = tid * 4;
    int a0 = c[i0], a1 = c[i0 + 1], a2 = c[i0 + 2], a3 = c[i0 + 3];
    sd[tid] = a0 + a1 + a2 + a3;
    __syncthreads();
    for (int off = 1; off < 1024; off <<= 1) {
        int v = (tid >= off) ? sd[tid - off] : 0;
        __syncthreads();
        sd[tid] += v;
        __syncthreads();
    }
    int base = tid ? sd[tid - 1] : 0;
    r[i0] = base; r[i0 + 1] = base + a0; r[i0 + 2] = base + a0 + a1; r[i0 + 3] = base + a0 + a1 + a2;
    if (tid == 1023) r[4096] = sd[1023];
}

__global__ void scatter_k(const int* __restrict__ rows, const int* __restrict__ cols,
                          const float* __restrict__ vals, const int* __restrict__ rp,
                          int* __restrict__ fill, int* __restrict__ sc, float* __restrict__ sv)
{
    int i = blockIdx.x * 256 + threadIdx.x;     // 2*65536 exact
    int s = i >> 16;
    int r = rows[i];
    int pos = rp[s * 4097 + r] + atomicAdd(&fill[(s << 12) + r], 1);
    sc[(s << 16) + pos] = cols[i];
    sv[(s << 16) + pos] = vals[i];
}

// ---------------- x0 build: hi/lo bf16 planes, half batch h -----------------
__global__ void x0build_k(const float* __restrict__ in, const float* __restrict__ hx,
                          uint* __restrict__ xh, uint* __restrict__ xl, int h)
{
    int i = blockIdx.x * 256 + threadIdx.x;     // NN*528 exact (quads)
    int n = i / 528, q = i - n * 528;
    float v[4];
    #pragma unroll
    for (int j = 0; j < 4; ++j) {
        int e = q * 4 + j;
        int bl = e / FD, f = e - bl * FD;
        int b = h * HB + bl;
        v[j] = (f < 2) ? in[(size_t)b * 8192 + n * 2 + f]
                       : hx[(size_t)b * 262144 + (size_t)n * 64 + (f - 2)];
    }
    uint2v hv, lv;
    hv.x = pkhi2(v[0], v[1]); hv.y = pkhi2(v[2], v[3]);
    lv.x = pklo2(v[0], v[1]); lv.y = pklo2(v[2], v[3]);
    __builtin_nontemporal_store(hv, (uint2v*)(xh + (size_t)n * ROW_U + q * 2));
    __builtin_nontemporal_store(lv, (uint2v*)(xl + (size_t)n * ROW_U + q * 2));
}

// ---------------- SpMM, feature-chunked for XCD-L2, hi/lo planes ------------
__global__ __launch_bounds__(256) void spmm_k(
    const uint* __restrict__ sh0, const uint* __restrict__ sl0,
    const uint* __restrict__ sh1, const uint* __restrict__ sl1,
    uint* __restrict__ dh0, uint* __restrict__ dl0,
    uint* __restrict__ dh1, uint* __restrict__ dl1,
    const uint* __restrict__ ph, const uint* __restrict__ pl,
    const int* __restrict__ rp, const int* __restrict__ sc,
    const float* __restrict__ sv, int cheb)
{
    const int s = blockIdx.y;
    const uint* __restrict__ xh = s ? sh1 : sh0;
    const uint* __restrict__ xl = s ? sl1 : sl0;
    uint* __restrict__ dh = s ? dh1 : dh0;
    uint* __restrict__ dl = s ? dl1 : dl0;
    const int chunk = blockIdx.x & 7;
    const int r = ((blockIdx.x >> 3) << 2) + (threadIdx.x >> 6);
    const int lane = threadIdx.x & 63;
    const int p0 = rp[s * 4097 + r], p1 = rp[s * 4097 + r + 1];
    const int* cs = sc + (s << 16);
    const float* vs = sv + (s << 16);
    const int q1 = chunk * 66 + lane;
    const int q2 = chunk * 66 + ((lane < 2) ? (64 + lane) : lane);
    const size_t o1 = (size_t)q1 * 2, o2 = (size_t)q2 * 2;

    float A[8] = {0,0,0,0,0,0,0,0}, B[8] = {0,0,0,0,0,0,0,0};
    int e = p0;
    for (; e + 2 <= p1; e += 2) {
        const int   c0 = cs[e],  c1 = cs[e + 1];
        const float v0 = vs[e],  v1 = vs[e + 1];
        const size_t rb0 = (size_t)c0 * ROW_U, rb1 = (size_t)c1 * ROW_U;
        const uint2v h1a = *(const uint2v*)(xh + rb0 + o1);
        const uint2v l1a = *(const uint2v*)(xl + rb0 + o1);
        const uint2v h2a = *(const uint2v*)(xh + rb0 + o2);
        const uint2v l2a = *(const uint2v*)(xl + rb0 + o2);
        const uint2v h1b = *(const uint2v*)(xh + rb1 + o1);
        const uint2v l1b = *(const uint2v*)(xl + rb1 + o1);
        const uint2v h2b = *(const uint2v*)(xh + rb1 + o2);
        const uint2v l2b = *(const uint2v*)(xl + rb1 + o2);
        A[0] = fmaf(v0, lo_f(h1a.x) + lo_f(l1a.x), A[0]);
        A[1] = fmaf(v0, hi_f(h1a.x) + hi_f(l1a.x), A[1]);
        A[2] = fmaf(v0, lo_f(h1a.y) + lo_f(l1a.y), A[2]);
        A[3] = fmaf(v0, hi_f(h1a.y) + hi_f(l1a.y), A[3]);
        A[4] = fmaf(v0, lo_f(h2a.x) + lo_f(l2a.x), A[4]);
        A[5] = fmaf(v0, hi_f(h2a.x) + hi_f(l2a.x), A[5]);
        A[6] = fmaf(v0, lo_f(h2a.y) + lo_f(l2a.y), A[6]);
        A[7] = fmaf(v0, hi_f(h2a.y) + hi_f(l2a.y), A[7]);
        B[0] = fmaf(v1, lo_f(h1b.x) + lo_f(l1b.x), B[0]);
        B[1] = fmaf(v1, hi_f(h1b.x) + hi_f(l1b.x), B[1]);
        B[2] = fmaf(v1, lo_f(h1b.y) + lo_f(l1b.y), B[2]);
        B[3] = fmaf(v1, hi_f(h1b.y) + hi_f(l1b.y), B[3]);
        B[4] = fmaf(v1, lo_f(h2b.x) + lo_f(l2b.x), B[4]);
        B[5] = fmaf(v1, hi_f(h2b.x) + hi_f(l2b.x), B[5]);
        B[6] = fmaf(v1, lo_f(h2b.y) + lo_f(l2b.y), B[6]);
        B[7] = fmaf(v1, hi_f(h2b.y) + hi_f(l2b.y), B[7]);
    }
    if (e < p1) {
        const int   c0 = cs[e];
        const float v0 = vs[e];
        const size_t rb0 = (size_t)c0 * ROW_U;
        const uint2v h1a = *(const uint2v*)(xh + rb0 + o1);
        const uint2v l1a = *(const uint2v*)(xl + rb0 + o1);
        const uint2v h2a = *(const uint2v*)(xh + rb0 + o2);
        const uint2v l2a = *(const uint2v*)(xl + rb0 + o2);
        A[0] = fmaf(v0, lo_f(h1a.x) + lo_f(l1a.x), A[0]);
        A[1] = fmaf(v0, hi_f(h1a.x) + hi_f(l1a.x), A[1]);
        A[2] = fmaf(v0, lo_f(h1a.y) + lo_f(l1a.y), A[2]);
        A[3] = fmaf(v0, hi_f(h1a.y) + hi_f(l1a.y), A[3]);
        A[4] = fmaf(v0, lo_f(h2a.x) + lo_f(l2a.x), A[4]);
        A[5] = fmaf(v0, hi_f(h2a.x) + hi_f(l2a.x), A[5]);
        A[6] = fmaf(v0, lo_f(h2a.y) + lo_f(l2a.y), A[6]);
        A[7] = fmaf(v0, hi_f(h2a.y) + hi_f(l2a.y), A[7]);
    }
    float R[8];
    #pragma unroll
    for (int j = 0; j < 8; ++j) R[j] = A[j] + B[j];

    const size_t rbase = (size_t)r * ROW_U;
    if (cheb) {
        const uint2v pvh = __builtin_nontemporal_load((const uint2v*)(ph + rbase + o1));
        const uint2v pvl = __builtin_nontemporal_load((const uint2v*)(pl + rbase + o1));
        R[0] = 2.0f * R[0] - (lo_f(pvh.x) + lo_f(pvl.x));
        R[1] = 2.0f * R[1] - (hi_f(pvh.x) + hi_f(pvl.x));
        R[2] = 2.0f * R[2] - (lo_f(pvh.y) + lo_f(pvl.y));
        R[3] = 2.0f * R[3] - (hi_f(pvh.y) + hi_f(pvl.y));
        if (lane < 2) {
            const uint2v qvh = __builtin_nontemporal_load((const uint2v*)(ph + rbase + o2));
            const uint2v qvl = __builtin_nontemporal_load((const uint2v*)(pl + rbase + o2));
            R[4] = 2.0f * R[4] - (lo_f(qvh.x) + lo_f(qvl.x));
            R[5] = 2.0f * R[5] - (hi_f(qvh.x) + hi_f(qvl.x));
            R[6] = 2.0f * R[6] - (lo_f(qvh.y) + lo_f(qvl.y));
            R[7] = 2.0f * R[7] - (hi_f(qvh.y) + hi_f(qvl.y));
        }
    }
    uint2v oh, ol;
    oh.x = pkhi2(R[0], R[1]); oh.y = pkhi2(R[2], R[3]);
    ol.x = pklo2(R[0], R[1]); ol.y = pklo2(R[2], R[3]);
    __builtin_nontemporal_store(oh, (uint2v*)(dh + rbase + o1));
    __builtin_nontemporal_store(ol, (uint2v*)(dl + rbase + o1));
    if (lane < 2) {
        uint2v oh2, ol2;
        oh2.x = pkhi2(R[4], R[5]); oh2.y = pkhi2(R[6], R[7]);
        ol2.x = pklo2(R[4], R[5]); ol2.y = pklo2(R[6], R[7]);
        __builtin_nontemporal_store(oh2, (uint2v*)(dh + rbase + o2));
        __builtin_nontemporal_store(ol2, (uint2v*)(dl + rbase + o2));
    }
}

// ------ mm staging: pure copy of hi/lo planes into LDS ----------------------
__device__ __forceinline__ void stage2(const uint* __restrict__ xh, const uint* __restrict__ xl,
                                       int n, int tid, uint* __restrict__ Bhi, uint* __restrict__ Blo)
{
    for (int i = tid; i < 480; i += 256) {      // zero K-pad words 165..179 per b-row
        int bl = i / 15, t = i - bl * 15;
        Bhi[bl * 180 + 165 + t] = 0u;
        Blo[bl * 180 + 165 + t] = 0u;
    }
    for (int i = tid; i < 2640; i += 256) {     // 5 planes x 528 uint2
        int m = i / 528, p = i - m * 528;
        int w0 = p * 2;
        const size_t g = (size_t)m * XSWU + (size_t)n * ROW_U + w0;
        uint2v hv = __builtin_nontemporal_load((const uint2v*)(xh + g));
        uint2v lv = __builtin_nontemporal_load((const uint2v*)(xl + g));
        int bl0 = w0 / 33, f0 = w0 - bl0 * 33;
        int w1 = w0 + 1;
        int bl1 = w1 / 33, f1 = w1 - bl1 * 33;
        Bhi[bl0 * 180 + m * 33 + f0] = hv.x;
        Bhi[bl1 * 180 + m * 33 + f1] = hv.y;
        Blo[bl0 * 180 + m * 33 + f0] = lv.x;
        Blo[bl1 * 180 + m * 33 + f1] = lv.y;
    }
}

#define MFMA(a, b, c) __builtin_amdgcn_mfma_f32_16x16x32_bf16(a, b, c, 0, 0, 0)

// ---------------- gconv1 matmul + sigmoid; u->out, r*hx->xs0 planes ---------
__global__ __launch_bounds__(256, 3) void mm_ru_k(const uint* __restrict__ xh, const uint* __restrict__ xl,
                                                  const ushort* __restrict__ whi, const ushort* __restrict__ wlo,
                                                  const float* __restrict__ bru, const float* __restrict__ hx,
                                                  float* __restrict__ uout,
                                                  uint* __restrict__ xh0, uint* __restrict__ xl0, int h)
{
    const int n = blockIdx.x;
    const int tid = threadIdx.x;
    const int lane = tid & 63, wave = tid >> 6;
    __shared__ uint Bhi[32 * 180];
    __shared__ uint Blo[32 * 180];

    stage2(xh, xl, n, tid, Bhi, Blo);
    __syncthreads();

    const int ob = wave * 32 + (lane & 15);
    const int ksub = (lane >> 4) * 8;
    const int brow = lane & 15;
    const ushort* BH = (const ushort*)Bhi;
    const ushort* BL = (const ushort*)Blo;
    f32x4 acc[2][2] = {};

    #pragma unroll 2
    for (int ks = 0; ks < KSTEPS; ++ks) {
        const int ko = ks * 32 + ksub;
        short8 Ah0 = *(const short8*)(whi + (size_t)ob * KP + ko);
        short8 Ah1 = *(const short8*)(whi + (size_t)(ob + 16) * KP + ko);
        short8 Al0 = *(const short8*)(wlo + (size_t)ob * KP + ko);
        short8 Al1 = *(const short8*)(wlo + (size_t)(ob + 16) * KP + ko);
        short8 Bh0 = *(const short8*)(BH + brow * 360 + ko);
        short8 Bh1 = *(const short8*)(BH + (16 + brow) * 360 + ko);
        short8 Bl0 = *(const short8*)(BL + brow * 360 + ko);
        short8 Bl1 = *(const short8*)(BL + (16 + brow) * 360 + ko);
        acc[0][0] = MFMA(Ah0, Bh0, acc[0][0]);
        acc[0][1] = MFMA(Ah0, Bh1, acc[0][1]);
        acc[1][0] = MFMA(Ah1, Bh0, acc[1][0]);
        acc[1][1] = MFMA(Ah1, Bh1, acc[1][1]);
        acc[0][0] = MFMA(Ah0, Bl0, acc[0][0]);
        acc[0][1] = MFMA(Ah0, Bl1, acc[0][1]);
        acc[1][0] = MFMA(Ah1, Bl0, acc[1][0]);
        acc[1][1] = MFMA(Ah1, Bl1, acc[1][1]);
        acc[0][0] = MFMA(Al0, Bh0, acc[0][0]);
        acc[0][1] = MFMA(Al0, Bh1, acc[0][1]);
        acc[1][0] = MFMA(Al1, Bh0, acc[1][0]);
        acc[1][1] = MFMA(Al1, Bh1, acc[1][1]);
    }

    const int g = lane >> 4, bcol = lane & 15;
    #pragma unroll
    for (int t = 0; t < 2; ++t) {
        const int o = wave * 32 + t * 16 + g * 4;
        const float bb0 = bru[o], bb1 = bru[o + 1], bb2 = bru[o + 2], bb3 = bru[o + 3];
        #pragma unroll
        for (int bt = 0; bt < 2; ++bt) {
            const int bl = bt * 16 + bcol;
            float s0 = sigm(acc[t][bt][0] + bb0);
            float s1 = sigm(acc[t][bt][1] + bb1);
            float s2 = sigm(acc[t][bt][2] + bb2);
            float s3 = sigm(acc[t][bt][3] + bb3);
            if (o < 64) {   // r-part: r*hx -> xs0 hi/lo planes
                const f32x4 hxv = *(const f32x4*)(hx + (size_t)(h * HB + bl) * 262144 + (size_t)n * 64 + o);
                float r0 = s0 * hxv[0], r1 = s1 * hxv[1];
                float r2 = s2 * hxv[2], r3 = s3 * hxv[3];
                const size_t wi = (size_t)n * ROW_U + bl * 33 + 1 + (o >> 1);
                xh0[wi]     = pkhi2(r0, r1);
                xh0[wi + 1] = pkhi2(r2, r3);
                xl0[wi]     = pklo2(r0, r1);
                xl0[wi + 1] = pklo2(r2, r3);
            } else {        // u-part -> d_out (temporary storage)
                f32x4 uv = {s0, s1, s2, s3};
                *(f32x4*)(uout + (size_t)(h * HB + bl) * 262144 + (size_t)n * 64 + (o - 64)) = uv;
            }
        }
    }
}

// ---------------- gconv2 matmul + tanh + final GRU combine ------------------
__global__ __launch_bounds__(256, 3) void mm_c_k(const uint* __restrict__ xh, const uint* __restrict__ xl,
                                                 const ushort* __restrict__ whi, const ushort* __restrict__ wlo,
                                                 const float* __restrict__ bc, const float* __restrict__ hx,
                                                 float* __restrict__ out, int h)
{
    const int n = blockIdx.x;
    const int tid = threadIdx.x;
    const int lane = tid & 63, wave = tid >> 6;
    __shared__ uint Bhi[32 * 180];
    __shared__ uint Blo[32 * 180];

    stage2(xh, xl, n, tid, Bhi, Blo);
    __syncthreads();

    const int ob = wave * 16 + (lane & 15);
    const int ksub = (lane >> 4) * 8;
    const int brow = lane & 15;
    const ushort* BH = (const ushort*)Bhi;
    const ushort* BL = (const ushort*)Blo;
    f32x4 acc[2] = {};

    #pragma unroll 2
    for (int ks = 0; ks < KSTEPS; ++ks) {
        const int ko = ks * 32 + ksub;
        short8 Ah = *(const short8*)(whi + (size_t)ob * KP + ko);
        short8 Al = *(const short8*)(wlo + (size_t)ob * KP + ko);
        short8 Bh0 = *(const short8*)(BH + brow * 360 + ko);
        short8 Bh1 = *(const short8*)(BH + (16 + brow) * 360 + ko);
        short8 Bl0 = *(const short8*)(BL + brow * 360 + ko);
        short8 Bl1 = *(const short8*)(BL + (16 + brow) * 360 + ko);
        acc[0] = MFMA(Ah, Bh0, acc[0]);
        acc[1] = MFMA(Ah, Bh1, acc[1]);
        acc[0] = MFMA(Ah, Bl0, acc[0]);
        acc[1] = MFMA(Ah, Bl1, acc[1]);
        acc[0] = MFMA(Al, Bh0, acc[0]);
        acc[1] = MFMA(Al, Bh1, acc[1]);
    }

    const int g = lane >> 4, bcol = lane & 15;
    const int o = wave * 16 + g * 4;
    const float bb0 = bc[o], bb1 = bc[o + 1], bb2 = bc[o + 2], bb3 = bc[o + 3];
    #pragma unroll
    for (int bt = 0; bt < 2; ++bt) {
        const int bl = bt * 16 + bcol;
        float c0 = tanh_fast(acc[bt][0] + bb0);
        float c1 = tanh_fast(acc[bt][1] + bb1);
        float c2 = tanh_fast(acc[bt][2] + bb2);
        float c3 = tanh_fast(acc[bt][3] + bb3);
        float* p = out + (size_t)(h * HB + bl) * 262144 + (size_t)n * 64 + o;
        const f32x4 hxv = *(const f32x4*)(hx + (size_t)(h * HB + bl) * 262144 + (size_t)n * 64 + o);
        f32x4 uv = *(const f32x4*)p;
        f32x4 ov;
        ov[0] = uv[0] * hxv[0] + (1.0f - uv[0]) * c0;
        ov[1] = uv[1] * hxv[1] + (1.0f - uv[1]) * c1;
        ov[2] = uv[2] * hxv[2] + (1.0f - uv[2]) * c2;
        ov[3] = uv[3] * hxv[3] + (1.0f - uv[3]) * c3;
        *(f32x4*)p = ov;
    }
}

// ---------------------------------------------------------------------------
extern "C" void kernel_launch(void* const* d_in, const int* in_sizes, int n_in,
                              void* d_out, int out_size, void* d_ws, size_t ws_size,
                              hipStream_t stream)
{
    (void)in_sizes; (void)n_in; (void)out_size; (void)ws_size;
    const float* inputs  = (const float*)d_in[0];
    const float* hx      = (const float*)d_in[1];
    const int*   sup_rows= (const int*)d_in[2];
    const int*   sup_cols= (const int*)d_in[3];
    const float* sup_vals= (const float*)d_in[4];
    const float* W_ru    = (const float*)d_in[5];
    const float* b_ru    = (const float*)d_in[6];
    const float* W_c     = (const float*)d_in[7];
    const float* b_c     = (const float*)d_in[8];
    float* out = (float*)d_out;

    char* ws = (char*)d_ws;
    uint* xh = (uint*)ws;                                   // 5 levels hi plane: 86.5 MB
    uint* xl = xh + 5ull * XSWU;                            // 5 levels lo plane: 86.5 MB
    size_t off = 2ull * 5ull * XSWU * 4ull;                 // 173,015,040
    ushort* wru_hi = (ushort*)(ws + off); off += 90112;
    ushort* wru_lo = (ushort*)(ws + off); off += 90112;
    ushort* wc_hi  = (ushort*)(ws + off); off += 45056;
    ushort* wc_lo  = (ushort*)(ws + off); off += 45056;
    int* row_ptr   = (int*)(ws + off);    off += 32800;
    int* cntfill   = (int*)(ws + off);    off += 65536;
    int* scols     = (int*)(ws + off);    off += 524288;
    float* svals   = (float*)(ws + off);  off += 524288;

    #define XH(m) (xh + (size_t)(m) * XSWU)
    #define XL(m) (xl + (size_t)(m) * XSWU)
    int* fill = cntfill + 8192;

    zero_k<<<64, 256, 0, stream>>>(cntfill);
    wtbuild_k<<<264, 256, 0, stream>>>(W_ru, W_c, wru_hi, wru_lo, wc_hi, wc_lo);
    count_k<<<512, 256, 0, stream>>>(sup_rows, cntfill);
    scan_k<<<2, 1024, 0, stream>>>(cntfill, row_ptr);
    scatter_k<<<512, 256, 0, stream>>>(sup_rows, sup_cols, sup_vals, row_ptr, fill, scols, svals);

    for (int h = 0; h < 2; ++h) {
        x0build_k<<<8448, 256, 0, stream>>>(inputs, hx, XH(0), XL(0), h);
        // gconv1 diffusion: step1 both supports from x0; step2 both supports
        spmm_k<<<dim3(8192, 2), 256, 0, stream>>>(XH(0), XL(0), XH(0), XL(0),
                                                  XH(1), XL(1), XH(3), XL(3),
                                                  XH(0), XL(0), row_ptr, scols, svals, 0);
        spmm_k<<<dim3(8192, 2), 256, 0, stream>>>(XH(1), XL(1), XH(3), XL(3),
                                                  XH(2), XL(2), XH(4), XL(4),
                                                  XH(0), XL(0), row_ptr, scols, svals, 1);
        // gconv1 matmul: u -> out, r*hx -> x0 planes
        mm_ru_k<<<NN, 256, 0, stream>>>(xh, xl, wru_hi, wru_lo, b_ru, hx, out, XH(0), XL(0), h);
        // gconv2 diffusion (x0 now holds [inputs, r*hx])
        spmm_k<<<dim3(8192, 2), 256, 0, stream>>>(XH(0), XL(0), XH(0), XL(0),
                                                  XH(1), XL(1), XH(3), XL(3),
                                                  XH(0), XL(0), row_ptr, scols, svals, 0);
        spmm_k<<<dim3(8192, 2), 256, 0, stream>>>(XH(1), XL(1), XH(3), XL(3),
                                                  XH(2), XL(2), XH(4), XL(4),
                                                  XH(0), XL(0), row_ptr, scols, svals, 1);
        // gconv2 matmul + tanh + final GRU combine
        mm_c_k<<<NN, 256, 0, stream>>>(xh, xl, wc_hi, wc_lo, b_c, hx, out, h);
    }
    #undef XH
    #undef XL
}

// Round 5
// 1616.682 us; speedup vs baseline: 1.1407x; 1.1407x over previous
//
#include <hip/hip_runtime.h>

typedef float f32x4 __attribute__((ext_vector_type(4)));
typedef float f32x2 __attribute__((ext_vector_type(2)));
typedef short short8 __attribute__((ext_vector_type(8)));

#define NN 4096
#define HB 32               // half batch
#define FD 66
#define ROW_E 2112          // HB*FD f32 per node row (half batch)
#define XSW 8650752ull      // f32 words per xs buffer (NN*ROW_E)
#define KP 352              // padded K (330 real)
#define KSTEPS 11

__device__ __forceinline__ ushort f2bf(float f){ uint i = __float_as_uint(f); return (ushort)((i + 0x7fffu + ((i >> 16) & 1u)) >> 16); }
__device__ __forceinline__ float bf2f(ushort u){ return __uint_as_float((uint)u << 16); }
__device__ __forceinline__ uint pkhi2(float a, float b){ return (uint)f2bf(a) | ((uint)f2bf(b) << 16); }
__device__ __forceinline__ uint pklo2(float a, float b){
    ushort ha = f2bf(a), hb = f2bf(b);
    return (uint)f2bf(a - bf2f(ha)) | ((uint)f2bf(b - bf2f(hb)) << 16);
}
__device__ __forceinline__ float sigm(float x){ return 1.0f / (1.0f + __expf(-x)); }
__device__ __forceinline__ float tanh_fast(float x){
    x = fminf(20.0f, fmaxf(-20.0f, x));
    float t = __expf(-2.0f * x);
    return (1.0f - t) / (1.0f + t);
}

// ---------------- zero scratch (cnt+fill), graph-capture-safe ---------------
__global__ void zero_k(int* __restrict__ p){ p[blockIdx.x * 256 + threadIdx.x] = 0; }

// ------- weight transform: Wt_hi/lo[o][k], k = m*66+f, bf16 hi/lo split -----
__global__ void wtbuild_k(const float* __restrict__ Wru, const float* __restrict__ Wc,
                          ushort* __restrict__ ru_hi, ushort* __restrict__ ru_lo,
                          ushort* __restrict__ c_hi,  ushort* __restrict__ c_lo)
{
    int idx = blockIdx.x * 256 + threadIdx.x;   // 192*352 exact
    float w = 0.0f;
    if (idx < 128 * KP) {
        int o = idx / KP, k = idx - o * KP;
        if (k < 330) { int m = k / FD, f = k - m * FD; w = Wru[(size_t)(f * 5 + m) * 128 + o]; }
        ushort hi = f2bf(w);
        ushort lo = f2bf(w - bf2f(hi));
        ru_hi[(size_t)o * KP + k] = hi;
        ru_lo[(size_t)o * KP + k] = lo;
    } else {
        int j = idx - 128 * KP;
        int o = j / KP, k = j - o * KP;
        if (k < 330) { int m = k / FD, f = k - m * FD; w = Wc[(size_t)(f * 5 + m) * 64 + o]; }
        ushort hi = f2bf(w);
        ushort lo = f2bf(w - bf2f(hi));
        c_hi[(size_t)o * KP + k] = hi;
        c_lo[(size_t)o * KP + k] = lo;
    }
}

// ---------------- CSR build ------------------------------------------------
__global__ void count_k(const int* __restrict__ rows, int* __restrict__ cnt)
{
    int i = blockIdx.x * 256 + threadIdx.x;     // 2*65536 exact
    int s = i >> 16;
    atomicAdd(&cnt[(s << 12) + rows[i]], 1);
}

__global__ __launch_bounds__(1024) void scan_k(const int* __restrict__ cnt, int* __restrict__ rp)
{
    int s = blockIdx.x;
    const int* c = cnt + (s << 12);
    int* r = rp + s * 4097;
    __shared__ int sd[1024];
    int tid = threadIdx.x;
    int i0 = tid * 4;
    int a0 = c[i0], a1 = c[i0 + 1], a2 = c[i0 + 2], a3 = c[i0 + 3];
    sd[tid] = a0 + a1 + a2 + a3;
    __syncthreads();
    for (int off = 1; off < 1024; off <<= 1) {
        int v = (tid >= off) ? sd[tid - off] : 0;
        __syncthreads();
        sd[tid] += v;
        __syncthreads();
    }
    int base = tid ? sd[tid - 1] : 0;
    r[i0] = base; r[i0 + 1] = base + a0; r[i0 + 2] = base + a0 + a1; r[i0 + 3] = base + a0 + a1 + a2;
    if (tid == 1023) r[4096] = sd[1023];
}

__global__ void scatter_k(const int* __restrict__ rows, const int* __restrict__ cols,
                          const float* __restrict__ vals, const int* __restrict__ rp,
                          int* __restrict__ fill, int* __restrict__ sc, float* __restrict__ sv)
{
    int i = blockIdx.x * 256 + threadIdx.x;     // 2*65536 exact
    int s = i >> 16;
    int r = rows[i];
    int pos = rp[s * 4097 + r] + atomicAdd(&fill[(s << 12) + r], 1);
    sc[(s << 16) + pos] = cols[i];
    sv[(s << 16) + pos] = vals[i];
}

// ---------------- x0 build (f32): x0[n][bl*66+f], half batch h --------------
__global__ void x0build_k(const float* __restrict__ in, const float* __restrict__ hx,
                          float* __restrict__ x0, int h)
{
    int i = blockIdx.x * 256 + threadIdx.x;     // NN*1056 exact (pairs)
    int e0 = i * 2;
    int n = e0 / ROW_E;
    int rem = e0 - n * ROW_E;
    int bl = rem / FD;
    int f = rem - bl * FD;                      // even
    int b = h * HB + bl;
    float v0 = (f < 2) ? in[(size_t)b * 8192 + n * 2 + f]
                       : hx[(size_t)b * 262144 + (size_t)n * 64 + (f - 2)];
    int f1 = f + 1;
    float v1 = (f1 < 2) ? in[(size_t)b * 8192 + n * 2 + f1]
                        : hx[(size_t)b * 262144 + (size_t)n * 64 + (f1 - 2)];
    f32x2 ov; ov.x = v0; ov.y = v1;
    __builtin_nontemporal_store(ov, (f32x2*)(x0 + e0));
}

// ---------------- SpMM, feature-chunked for XCD-L2 residency ----------------
// chunk = blockIdx.x & 7 -> XCD pin (round-robin dispatch). Each XCD touches
// only cols [chunk*66*4 ...) of the source: slice = 4096*1056B = 4.33 MB ~ L2.
// Main loop: 1x16B load/edge/lane (quads 0..63 of chunk). Leftover quads 64,65
// handled by an exec-masked epilogue loop on lanes 0-1 (halves L2 requests vs
// the old dup-load scheme).
__global__ __launch_bounds__(256) void spmm_k(const float* __restrict__ src0, const float* __restrict__ src1,
                                              float* __restrict__ dst0, float* __restrict__ dst1,
                                              const float* __restrict__ prev,
                                              const int* __restrict__ rp, const int* __restrict__ sc,
                                              const float* __restrict__ sv, int cheb, int supbase)
{
    const int s = supbase + blockIdx.y;
    const float* __restrict__ x = s ? src1 : src0;
    float* __restrict__ dst = s ? dst1 : dst0;
    const int chunk = blockIdx.x & 7;
    const int r = ((blockIdx.x >> 3) << 2) + (threadIdx.x >> 6);
    const int lane = threadIdx.x & 63;
    const int p0 = rp[s * 4097 + r], p1 = rp[s * 4097 + r + 1];
    const int* cs = sc + (s << 16);
    const float* vs = sv + (s << 16);
    const int q1 = chunk * 66 + lane;
    const size_t o1 = (size_t)q1 << 2;

    f32x4 A1 = {0,0,0,0}, B1 = {0,0,0,0};
    int e = p0;
    for (; e + 2 <= p1; e += 2) {
        const int   c0 = cs[e],  c1 = cs[e + 1];
        const float v0 = vs[e],  v1 = vs[e + 1];
        const f32x4 xa = *(const f32x4*)(x + (size_t)c0 * ROW_E + o1);
        const f32x4 xb = *(const f32x4*)(x + (size_t)c1 * ROW_E + o1);
        A1.x = fmaf(v0, xa.x, A1.x); A1.y = fmaf(v0, xa.y, A1.y);
        A1.z = fmaf(v0, xa.z, A1.z); A1.w = fmaf(v0, xa.w, A1.w);
        B1.x = fmaf(v1, xb.x, B1.x); B1.y = fmaf(v1, xb.y, B1.y);
        B1.z = fmaf(v1, xb.z, B1.z); B1.w = fmaf(v1, xb.w, B1.w);
    }
    if (e < p1) {
        const int   c0 = cs[e];
        const float v0 = vs[e];
        const f32x4 xa = *(const f32x4*)(x + (size_t)c0 * ROW_E + o1);
        A1.x = fmaf(v0, xa.x, A1.x); A1.y = fmaf(v0, xa.y, A1.y);
        A1.z = fmaf(v0, xa.z, A1.z); A1.w = fmaf(v0, xa.w, A1.w);
    }
    f32x4 R1;
    R1.x = A1.x + B1.x; R1.y = A1.y + B1.y; R1.z = A1.z + B1.z; R1.w = A1.w + B1.w;

    // leftover quads: lanes 0,1 cover quads chunk*66+64, chunk*66+65
    const size_t o2 = (size_t)(chunk * 66 + 64 + lane) << 2;
    f32x4 R2 = {0,0,0,0};
    if (lane < 2) {
        f32x4 A2 = {0,0,0,0}, B2 = {0,0,0,0};
        int e2 = p0;
        for (; e2 + 2 <= p1; e2 += 2) {
            const int   c0 = cs[e2],  c1 = cs[e2 + 1];
            const float v0 = vs[e2],  v1 = vs[e2 + 1];
            const f32x4 ya = *(const f32x4*)(x + (size_t)c0 * ROW_E + o2);
            const f32x4 yb = *(const f32x4*)(x + (size_t)c1 * ROW_E + o2);
            A2.x = fmaf(v0, ya.x, A2.x); A2.y = fmaf(v0, ya.y, A2.y);
            A2.z = fmaf(v0, ya.z, A2.z); A2.w = fmaf(v0, ya.w, A2.w);
            B2.x = fmaf(v1, yb.x, B2.x); B2.y = fmaf(v1, yb.y, B2.y);
            B2.z = fmaf(v1, yb.z, B2.z); B2.w = fmaf(v1, yb.w, B2.w);
        }
        if (e2 < p1) {
            const int   c0 = cs[e2];
            const float v0 = vs[e2];
            const f32x4 ya = *(const f32x4*)(x + (size_t)c0 * ROW_E + o2);
            A2.x = fmaf(v0, ya.x, A2.x); A2.y = fmaf(v0, ya.y, A2.y);
            A2.z = fmaf(v0, ya.z, A2.z); A2.w = fmaf(v0, ya.w, A2.w);
        }
        R2.x = A2.x + B2.x; R2.y = A2.y + B2.y; R2.z = A2.z + B2.z; R2.w = A2.w + B2.w;
    }

    const size_t rbase = (size_t)r * ROW_E;
    if (cheb) {
        const f32x4 p1v = __builtin_nontemporal_load((const f32x4*)(prev + rbase + o1));
        R1.x = 2.0f * R1.x - p1v.x; R1.y = 2.0f * R1.y - p1v.y;
        R1.z = 2.0f * R1.z - p1v.z; R1.w = 2.0f * R1.w - p1v.w;
        if (lane < 2) {
            const f32x4 p2v = __builtin_nontemporal_load((const f32x4*)(prev + rbase + o2));
            R2.x = 2.0f * R2.x - p2v.x; R2.y = 2.0f * R2.y - p2v.y;
            R2.z = 2.0f * R2.z - p2v.z; R2.w = 2.0f * R2.w - p2v.w;
        }
    }
    __builtin_nontemporal_store(R1, (f32x4*)(dst + rbase + o1));
    if (lane < 2)
        __builtin_nontemporal_store(R2, (f32x4*)(dst + rbase + o2));
}

// ------ mm staging: f32 rows -> hi/lo bf16 packed LDS (f32x4 loads) ---------
__device__ __forceinline__ void stage_hilo(const float* __restrict__ xs, int n, int tid,
                                           uint* __restrict__ Bhi, uint* __restrict__ Blo)
{
    for (int i = tid; i < 480; i += 256) {      // zero K-pad words 165..179 per b-row
        int bl = i / 15, t = i - bl * 15;
        Bhi[bl * 180 + 165 + t] = 0u;
        Blo[bl * 180 + 165 + t] = 0u;
    }
    for (int i = tid; i < 2640; i += 256) {     // 5 levels x 528 f32x4
        int m = i / 528, p = i - m * 528;
        const f32x4 v = __builtin_nontemporal_load(
            (const f32x4*)(xs + (size_t)m * XSW + (size_t)n * ROW_E + p * 4));
        int w0 = p * 2;
        int bl0 = w0 / 33, f0 = w0 - bl0 * 33;
        int w1 = w0 + 1;
        int bl1 = w1 / 33, f1 = w1 - bl1 * 33;
        Bhi[bl0 * 180 + m * 33 + f0] = pkhi2(v.x, v.y);
        Blo[bl0 * 180 + m * 33 + f0] = pklo2(v.x, v.y);
        Bhi[bl1 * 180 + m * 33 + f1] = pkhi2(v.z, v.w);
        Blo[bl1 * 180 + m * 33 + f1] = pklo2(v.z, v.w);
    }
}

#define MFMA(a, b, c) __builtin_amdgcn_mfma_f32_16x16x32_bf16(a, b, c, 0, 0, 0)

// ---------------- gconv1 matmul + sigmoid; u->out, r*hx->xs0 ----------------
__global__ __launch_bounds__(256, 3) void mm_ru_k(const float* __restrict__ xs,
                                                  const ushort* __restrict__ whi, const ushort* __restrict__ wlo,
                                                  const float* __restrict__ bru, const float* __restrict__ hx,
                                                  float* __restrict__ uout, float* __restrict__ xs0w, int h)
{
    const int n = blockIdx.x;
    const int tid = threadIdx.x;
    const int lane = tid & 63, wave = tid >> 6;
    __shared__ uint Bhi[32 * 180];
    __shared__ uint Blo[32 * 180];

    stage_hilo(xs, n, tid, Bhi, Blo);
    __syncthreads();

    const int ob = wave * 32 + (lane & 15);
    const int ksub = (lane >> 4) * 8;
    const int brow = lane & 15;
    const ushort* BH = (const ushort*)Bhi;
    const ushort* BL = (const ushort*)Blo;
    f32x4 acc[2][2] = {};

    #pragma unroll 2
    for (int ks = 0; ks < KSTEPS; ++ks) {
        const int ko = ks * 32 + ksub;
        short8 Ah0 = *(const short8*)(whi + (size_t)ob * KP + ko);
        short8 Ah1 = *(const short8*)(whi + (size_t)(ob + 16) * KP + ko);
        short8 Al0 = *(const short8*)(wlo + (size_t)ob * KP + ko);
        short8 Al1 = *(const short8*)(wlo + (size_t)(ob + 16) * KP + ko);
        short8 Bh0 = *(const short8*)(BH + brow * 360 + ko);
        short8 Bh1 = *(const short8*)(BH + (16 + brow) * 360 + ko);
        short8 Bl0 = *(const short8*)(BL + brow * 360 + ko);
        short8 Bl1 = *(const short8*)(BL + (16 + brow) * 360 + ko);
        acc[0][0] = MFMA(Ah0, Bh0, acc[0][0]);
        acc[0][1] = MFMA(Ah0, Bh1, acc[0][1]);
        acc[1][0] = MFMA(Ah1, Bh0, acc[1][0]);
        acc[1][1] = MFMA(Ah1, Bh1, acc[1][1]);
        acc[0][0] = MFMA(Ah0, Bl0, acc[0][0]);
        acc[0][1] = MFMA(Ah0, Bl1, acc[0][1]);
        acc[1][0] = MFMA(Ah1, Bl0, acc[1][0]);
        acc[1][1] = MFMA(Ah1, Bl1, acc[1][1]);
        acc[0][0] = MFMA(Al0, Bh0, acc[0][0]);
        acc[0][1] = MFMA(Al0, Bh1, acc[0][1]);
        acc[1][0] = MFMA(Al1, Bh0, acc[1][0]);
        acc[1][1] = MFMA(Al1, Bh1, acc[1][1]);
    }

    const int g = lane >> 4, bcol = lane & 15;
    #pragma unroll
    for (int t = 0; t < 2; ++t) {
        const int o = wave * 32 + t * 16 + g * 4;
        const float bb0 = bru[o], bb1 = bru[o + 1], bb2 = bru[o + 2], bb3 = bru[o + 3];
        #pragma unroll
        for (int bt = 0; bt < 2; ++bt) {
            const int bl = bt * 16 + bcol;
            float s0 = sigm(acc[t][bt][0] + bb0);
            float s1 = sigm(acc[t][bt][1] + bb1);
            float s2 = sigm(acc[t][bt][2] + bb2);
            float s3 = sigm(acc[t][bt][3] + bb3);
            if (o < 64) {   // r-part: write r*hx into xs0 state features (f32)
                const f32x4 hxv = *(const f32x4*)(hx + (size_t)(h * HB + bl) * 262144 + (size_t)n * 64 + o);
                float* dw = xs0w + (size_t)n * ROW_E + bl * FD + 2 + o;
                f32x2 w0; w0.x = s0 * hxv[0]; w0.y = s1 * hxv[1];
                f32x2 w1; w1.x = s2 * hxv[2]; w1.y = s3 * hxv[3];
                *(f32x2*)(dw) = w0;
                *(f32x2*)(dw + 2) = w1;
            } else {        // u-part -> d_out (temporary storage)
                f32x4 uv = {s0, s1, s2, s3};
                *(f32x4*)(uout + (size_t)(h * HB + bl) * 262144 + (size_t)n * 64 + (o - 64)) = uv;
            }
        }
    }
}

// ---------------- gconv2 matmul + tanh + final GRU combine ------------------
__global__ __launch_bounds__(256, 3) void mm_c_k(const float* __restrict__ xs,
                                                 const ushort* __restrict__ whi, const ushort* __restrict__ wlo,
                                                 const float* __restrict__ bc, const float* __restrict__ hx,
                                                 float* __restrict__ out, int h)
{
    const int n = blockIdx.x;
    const int tid = threadIdx.x;
    const int lane = tid & 63, wave = tid >> 6;
    __shared__ uint Bhi[32 * 180];
    __shared__ uint Blo[32 * 180];

    stage_hilo(xs, n, tid, Bhi, Blo);
    __syncthreads();

    const int ob = wave * 16 + (lane & 15);
    const int ksub = (lane >> 4) * 8;
    const int brow = lane & 15;
    const ushort* BH = (const ushort*)Bhi;
    const ushort* BL = (const ushort*)Blo;
    f32x4 acc[2] = {};

    #pragma unroll 2
    for (int ks = 0; ks < KSTEPS; ++ks) {
        const int ko = ks * 32 + ksub;
        short8 Ah = *(const short8*)(whi + (size_t)ob * KP + ko);
        short8 Al = *(const short8*)(wlo + (size_t)ob * KP + ko);
        short8 Bh0 = *(const short8*)(BH + brow * 360 + ko);
        short8 Bh1 = *(const short8*)(BH + (16 + brow) * 360 + ko);
        short8 Bl0 = *(const short8*)(BL + brow * 360 + ko);
        short8 Bl1 = *(const short8*)(BL + (16 + brow) * 360 + ko);
        acc[0] = MFMA(Ah, Bh0, acc[0]);
        acc[1] = MFMA(Ah, Bh1, acc[1]);
        acc[0] = MFMA(Ah, Bl0, acc[0]);
        acc[1] = MFMA(Ah, Bl1, acc[1]);
        acc[0] = MFMA(Al, Bh0, acc[0]);
        acc[1] = MFMA(Al, Bh1, acc[1]);
    }

    const int g = lane >> 4, bcol = lane & 15;
    const int o = wave * 16 + g * 4;
    const float bb0 = bc[o], bb1 = bc[o + 1], bb2 = bc[o + 2], bb3 = bc[o + 3];
    #pragma unroll
    for (int bt = 0; bt < 2; ++bt) {
        const int bl = bt * 16 + bcol;
        float c0 = tanh_fast(acc[bt][0] + bb0);
        float c1 = tanh_fast(acc[bt][1] + bb1);
        float c2 = tanh_fast(acc[bt][2] + bb2);
        float c3 = tanh_fast(acc[bt][3] + bb3);
        float* p = out + (size_t)(h * HB + bl) * 262144 + (size_t)n * 64 + o;
        const f32x4 hxv = *(const f32x4*)(hx + (size_t)(h * HB + bl) * 262144 + (size_t)n * 64 + o);
        f32x4 uv = *(const f32x4*)p;
        f32x4 ov;
        ov[0] = uv[0] * hxv[0] + (1.0f - uv[0]) * c0;
        ov[1] = uv[1] * hxv[1] + (1.0f - uv[1]) * c1;
        ov[2] = uv[2] * hxv[2] + (1.0f - uv[2]) * c2;
        ov[3] = uv[3] * hxv[3] + (1.0f - uv[3]) * c3;
        *(f32x4*)p = ov;
    }
}

// ---------------------------------------------------------------------------
extern "C" void kernel_launch(void* const* d_in, const int* in_sizes, int n_in,
                              void* d_out, int out_size, void* d_ws, size_t ws_size,
                              hipStream_t stream)
{
    (void)in_sizes; (void)n_in; (void)out_size; (void)ws_size;
    const float* inputs  = (const float*)d_in[0];
    const float* hx      = (const float*)d_in[1];
    const int*   sup_rows= (const int*)d_in[2];
    const int*   sup_cols= (const int*)d_in[3];
    const float* sup_vals= (const float*)d_in[4];
    const float* W_ru    = (const float*)d_in[5];
    const float* b_ru    = (const float*)d_in[6];
    const float* W_c     = (const float*)d_in[7];
    const float* b_c     = (const float*)d_in[8];
    float* out = (float*)d_out;

    char* ws = (char*)d_ws;
    float* xs = (float*)ws;                                 // 5 f32 buffers (half batch)
    size_t off = 5ull * 34603008ull;                        // 173,015,040
    ushort* wru_hi = (ushort*)(ws + off); off += 90112;
    ushort* wru_lo = (ushort*)(ws + off); off += 90112;
    ushort* wc_hi  = (ushort*)(ws + off); off += 45056;
    ushort* wc_lo  = (ushort*)(ws + off); off += 45056;
    int* row_ptr   = (int*)(ws + off);    off += 32800;
    int* cntfill   = (int*)(ws + off);    off += 65536;
    int* scols     = (int*)(ws + off);    off += 524288;
    float* svals   = (float*)(ws + off);  off += 524288;

    float* xs0 = xs;
    float* xs1 = xs + 1 * XSW;
    float* xs2 = xs + 2 * XSW;
    float* xs3 = xs + 3 * XSW;
    float* xs4 = xs + 4 * XSW;
    int* fill = cntfill + 8192;

    zero_k<<<64, 256, 0, stream>>>(cntfill);
    wtbuild_k<<<264, 256, 0, stream>>>(W_ru, W_c, wru_hi, wru_lo, wc_hi, wc_lo);
    count_k<<<512, 256, 0, stream>>>(sup_rows, cntfill);
    scan_k<<<2, 1024, 0, stream>>>(cntfill, row_ptr);
    scatter_k<<<512, 256, 0, stream>>>(sup_rows, sup_cols, sup_vals, row_ptr, fill, scols, svals);

    for (int h = 0; h < 2; ++h) {
        x0build_k<<<16896, 256, 0, stream>>>(inputs, hx, xs0, h);
        // gconv1 diffusion: step1 (both supports read xs0), step2 split per support
        spmm_k<<<dim3(8192, 2), 256, 0, stream>>>(xs0, xs0, xs1, xs3, xs0, row_ptr, scols, svals, 0, 0);
        spmm_k<<<dim3(8192, 1), 256, 0, stream>>>(xs1, xs1, xs2, xs2, xs0, row_ptr, scols, svals, 1, 0);
        spmm_k<<<dim3(8192, 1), 256, 0, stream>>>(xs3, xs3, xs4, xs4, xs0, row_ptr, scols, svals, 1, 1);
        // gconv1 matmul: u -> out, r*hx -> xs0 state part
        mm_ru_k<<<NN, 256, 0, stream>>>(xs, wru_hi, wru_lo, b_ru, hx, out, xs0, h);
        // gconv2 diffusion (xs0 now holds [inputs, r*hx])
        spmm_k<<<dim3(8192, 2), 256, 0, stream>>>(xs0, xs0, xs1, xs3, xs0, row_ptr, scols, svals, 0, 0);
        spmm_k<<<dim3(8192, 1), 256, 0, stream>>>(xs1, xs1, xs2, xs2, xs0, row_ptr, scols, svals, 1, 0);
        spmm_k<<<dim3(8192, 1), 256, 0, stream>>>(xs3, xs3, xs4, xs4, xs0, row_ptr, scols, svals, 1, 1);
        // gconv2 matmul + tanh + final GRU combine
        mm_c_k<<<NN, 256, 0, stream>>>(xs, wc_hi, wc_lo, b_c, hx, out, h);
    }
}

// Round 6
// 1369.656 us; speedup vs baseline: 1.3464x; 1.1804x over previous
//
#include <hip/hip_runtime.h>

typedef float f32x4 __attribute__((ext_vector_type(4)));
typedef float f32x2 __attribute__((ext_vector_type(2)));
typedef short short8 __attribute__((ext_vector_type(8)));

#define NN 4096
#define HB 32               // half batch
#define FD 66
#define ROW_E 2112          // HB*FD f32 per node row (half batch)
#define XSW 8650752ull      // f32 words per xs buffer (NN*ROW_E)
#define KP 352              // padded K (330 real)
#define KSTEPS 11

__device__ __forceinline__ ushort f2bf(float f){ uint i = __float_as_uint(f); return (ushort)((i + 0x7fffu + ((i >> 16) & 1u)) >> 16); }
__device__ __forceinline__ float bf2f(ushort u){ return __uint_as_float((uint)u << 16); }
__device__ __forceinline__ uint pkhi2(float a, float b){ return (uint)f2bf(a) | ((uint)f2bf(b) << 16); }
__device__ __forceinline__ uint pklo2(float a, float b){
    ushort ha = f2bf(a), hb = f2bf(b);
    return (uint)f2bf(a - bf2f(ha)) | ((uint)f2bf(b - bf2f(hb)) << 16);
}
__device__ __forceinline__ float sigm(float x){ return 1.0f / (1.0f + __expf(-x)); }
__device__ __forceinline__ float tanh_fast(float x){
    x = fminf(20.0f, fmaxf(-20.0f, x));
    float t = __expf(-2.0f * x);
    return (1.0f - t) / (1.0f + t);
}
__device__ __forceinline__ f32x4 fma4(float v, f32x4 x, f32x4 a){
    a.x = fmaf(v, x.x, a.x); a.y = fmaf(v, x.y, a.y);
    a.z = fmaf(v, x.z, a.z); a.w = fmaf(v, x.w, a.w);
    return a;
}

// ---------------- zero scratch (cnt+fill), graph-capture-safe ---------------
__global__ void zero_k(int* __restrict__ p){ p[blockIdx.x * 256 + threadIdx.x] = 0; }

// ------- weight transform: Wt_hi/lo[o][k], k = m*66+f, bf16 hi/lo split -----
__global__ void wtbuild_k(const float* __restrict__ Wru, const float* __restrict__ Wc,
                          ushort* __restrict__ ru_hi, ushort* __restrict__ ru_lo,
                          ushort* __restrict__ c_hi,  ushort* __restrict__ c_lo)
{
    int idx = blockIdx.x * 256 + threadIdx.x;   // 192*352 exact
    float w = 0.0f;
    if (idx < 128 * KP) {
        int o = idx / KP, k = idx - o * KP;
        if (k < 330) { int m = k / FD, f = k - m * FD; w = Wru[(size_t)(f * 5 + m) * 128 + o]; }
        ushort hi = f2bf(w);
        ushort lo = f2bf(w - bf2f(hi));
        ru_hi[(size_t)o * KP + k] = hi;
        ru_lo[(size_t)o * KP + k] = lo;
    } else {
        int j = idx - 128 * KP;
        int o = j / KP, k = j - o * KP;
        if (k < 330) { int m = k / FD, f = k - m * FD; w = Wc[(size_t)(f * 5 + m) * 64 + o]; }
        ushort hi = f2bf(w);
        ushort lo = f2bf(w - bf2f(hi));
        c_hi[(size_t)o * KP + k] = hi;
        c_lo[(size_t)o * KP + k] = lo;
    }
}

// ---------------- CSR build ------------------------------------------------
__global__ void count_k(const int* __restrict__ rows, int* __restrict__ cnt)
{
    int i = blockIdx.x * 256 + threadIdx.x;     // 2*65536 exact
    int s = i >> 16;
    atomicAdd(&cnt[(s << 12) + rows[i]], 1);
}

__global__ __launch_bounds__(1024) void scan_k(const int* __restrict__ cnt, int* __restrict__ rp)
{
    int s = blockIdx.x;
    const int* c = cnt + (s << 12);
    int* r = rp + s * 4097;
    __shared__ int sd[1024];
    int tid = threadIdx.x;
    int i0 = tid * 4;
    int a0 = c[i0], a1 = c[i0 + 1], a2 = c[i0 + 2], a3 = c[i0 + 3];
    sd[tid] = a0 + a1 + a2 + a3;
    __syncthreads();
    for (int off = 1; off < 1024; off <<= 1) {
        int v = (tid >= off) ? sd[tid - off] : 0;
        __syncthreads();
        sd[tid] += v;
        __syncthreads();
    }
    int base = tid ? sd[tid - 1] : 0;
    r[i0] = base; r[i0 + 1] = base + a0; r[i0 + 2] = base + a0 + a1; r[i0 + 3] = base + a0 + a1 + a2;
    if (tid == 1023) r[4096] = sd[1023];
}

// scatter into packed (col, val) CSR stream
__global__ void scatter_k(const int* __restrict__ rows, const int* __restrict__ cols,
                          const float* __restrict__ vals, const int* __restrict__ rp,
                          int* __restrict__ fill, int2* __restrict__ pcv)
{
    int i = blockIdx.x * 256 + threadIdx.x;     // 2*65536 exact
    int s = i >> 16;
    int r = rows[i];
    int pos = rp[s * 4097 + r] + atomicAdd(&fill[(s << 12) + r], 1);
    int2 e; e.x = cols[i]; e.y = __float_as_int(vals[i]);
    pcv[(s << 16) + pos] = e;
}

// ---------------- x0 build (f32): x0[n][bl*66+f], half batch h --------------
__global__ void x0build_k(const float* __restrict__ in, const float* __restrict__ hx,
                          float* __restrict__ x0, int h)
{
    int i = blockIdx.x * 256 + threadIdx.x;     // NN*1056 exact (pairs)
    int e0 = i * 2;
    int n = e0 / ROW_E;
    int rem = e0 - n * ROW_E;
    int bl = rem / FD;
    int f = rem - bl * FD;                      // even
    int b = h * HB + bl;
    float v0 = (f < 2) ? in[(size_t)b * 8192 + n * 2 + f]
                       : hx[(size_t)b * 262144 + (size_t)n * 64 + (f - 2)];
    int f1 = f + 1;
    float v1 = (f1 < 2) ? in[(size_t)b * 8192 + n * 2 + f1]
                        : hx[(size_t)b * 262144 + (size_t)n * 64 + (f1 - 2)];
    f32x2 ov; ov.x = v0; ov.y = v1;
    __builtin_nontemporal_store(ov, (f32x2*)(x0 + e0));
}

// ---------------- SpMM v3: 16 sub-chunks x 33 quads, phase-ordered ----------
// blockIdx.x = [phase:1][rowgrp:10][xcd:3]. XCD c owns sub-chunks 2c (phase 0)
// then 2c+1 (phase 1); per-phase slice = 4096 x 528 B = 2.16 MB + CSR < L2.
// Wave = one row; lanes 0..32 active, 1 f32x4 gather/edge/lane; 4-edge unroll.
__global__ __launch_bounds__(256) void spmm_k(const float* __restrict__ src0, const float* __restrict__ src1,
                                              float* __restrict__ dst0, float* __restrict__ dst1,
                                              const float* __restrict__ prev,
                                              const int* __restrict__ rp, const int2* __restrict__ pcv,
                                              int cheb, int supbase)
{
    const int s = supbase + blockIdx.y;
    const float* __restrict__ x = s ? src1 : src0;
    float* __restrict__ dst = s ? dst1 : dst0;
    const int xcd = blockIdx.x & 7;
    const int phase = blockIdx.x >> 13;
    const int sub = xcd * 2 + phase;
    const int r = (((blockIdx.x >> 3) & 1023) << 2) + (threadIdx.x >> 6);
    const int lane = threadIdx.x & 63;
    const int p0 = rp[s * 4097 + r], p1 = rp[s * 4097 + r + 1];
    const int2* __restrict__ es = pcv + (s << 16);
    const size_t o = (size_t)(sub * 33 + lane) * 4;     // f32 offset (lane<33)
    const size_t rbase = (size_t)r * ROW_E;

    if (lane < 33) {
        f32x4 a0 = {0,0,0,0}, a1 = {0,0,0,0}, a2 = {0,0,0,0}, a3 = {0,0,0,0};
        int e = p0;
        for (; e + 4 <= p1; e += 4) {
            const int2 e0 = es[e], e1 = es[e + 1], e2 = es[e + 2], e3 = es[e + 3];
            const f32x4 x0v = *(const f32x4*)(x + (size_t)e0.x * ROW_E + o);
            const f32x4 x1v = *(const f32x4*)(x + (size_t)e1.x * ROW_E + o);
            const f32x4 x2v = *(const f32x4*)(x + (size_t)e2.x * ROW_E + o);
            const f32x4 x3v = *(const f32x4*)(x + (size_t)e3.x * ROW_E + o);
            a0 = fma4(__int_as_float(e0.y), x0v, a0);
            a1 = fma4(__int_as_float(e1.y), x1v, a1);
            a2 = fma4(__int_as_float(e2.y), x2v, a2);
            a3 = fma4(__int_as_float(e3.y), x3v, a3);
        }
        for (; e < p1; ++e) {
            const int2 e0 = es[e];
            const f32x4 x0v = *(const f32x4*)(x + (size_t)e0.x * ROW_E + o);
            a0 = fma4(__int_as_float(e0.y), x0v, a0);
        }
        f32x4 R;
        R.x = (a0.x + a1.x) + (a2.x + a3.x);
        R.y = (a0.y + a1.y) + (a2.y + a3.y);
        R.z = (a0.z + a1.z) + (a2.z + a3.z);
        R.w = (a0.w + a1.w) + (a2.w + a3.w);
        if (cheb) {
            const f32x4 pv = __builtin_nontemporal_load((const f32x4*)(prev + rbase + o));
            R.x = 2.0f * R.x - pv.x; R.y = 2.0f * R.y - pv.y;
            R.z = 2.0f * R.z - pv.z; R.w = 2.0f * R.w - pv.w;
        }
        __builtin_nontemporal_store(R, (f32x4*)(dst + rbase + o));
    }
}

// ------ mm staging: f32 rows -> hi/lo bf16 packed LDS (f32x4 loads) ---------
__device__ __forceinline__ void stage_hilo(const float* __restrict__ xs, int n, int tid,
                                           uint* __restrict__ Bhi, uint* __restrict__ Blo)
{
    for (int i = tid; i < 480; i += 256) {      // zero K-pad words 165..179 per b-row
        int bl = i / 15, t = i - bl * 15;
        Bhi[bl * 180 + 165 + t] = 0u;
        Blo[bl * 180 + 165 + t] = 0u;
    }
    for (int i = tid; i < 2640; i += 256) {     // 5 levels x 528 f32x4
        int m = i / 528, p = i - m * 528;
        const f32x4 v = __builtin_nontemporal_load(
            (const f32x4*)(xs + (size_t)m * XSW + (size_t)n * ROW_E + p * 4));
        int w0 = p * 2;
        int bl0 = w0 / 33, f0 = w0 - bl0 * 33;
        int w1 = w0 + 1;
        int bl1 = w1 / 33, f1 = w1 - bl1 * 33;
        Bhi[bl0 * 180 + m * 33 + f0] = pkhi2(v.x, v.y);
        Blo[bl0 * 180 + m * 33 + f0] = pklo2(v.x, v.y);
        Bhi[bl1 * 180 + m * 33 + f1] = pkhi2(v.z, v.w);
        Blo[bl1 * 180 + m * 33 + f1] = pklo2(v.z, v.w);
    }
}

#define MFMA(a, b, c) __builtin_amdgcn_mfma_f32_16x16x32_bf16(a, b, c, 0, 0, 0)

// ---------------- gconv1 matmul + sigmoid; u->out, r*hx->xs0 ----------------
__global__ __launch_bounds__(256, 3) void mm_ru_k(const float* __restrict__ xs,
                                                  const ushort* __restrict__ whi, const ushort* __restrict__ wlo,
                                                  const float* __restrict__ bru, const float* __restrict__ hx,
                                                  float* __restrict__ uout, float* __restrict__ xs0w, int h)
{
    const int n = blockIdx.x;
    const int tid = threadIdx.x;
    const int lane = tid & 63, wave = tid >> 6;
    __shared__ uint Bhi[32 * 180];
    __shared__ uint Blo[32 * 180];

    stage_hilo(xs, n, tid, Bhi, Blo);
    __syncthreads();

    const int ob = wave * 32 + (lane & 15);
    const int ksub = (lane >> 4) * 8;
    const int brow = lane & 15;
    const ushort* BH = (const ushort*)Bhi;
    const ushort* BL = (const ushort*)Blo;
    f32x4 acc[2][2] = {};

    #pragma unroll 2
    for (int ks = 0; ks < KSTEPS; ++ks) {
        const int ko = ks * 32 + ksub;
        short8 Ah0 = *(const short8*)(whi + (size_t)ob * KP + ko);
        short8 Ah1 = *(const short8*)(whi + (size_t)(ob + 16) * KP + ko);
        short8 Al0 = *(const short8*)(wlo + (size_t)ob * KP + ko);
        short8 Al1 = *(const short8*)(wlo + (size_t)(ob + 16) * KP + ko);
        short8 Bh0 = *(const short8*)(BH + brow * 360 + ko);
        short8 Bh1 = *(const short8*)(BH + (16 + brow) * 360 + ko);
        short8 Bl0 = *(const short8*)(BL + brow * 360 + ko);
        short8 Bl1 = *(const short8*)(BL + (16 + brow) * 360 + ko);
        acc[0][0] = MFMA(Ah0, Bh0, acc[0][0]);
        acc[0][1] = MFMA(Ah0, Bh1, acc[0][1]);
        acc[1][0] = MFMA(Ah1, Bh0, acc[1][0]);
        acc[1][1] = MFMA(Ah1, Bh1, acc[1][1]);
        acc[0][0] = MFMA(Ah0, Bl0, acc[0][0]);
        acc[0][1] = MFMA(Ah0, Bl1, acc[0][1]);
        acc[1][0] = MFMA(Ah1, Bl0, acc[1][0]);
        acc[1][1] = MFMA(Ah1, Bl1, acc[1][1]);
        acc[0][0] = MFMA(Al0, Bh0, acc[0][0]);
        acc[0][1] = MFMA(Al0, Bh1, acc[0][1]);
        acc[1][0] = MFMA(Al1, Bh0, acc[1][0]);
        acc[1][1] = MFMA(Al1, Bh1, acc[1][1]);
    }

    const int g = lane >> 4, bcol = lane & 15;
    #pragma unroll
    for (int t = 0; t < 2; ++t) {
        const int o = wave * 32 + t * 16 + g * 4;
        const float bb0 = bru[o], bb1 = bru[o + 1], bb2 = bru[o + 2], bb3 = bru[o + 3];
        #pragma unroll
        for (int bt = 0; bt < 2; ++bt) {
            const int bl = bt * 16 + bcol;
            float s0 = sigm(acc[t][bt][0] + bb0);
            float s1 = sigm(acc[t][bt][1] + bb1);
            float s2 = sigm(acc[t][bt][2] + bb2);
            float s3 = sigm(acc[t][bt][3] + bb3);
            if (o < 64) {   // r-part: write r*hx into xs0 state features (f32)
                const f32x4 hxv = *(const f32x4*)(hx + (size_t)(h * HB + bl) * 262144 + (size_t)n * 64 + o);
                float* dw = xs0w + (size_t)n * ROW_E + bl * FD + 2 + o;
                f32x2 w0; w0.x = s0 * hxv[0]; w0.y = s1 * hxv[1];
                f32x2 w1; w1.x = s2 * hxv[2]; w1.y = s3 * hxv[3];
                *(f32x2*)(dw) = w0;
                *(f32x2*)(dw + 2) = w1;
            } else {        // u-part -> d_out (temporary storage)
                f32x4 uv = {s0, s1, s2, s3};
                *(f32x4*)(uout + (size_t)(h * HB + bl) * 262144 + (size_t)n * 64 + (o - 64)) = uv;
            }
        }
    }
}

// ---------------- gconv2 matmul + tanh + final GRU combine ------------------
__global__ __launch_bounds__(256, 3) void mm_c_k(const float* __restrict__ xs,
                                                 const ushort* __restrict__ whi, const ushort* __restrict__ wlo,
                                                 const float* __restrict__ bc, const float* __restrict__ hx,
                                                 float* __restrict__ out, int h)
{
    const int n = blockIdx.x;
    const int tid = threadIdx.x;
    const int lane = tid & 63, wave = tid >> 6;
    __shared__ uint Bhi[32 * 180];
    __shared__ uint Blo[32 * 180];

    stage_hilo(xs, n, tid, Bhi, Blo);
    __syncthreads();

    const int ob = wave * 16 + (lane & 15);
    const int ksub = (lane >> 4) * 8;
    const int brow = lane & 15;
    const ushort* BH = (const ushort*)Bhi;
    const ushort* BL = (const ushort*)Blo;
    f32x4 acc[2] = {};

    #pragma unroll 2
    for (int ks = 0; ks < KSTEPS; ++ks) {
        const int ko = ks * 32 + ksub;
        short8 Ah = *(const short8*)(whi + (size_t)ob * KP + ko);
        short8 Al = *(const short8*)(wlo + (size_t)ob * KP + ko);
        short8 Bh0 = *(const short8*)(BH + brow * 360 + ko);
        short8 Bh1 = *(const short8*)(BH + (16 + brow) * 360 + ko);
        short8 Bl0 = *(const short8*)(BL + brow * 360 + ko);
        short8 Bl1 = *(const short8*)(BL + (16 + brow) * 360 + ko);
        acc[0] = MFMA(Ah, Bh0, acc[0]);
        acc[1] = MFMA(Ah, Bh1, acc[1]);
        acc[0] = MFMA(Ah, Bl0, acc[0]);
        acc[1] = MFMA(Ah, Bl1, acc[1]);
        acc[0] = MFMA(Al, Bh0, acc[0]);
        acc[1] = MFMA(Al, Bh1, acc[1]);
    }

    const int g = lane >> 4, bcol = lane & 15;
    const int o = wave * 16 + g * 4;
    const float bb0 = bc[o], bb1 = bc[o + 1], bb2 = bc[o + 2], bb3 = bc[o + 3];
    #pragma unroll
    for (int bt = 0; bt < 2; ++bt) {
        const int bl = bt * 16 + bcol;
        float c0 = tanh_fast(acc[bt][0] + bb0);
        float c1 = tanh_fast(acc[bt][1] + bb1);
        float c2 = tanh_fast(acc[bt][2] + bb2);
        float c3 = tanh_fast(acc[bt][3] + bb3);
        float* p = out + (size_t)(h * HB + bl) * 262144 + (size_t)n * 64 + o;
        const f32x4 hxv = *(const f32x4*)(hx + (size_t)(h * HB + bl) * 262144 + (size_t)n * 64 + o);
        f32x4 uv = *(const f32x4*)p;
        f32x4 ov;
        ov[0] = uv[0] * hxv[0] + (1.0f - uv[0]) * c0;
        ov[1] = uv[1] * hxv[1] + (1.0f - uv[1]) * c1;
        ov[2] = uv[2] * hxv[2] + (1.0f - uv[2]) * c2;
        ov[3] = uv[3] * hxv[3] + (1.0f - uv[3]) * c3;
        *(f32x4*)p = ov;
    }
}

// ---------------------------------------------------------------------------
extern "C" void kernel_launch(void* const* d_in, const int* in_sizes, int n_in,
                              void* d_out, int out_size, void* d_ws, size_t ws_size,
                              hipStream_t stream)
{
    (void)in_sizes; (void)n_in; (void)out_size; (void)ws_size;
    const float* inputs  = (const float*)d_in[0];
    const float* hx      = (const float*)d_in[1];
    const int*   sup_rows= (const int*)d_in[2];
    const int*   sup_cols= (const int*)d_in[3];
    const float* sup_vals= (const float*)d_in[4];
    const float* W_ru    = (const float*)d_in[5];
    const float* b_ru    = (const float*)d_in[6];
    const float* W_c     = (const float*)d_in[7];
    const float* b_c     = (const float*)d_in[8];
    float* out = (float*)d_out;

    char* ws = (char*)d_ws;
    float* xs = (float*)ws;                                 // 5 f32 buffers (half batch)
    size_t off = 5ull * 34603008ull;                        // 173,015,040
    ushort* wru_hi = (ushort*)(ws + off); off += 90112;
    ushort* wru_lo = (ushort*)(ws + off); off += 90112;
    ushort* wc_hi  = (ushort*)(ws + off); off += 45056;
    ushort* wc_lo  = (ushort*)(ws + off); off += 45056;
    int* row_ptr   = (int*)(ws + off);    off += 32800;
    int* cntfill   = (int*)(ws + off);    off += 65536;
    int2* pcv      = (int2*)(ws + off);   off += 1048576;   // packed (col,val) CSR

    float* xs0 = xs;
    float* xs1 = xs + 1 * XSW;
    float* xs2 = xs + 2 * XSW;
    float* xs3 = xs + 3 * XSW;
    float* xs4 = xs + 4 * XSW;
    int* fill = cntfill + 8192;

    zero_k<<<64, 256, 0, stream>>>(cntfill);
    wtbuild_k<<<264, 256, 0, stream>>>(W_ru, W_c, wru_hi, wru_lo, wc_hi, wc_lo);
    count_k<<<512, 256, 0, stream>>>(sup_rows, cntfill);
    scan_k<<<2, 1024, 0, stream>>>(cntfill, row_ptr);
    scatter_k<<<512, 256, 0, stream>>>(sup_rows, sup_cols, sup_vals, row_ptr, fill, pcv);

    for (int h = 0; h < 2; ++h) {
        x0build_k<<<16896, 256, 0, stream>>>(inputs, hx, xs0, h);
        // gconv1 diffusion: step1 (both supports read xs0), step2 split per support
        spmm_k<<<dim3(16384, 2), 256, 0, stream>>>(xs0, xs0, xs1, xs3, xs0, row_ptr, pcv, 0, 0);
        spmm_k<<<dim3(16384, 1), 256, 0, stream>>>(xs1, xs1, xs2, xs2, xs0, row_ptr, pcv, 1, 0);
        spmm_k<<<dim3(16384, 1), 256, 0, stream>>>(xs3, xs3, xs4, xs4, xs0, row_ptr, pcv, 1, 1);
        // gconv1 matmul: u -> out, r*hx -> xs0 state part
        mm_ru_k<<<NN, 256, 0, stream>>>(xs, wru_hi, wru_lo, b_ru, hx, out, xs0, h);
        // gconv2 diffusion (xs0 now holds [inputs, r*hx])
        spmm_k<<<dim3(16384, 2), 256, 0, stream>>>(xs0, xs0, xs1, xs3, xs0, row_ptr, pcv, 0, 0);
        spmm_k<<<dim3(16384, 1), 256, 0, stream>>>(xs1, xs1, xs2, xs2, xs0, row_ptr, pcv, 1, 0);
        spmm_k<<<dim3(16384, 1), 256, 0, stream>>>(xs3, xs3, xs4, xs4, xs0, row_ptr, pcv, 1, 1);
        // gconv2 matmul + tanh + final GRU combine
        mm_c_k<<<NN, 256, 0, stream>>>(xs, wc_hi, wc_lo, b_c, hx, out, h);
    }
}

// Round 7
// 1064.426 us; speedup vs baseline: 1.7325x; 1.2868x over previous
//
#include <hip/hip_runtime.h>

typedef float f32x4 __attribute__((ext_vector_type(4)));
typedef float f32x2 __attribute__((ext_vector_type(2)));
typedef short short8 __attribute__((ext_vector_type(8)));

#define NN 4096
#define HB 32               // half batch
#define SROW 2048           // state f32 per node row (32 b x 64 f)
#define IROW 64             // input f32 per node row (32 b x 2 f)
#define SLVL 8388608ull     // f32 per state level (NN*SROW)
#define ILVL 262144ull      // f32 per input level (NN*IROW)
#define KP 352              // padded K (330 real)
#define KSTEPS 11

__device__ __forceinline__ ushort f2bf(float f){ uint i = __float_as_uint(f); return (ushort)((i + 0x7fffu + ((i >> 16) & 1u)) >> 16); }
__device__ __forceinline__ float bf2f(ushort u){ return __uint_as_float((uint)u << 16); }
__device__ __forceinline__ uint pkhi2(float a, float b){ return (uint)f2bf(a) | ((uint)f2bf(b) << 16); }
__device__ __forceinline__ uint pklo2(float a, float b){
    ushort ha = f2bf(a), hb = f2bf(b);
    return (uint)f2bf(a - bf2f(ha)) | ((uint)f2bf(b - bf2f(hb)) << 16);
}
__device__ __forceinline__ float sigm(float x){ return 1.0f / (1.0f + __expf(-x)); }
__device__ __forceinline__ float tanh_fast(float x){
    x = fminf(20.0f, fmaxf(-20.0f, x));
    float t = __expf(-2.0f * x);
    return (1.0f - t) / (1.0f + t);
}
__device__ __forceinline__ f32x4 fma4(float v, f32x4 x, f32x4 a){
    a.x = fmaf(v, x.x, a.x); a.y = fmaf(v, x.y, a.y);
    a.z = fmaf(v, x.z, a.z); a.w = fmaf(v, x.w, a.w);
    return a;
}

// ---------------- zero scratch (cnt+fill), graph-capture-safe ---------------
__global__ void zero_k(int* __restrict__ p){ p[blockIdx.x * 256 + threadIdx.x] = 0; }

// ------- weight transform: Wt_hi/lo[o][k], k = m*66+f, bf16 hi/lo split -----
__global__ void wtbuild_k(const float* __restrict__ Wru, const float* __restrict__ Wc,
                          ushort* __restrict__ ru_hi, ushort* __restrict__ ru_lo,
                          ushort* __restrict__ c_hi,  ushort* __restrict__ c_lo)
{
    int idx = blockIdx.x * 256 + threadIdx.x;   // 192*352 exact
    float w = 0.0f;
    if (idx < 128 * KP) {
        int o = idx / KP, k = idx - o * KP;
        if (k < 330) { int m = k / 66, f = k - m * 66; w = Wru[(size_t)(f * 5 + m) * 128 + o]; }
        ushort hi = f2bf(w);
        ushort lo = f2bf(w - bf2f(hi));
        ru_hi[(size_t)o * KP + k] = hi;
        ru_lo[(size_t)o * KP + k] = lo;
    } else {
        int j = idx - 128 * KP;
        int o = j / KP, k = j - o * KP;
        if (k < 330) { int m = k / 66, f = k - m * 66; w = Wc[(size_t)(f * 5 + m) * 64 + o]; }
        ushort hi = f2bf(w);
        ushort lo = f2bf(w - bf2f(hi));
        c_hi[(size_t)o * KP + k] = hi;
        c_lo[(size_t)o * KP + k] = lo;
    }
}

// ---------------- CSR build ------------------------------------------------
__global__ void count_k(const int* __restrict__ rows, int* __restrict__ cnt)
{
    int i = blockIdx.x * 256 + threadIdx.x;     // 2*65536 exact
    int s = i >> 16;
    atomicAdd(&cnt[(s << 12) + rows[i]], 1);
}

__global__ __launch_bounds__(1024) void scan_k(const int* __restrict__ cnt, int* __restrict__ rp)
{
    int s = blockIdx.x;
    const int* c = cnt + (s << 12);
    int* r = rp + s * 4097;
    __shared__ int sd[1024];
    int tid = threadIdx.x;
    int i0 = tid * 4;
    int a0 = c[i0], a1 = c[i0 + 1], a2 = c[i0 + 2], a3 = c[i0 + 3];
    sd[tid] = a0 + a1 + a2 + a3;
    __syncthreads();
    for (int off = 1; off < 1024; off <<= 1) {
        int v = (tid >= off) ? sd[tid - off] : 0;
        __syncthreads();
        sd[tid] += v;
        __syncthreads();
    }
    int base = tid ? sd[tid - 1] : 0;
    r[i0] = base; r[i0 + 1] = base + a0; r[i0 + 2] = base + a0 + a1; r[i0 + 3] = base + a0 + a1 + a2;
    if (tid == 1023) r[4096] = sd[1023];
}

// scatter into packed (col, val) CSR stream
__global__ void scatter_k(const int* __restrict__ rows, const int* __restrict__ cols,
                          const float* __restrict__ vals, const int* __restrict__ rp,
                          int* __restrict__ fill, int2* __restrict__ pcv)
{
    int i = blockIdx.x * 256 + threadIdx.x;     // 2*65536 exact
    int s = i >> 16;
    int r = rows[i];
    int pos = rp[s * 4097 + r] + atomicAdd(&fill[(s << 12) + r], 1);
    int2 e; e.x = cols[i]; e.y = __float_as_int(vals[i]);
    pcv[(s << 16) + pos] = e;
}

// ---------------- x0 build: state part (transpose hx) -----------------------
__global__ void x0s_k(const float* __restrict__ hx, float* __restrict__ x0s, int h)
{
    int i = blockIdx.x * 256 + threadIdx.x;     // 4096*512 quads exact
    int n = i >> 9, ql = i & 511;
    int bl = ql >> 4, fq = ql & 15;
    const f32x4 v = *(const f32x4*)(hx + (size_t)(h * HB + bl) * 262144 + (size_t)n * 64 + fq * 4);
    __builtin_nontemporal_store(v, (f32x4*)(x0s + (size_t)n * SROW + bl * 64 + fq * 4));
}

// ---------------- x0 build: input part --------------------------------------
__global__ void x0i_k(const float* __restrict__ in, float* __restrict__ x0i, int h)
{
    int i = blockIdx.x * 256 + threadIdx.x;     // 4096*32 exact
    int n = i >> 5, bl = i & 31;
    const f32x2 v = *(const f32x2*)(in + (size_t)(h * HB + bl) * 8192 + n * 2);
    __builtin_nontemporal_store(v, (f32x2*)(x0i + (size_t)n * IROW + bl * 2));
}

// ---------------- SpMM v4: full-lane waves, state+input split ---------------
// Main blocks (0..8191): [j:10][xcd:3]; j = [phase:1][rowgrp:9].
// sub = xcd*2+phase (16 subchunks x 32 quads); per-phase XCD slice = 2 MB ~ L2.
// Wave = 2 rows x 32 quads (all 64 lanes). 4-edge unroll.
// Input blocks (8192..8447): wave = 4 rows x 16 quads on the 1 MB input level.
__global__ __launch_bounds__(256) void spmm_k(
    const float* __restrict__ ss0, const float* __restrict__ si0,
    const float* __restrict__ ss1, const float* __restrict__ si1,
    float* __restrict__ ds0, float* __restrict__ di0,
    float* __restrict__ ds1, float* __restrict__ di1,
    const float* __restrict__ ps, const float* __restrict__ pi,
    const int* __restrict__ rp, const int2* __restrict__ pcv,
    int cheb, int supbase)
{
    const int s = supbase + blockIdx.y;
    const int2* __restrict__ es = pcv + (s << 16);
    const int tid = threadIdx.x;
    const float* __restrict__ x;
    float* __restrict__ dst;
    const float* __restrict__ prev;
    int r, o_, rs;
    if (blockIdx.x < 8192) {
        const int xcd = blockIdx.x & 7;
        const int j = blockIdx.x >> 3;          // 0..1023
        const int phase = j >> 9;               // 0/1
        const int rowgrp = j & 511;
        const int sub = xcd * 2 + phase;
        const int w = tid >> 6, half = (tid >> 5) & 1, l5 = tid & 31;
        r = rowgrp * 8 + w * 2 + half;
        o_ = (sub * 32 + l5) * 4;
        rs = SROW;
        x = s ? ss1 : ss0; dst = s ? ds1 : ds0; prev = ps;
    } else {
        const int j = blockIdx.x - 8192;        // 0..255
        const int w = tid >> 6, lane = tid & 63;
        r = (j * 4 + w) * 4 + (lane >> 4);
        o_ = (lane & 15) * 4;
        rs = IROW;
        x = s ? si1 : si0; dst = s ? di1 : di0; prev = pi;
    }
    const int p0 = rp[s * 4097 + r];
    const int cnt = rp[s * 4097 + r + 1] - p0;

    f32x4 a0 = {0,0,0,0}, a1 = {0,0,0,0}, a2 = {0,0,0,0}, a3 = {0,0,0,0};
    int e = 0;
    for (; e + 4 <= cnt; e += 4) {
        const int2 E0 = es[p0 + e],     E1 = es[p0 + e + 1];
        const int2 E2 = es[p0 + e + 2], E3 = es[p0 + e + 3];
        const f32x4 x0v = *(const f32x4*)(x + (size_t)E0.x * rs + o_);
        const f32x4 x1v = *(const f32x4*)(x + (size_t)E1.x * rs + o_);
        const f32x4 x2v = *(const f32x4*)(x + (size_t)E2.x * rs + o_);
        const f32x4 x3v = *(const f32x4*)(x + (size_t)E3.x * rs + o_);
        a0 = fma4(__int_as_float(E0.y), x0v, a0);
        a1 = fma4(__int_as_float(E1.y), x1v, a1);
        a2 = fma4(__int_as_float(E2.y), x2v, a2);
        a3 = fma4(__int_as_float(E3.y), x3v, a3);
    }
    for (; e < cnt; ++e) {
        const int2 E0 = es[p0 + e];
        const f32x4 x0v = *(const f32x4*)(x + (size_t)E0.x * rs + o_);
        a0 = fma4(__int_as_float(E0.y), x0v, a0);
    }
    f32x4 R;
    R.x = (a0.x + a1.x) + (a2.x + a3.x);
    R.y = (a0.y + a1.y) + (a2.y + a3.y);
    R.z = (a0.z + a1.z) + (a2.z + a3.z);
    R.w = (a0.w + a1.w) + (a2.w + a3.w);

    const size_t db = (size_t)r * rs + o_;
    if (cheb) {
        const f32x4 pv = __builtin_nontemporal_load((const f32x4*)(prev + db));
        R.x = 2.0f * R.x - pv.x; R.y = 2.0f * R.y - pv.y;
        R.z = 2.0f * R.z - pv.z; R.w = 2.0f * R.w - pv.w;
    }
    __builtin_nontemporal_store(R, (f32x4*)(dst + db));
}

// ------ mm staging: state+input f32 -> hi/lo bf16 packed LDS ----------------
__device__ __forceinline__ void stage_hilo(const float* __restrict__ xs, const float* __restrict__ xi,
                                           int n, int tid, uint* __restrict__ Bhi, uint* __restrict__ Blo)
{
    for (int i = tid; i < 480; i += 256) {      // zero K-pad words 165..179 per b-row
        int bl = i / 15, t = i - bl * 15;
        Bhi[bl * 180 + 165 + t] = 0u;
        Blo[bl * 180 + 165 + t] = 0u;
    }
    for (int i = tid; i < 2560; i += 256) {     // state: 5 m x 32 bl x 16 quads
        int m = i >> 9, rem = i & 511, bl = rem >> 4, fq = rem & 15;
        const f32x4 v = __builtin_nontemporal_load(
            (const f32x4*)(xs + (size_t)m * SLVL + (size_t)n * SROW + bl * 64 + fq * 4));
        const int base = bl * 180 + m * 33 + 1 + fq * 2;
        Bhi[base]     = pkhi2(v.x, v.y);
        Blo[base]     = pklo2(v.x, v.y);
        Bhi[base + 1] = pkhi2(v.z, v.w);
        Blo[base + 1] = pklo2(v.z, v.w);
    }
    for (int i = tid; i < 160; i += 256) {      // input: 5 m x 32 bl
        int m = i >> 5, bl = i & 31;
        const f32x2 v = __builtin_nontemporal_load(
            (const f32x2*)(xi + (size_t)m * ILVL + (size_t)n * IROW + bl * 2));
        Bhi[bl * 180 + m * 33] = pkhi2(v.x, v.y);
        Blo[bl * 180 + m * 33] = pklo2(v.x, v.y);
    }
}

#define MFMA(a, b, c) __builtin_amdgcn_mfma_f32_16x16x32_bf16(a, b, c, 0, 0, 0)

// ---------------- gconv1 matmul + sigmoid; u->out, r*hx->x0 state -----------
__global__ __launch_bounds__(256, 3) void mm_ru_k(const float* __restrict__ xs, const float* __restrict__ xi,
                                                  const ushort* __restrict__ whi, const ushort* __restrict__ wlo,
                                                  const float* __restrict__ bru, const float* __restrict__ hx,
                                                  float* __restrict__ uout, float* __restrict__ xs0s, int h)
{
    const int n = blockIdx.x;
    const int tid = threadIdx.x;
    const int lane = tid & 63, wave = tid >> 6;
    __shared__ uint Bhi[32 * 180];
    __shared__ uint Blo[32 * 180];

    stage_hilo(xs, xi, n, tid, Bhi, Blo);
    __syncthreads();

    const int ob = wave * 32 + (lane & 15);
    const int ksub = (lane >> 4) * 8;
    const int brow = lane & 15;
    const ushort* BH = (const ushort*)Bhi;
    const ushort* BL = (const ushort*)Blo;
    f32x4 acc[2][2] = {};

    #pragma unroll 2
    for (int ks = 0; ks < KSTEPS; ++ks) {
        const int ko = ks * 32 + ksub;
        short8 Ah0 = *(const short8*)(whi + (size_t)ob * KP + ko);
        short8 Ah1 = *(const short8*)(whi + (size_t)(ob + 16) * KP + ko);
        short8 Al0 = *(const short8*)(wlo + (size_t)ob * KP + ko);
        short8 Al1 = *(const short8*)(wlo + (size_t)(ob + 16) * KP + ko);
        short8 Bh0 = *(const short8*)(BH + brow * 360 + ko);
        short8 Bh1 = *(const short8*)(BH + (16 + brow) * 360 + ko);
        short8 Bl0 = *(const short8*)(BL + brow * 360 + ko);
        short8 Bl1 = *(const short8*)(BL + (16 + brow) * 360 + ko);
        acc[0][0] = MFMA(Ah0, Bh0, acc[0][0]);
        acc[0][1] = MFMA(Ah0, Bh1, acc[0][1]);
        acc[1][0] = MFMA(Ah1, Bh0, acc[1][0]);
        acc[1][1] = MFMA(Ah1, Bh1, acc[1][1]);
        acc[0][0] = MFMA(Ah0, Bl0, acc[0][0]);
        acc[0][1] = MFMA(Ah0, Bl1, acc[0][1]);
        acc[1][0] = MFMA(Ah1, Bl0, acc[1][0]);
        acc[1][1] = MFMA(Ah1, Bl1, acc[1][1]);
        acc[0][0] = MFMA(Al0, Bh0, acc[0][0]);
        acc[0][1] = MFMA(Al0, Bh1, acc[0][1]);
        acc[1][0] = MFMA(Al1, Bh0, acc[1][0]);
        acc[1][1] = MFMA(Al1, Bh1, acc[1][1]);
    }

    const int g = lane >> 4, bcol = lane & 15;
    #pragma unroll
    for (int t = 0; t < 2; ++t) {
        const int o = wave * 32 + t * 16 + g * 4;
        const float bb0 = bru[o], bb1 = bru[o + 1], bb2 = bru[o + 2], bb3 = bru[o + 3];
        #pragma unroll
        for (int bt = 0; bt < 2; ++bt) {
            const int bl = bt * 16 + bcol;
            float s0 = sigm(acc[t][bt][0] + bb0);
            float s1 = sigm(acc[t][bt][1] + bb1);
            float s2 = sigm(acc[t][bt][2] + bb2);
            float s3 = sigm(acc[t][bt][3] + bb3);
            if (o < 64) {   // r-part: r*hx -> x0 state (aligned f32x4)
                const f32x4 hxv = *(const f32x4*)(hx + (size_t)(h * HB + bl) * 262144 + (size_t)n * 64 + o);
                f32x4 rv;
                rv[0] = s0 * hxv[0]; rv[1] = s1 * hxv[1];
                rv[2] = s2 * hxv[2]; rv[3] = s3 * hxv[3];
                *(f32x4*)(xs0s + (size_t)n * SROW + bl * 64 + o) = rv;
            } else {        // u-part -> d_out (temporary storage)
                f32x4 uv = {s0, s1, s2, s3};
                *(f32x4*)(uout + (size_t)(h * HB + bl) * 262144 + (size_t)n * 64 + (o - 64)) = uv;
            }
        }
    }
}

// ---------------- gconv2 matmul + tanh + final GRU combine ------------------
__global__ __launch_bounds__(256, 3) void mm_c_k(const float* __restrict__ xs, const float* __restrict__ xi,
                                                 const ushort* __restrict__ whi, const ushort* __restrict__ wlo,
                                                 const float* __restrict__ bc, const float* __restrict__ hx,
                                                 float* __restrict__ out, int h)
{
    const int n = blockIdx.x;
    const int tid = threadIdx.x;
    const int lane = tid & 63, wave = tid >> 6;
    __shared__ uint Bhi[32 * 180];
    __shared__ uint Blo[32 * 180];

    stage_hilo(xs, xi, n, tid, Bhi, Blo);
    __syncthreads();

    const int ob = wave * 16 + (lane & 15);
    const int ksub = (lane >> 4) * 8;
    const int brow = lane & 15;
    const ushort* BH = (const ushort*)Bhi;
    const ushort* BL = (const ushort*)Blo;
    f32x4 acc[2] = {};

    #pragma unroll 2
    for (int ks = 0; ks < KSTEPS; ++ks) {
        const int ko = ks * 32 + ksub;
        short8 Ah = *(const short8*)(whi + (size_t)ob * KP + ko);
        short8 Al = *(const short8*)(wlo + (size_t)ob * KP + ko);
        short8 Bh0 = *(const short8*)(BH + brow * 360 + ko);
        short8 Bh1 = *(const short8*)(BH + (16 + brow) * 360 + ko);
        short8 Bl0 = *(const short8*)(BL + brow * 360 + ko);
        short8 Bl1 = *(const short8*)(BL + (16 + brow) * 360 + ko);
        acc[0] = MFMA(Ah, Bh0, acc[0]);
        acc[1] = MFMA(Ah, Bh1, acc[1]);
        acc[0] = MFMA(Ah, Bl0, acc[0]);
        acc[1] = MFMA(Ah, Bl1, acc[1]);
        acc[0] = MFMA(Al, Bh0, acc[0]);
        acc[1] = MFMA(Al, Bh1, acc[1]);
    }

    const int g = lane >> 4, bcol = lane & 15;
    const int o = wave * 16 + g * 4;
    const float bb0 = bc[o], bb1 = bc[o + 1], bb2 = bc[o + 2], bb3 = bc[o + 3];
    #pragma unroll
    for (int bt = 0; bt < 2; ++bt) {
        const int bl = bt * 16 + bcol;
        float c0 = tanh_fast(acc[bt][0] + bb0);
        float c1 = tanh_fast(acc[bt][1] + bb1);
        float c2 = tanh_fast(acc[bt][2] + bb2);
        float c3 = tanh_fast(acc[bt][3] + bb3);
        float* p = out + (size_t)(h * HB + bl) * 262144 + (size_t)n * 64 + o;
        const f32x4 hxv = *(const f32x4*)(hx + (size_t)(h * HB + bl) * 262144 + (size_t)n * 64 + o);
        f32x4 uv = *(const f32x4*)p;
        f32x4 ov;
        ov[0] = uv[0] * hxv[0] + (1.0f - uv[0]) * c0;
        ov[1] = uv[1] * hxv[1] + (1.0f - uv[1]) * c1;
        ov[2] = uv[2] * hxv[2] + (1.0f - uv[2]) * c2;
        ov[3] = uv[3] * hxv[3] + (1.0f - uv[3]) * c3;
        *(f32x4*)p = ov;
    }
}

// ---------------------------------------------------------------------------
extern "C" void kernel_launch(void* const* d_in, const int* in_sizes, int n_in,
                              void* d_out, int out_size, void* d_ws, size_t ws_size,
                              hipStream_t stream)
{
    (void)in_sizes; (void)n_in; (void)out_size; (void)ws_size;
    const float* inputs  = (const float*)d_in[0];
    const float* hx      = (const float*)d_in[1];
    const int*   sup_rows= (const int*)d_in[2];
    const int*   sup_cols= (const int*)d_in[3];
    const float* sup_vals= (const float*)d_in[4];
    const float* W_ru    = (const float*)d_in[5];
    const float* b_ru    = (const float*)d_in[6];
    const float* W_c     = (const float*)d_in[7];
    const float* b_c     = (const float*)d_in[8];
    float* out = (float*)d_out;

    char* ws = (char*)d_ws;
    float* xs = (float*)ws;                                 // 5 state levels: 167.8 MB
    float* xi = xs + 5ull * SLVL;                           // 5 input levels: 5.2 MB
    size_t off = (5ull * SLVL + 5ull * ILVL) * 4ull;        // 173,015,040
    ushort* wru_hi = (ushort*)(ws + off); off += 90112;
    ushort* wru_lo = (ushort*)(ws + off); off += 90112;
    ushort* wc_hi  = (ushort*)(ws + off); off += 45056;
    ushort* wc_lo  = (ushort*)(ws + off); off += 45056;
    int* row_ptr   = (int*)(ws + off);    off += 32800;
    int* cntfill   = (int*)(ws + off);    off += 65536;
    int2* pcv      = (int2*)(ws + off);   off += 1048576;   // packed (col,val) CSR

    #define XS(m) (xs + (size_t)(m) * SLVL)
    #define XI(m) (xi + (size_t)(m) * ILVL)
    int* fill = cntfill + 8192;

    zero_k<<<64, 256, 0, stream>>>(cntfill);
    wtbuild_k<<<264, 256, 0, stream>>>(W_ru, W_c, wru_hi, wru_lo, wc_hi, wc_lo);
    count_k<<<512, 256, 0, stream>>>(sup_rows, cntfill);
    scan_k<<<2, 1024, 0, stream>>>(cntfill, row_ptr);
    scatter_k<<<512, 256, 0, stream>>>(sup_rows, sup_cols, sup_vals, row_ptr, fill, pcv);

    for (int h = 0; h < 2; ++h) {
        x0s_k<<<8192, 256, 0, stream>>>(hx, XS(0), h);
        x0i_k<<<512, 256, 0, stream>>>(inputs, XI(0), h);
        // gconv1 diffusion
        spmm_k<<<dim3(8448, 2), 256, 0, stream>>>(XS(0), XI(0), XS(0), XI(0),
                                                  XS(1), XI(1), XS(3), XI(3),
                                                  XS(0), XI(0), row_ptr, pcv, 0, 0);
        spmm_k<<<dim3(8448, 1), 256, 0, stream>>>(XS(1), XI(1), XS(1), XI(1),
                                                  XS(2), XI(2), XS(2), XI(2),
                                                  XS(0), XI(0), row_ptr, pcv, 1, 0);
        spmm_k<<<dim3(8448, 1), 256, 0, stream>>>(XS(3), XI(3), XS(3), XI(3),
                                                  XS(4), XI(4), XS(4), XI(4),
                                                  XS(0), XI(0), row_ptr, pcv, 1, 1);
        // gconv1 matmul: u -> out, r*hx -> x0 state part (input part reused)
        mm_ru_k<<<NN, 256, 0, stream>>>(xs, xi, wru_hi, wru_lo, b_ru, hx, out, XS(0), h);
        // gconv2 diffusion (x0 = [inputs, r*hx])
        spmm_k<<<dim3(8448, 2), 256, 0, stream>>>(XS(0), XI(0), XS(0), XI(0),
                                                  XS(1), XI(1), XS(3), XI(3),
                                                  XS(0), XI(0), row_ptr, pcv, 0, 0);
        spmm_k<<<dim3(8448, 1), 256, 0, stream>>>(XS(1), XI(1), XS(1), XI(1),
                                                  XS(2), XI(2), XS(2), XI(2),
                                                  XS(0), XI(0), row_ptr, pcv, 1, 0);
        spmm_k<<<dim3(8448, 1), 256, 0, stream>>>(XS(3), XI(3), XS(3), XI(3),
                                                  XS(4), XI(4), XS(4), XI(4),
                                                  XS(0), XI(0), row_ptr, pcv, 1, 1);
        // gconv2 matmul + tanh + final GRU combine
        mm_c_k<<<NN, 256, 0, stream>>>(xs, xi, wc_hi, wc_lo, b_c, hx, out, h);
    }
    #undef XS
    #undef XI
}

// Round 8
// 974.379 us; speedup vs baseline: 1.8926x; 1.0924x over previous
//
#include <hip/hip_runtime.h>

typedef float f32x4 __attribute__((ext_vector_type(4)));
typedef float f32x2 __attribute__((ext_vector_type(2)));
typedef short short8 __attribute__((ext_vector_type(8)));

#define NN 4096
#define HB 32               // half batch
#define SROW 2048           // state f32 per node row (32 b x 64 f), 1<<11
#define IROW 64             // input f32 per node row (32 b x 2 f), 1<<6
#define SLVL 8388608ull     // f32 per state level (NN*SROW)
#define ILVL 262144ull      // f32 per input level (NN*IROW)
#define KP 352              // padded K (330 real)
#define KSTEPS 11

__device__ __forceinline__ ushort f2bf(float f){ uint i = __float_as_uint(f); return (ushort)((i + 0x7fffu + ((i >> 16) & 1u)) >> 16); }
__device__ __forceinline__ float bf2f(ushort u){ return __uint_as_float((uint)u << 16); }
__device__ __forceinline__ uint pkhi2(float a, float b){ return (uint)f2bf(a) | ((uint)f2bf(b) << 16); }
__device__ __forceinline__ uint pklo2(float a, float b){
    ushort ha = f2bf(a), hb = f2bf(b);
    return (uint)f2bf(a - bf2f(ha)) | ((uint)f2bf(b - bf2f(hb)) << 16);
}
__device__ __forceinline__ float sigm(float x){ return 1.0f / (1.0f + __expf(-x)); }
__device__ __forceinline__ float tanh_fast(float x){
    x = fminf(20.0f, fmaxf(-20.0f, x));
    float t = __expf(-2.0f * x);
    return (1.0f - t) / (1.0f + t);
}
__device__ __forceinline__ f32x4 fma4(float v, f32x4 x, f32x4 a){
    a.x = fmaf(v, x.x, a.x); a.y = fmaf(v, x.y, a.y);
    a.z = fmaf(v, x.z, a.z); a.w = fmaf(v, x.w, a.w);
    return a;
}

// ---------------- zero scratch (cnt+fill), graph-capture-safe ---------------
__global__ void zero_k(int* __restrict__ p){ p[blockIdx.x * 256 + threadIdx.x] = 0; }

// ------- weight transform: Wt_hi/lo[o][k], k = m*66+f, bf16 hi/lo split -----
__global__ void wtbuild_k(const float* __restrict__ Wru, const float* __restrict__ Wc,
                          ushort* __restrict__ ru_hi, ushort* __restrict__ ru_lo,
                          ushort* __restrict__ c_hi,  ushort* __restrict__ c_lo)
{
    int idx = blockIdx.x * 256 + threadIdx.x;   // 192*352 exact
    float w = 0.0f;
    if (idx < 128 * KP) {
        int o = idx / KP, k = idx - o * KP;
        if (k < 330) { int m = k / 66, f = k - m * 66; w = Wru[(size_t)(f * 5 + m) * 128 + o]; }
        ushort hi = f2bf(w);
        ushort lo = f2bf(w - bf2f(hi));
        ru_hi[(size_t)o * KP + k] = hi;
        ru_lo[(size_t)o * KP + k] = lo;
    } else {
        int j = idx - 128 * KP;
        int o = j / KP, k = j - o * KP;
        if (k < 330) { int m = k / 66, f = k - m * 66; w = Wc[(size_t)(f * 5 + m) * 64 + o]; }
        ushort hi = f2bf(w);
        ushort lo = f2bf(w - bf2f(hi));
        c_hi[(size_t)o * KP + k] = hi;
        c_lo[(size_t)o * KP + k] = lo;
    }
}

// ---------------- CSR build ------------------------------------------------
__global__ void count_k(const int* __restrict__ rows, int* __restrict__ cnt)
{
    int i = blockIdx.x * 256 + threadIdx.x;     // 2*65536 exact
    int s = i >> 16;
    atomicAdd(&cnt[(s << 12) + rows[i]], 1);
}

__global__ __launch_bounds__(1024) void scan_k(const int* __restrict__ cnt, int* __restrict__ rp)
{
    int s = blockIdx.x;
    const int* c = cnt + (s << 12);
    int* r = rp + s * 4097;
    __shared__ int sd[1024];
    int tid = threadIdx.x;
    int i0 = tid * 4;
    int a0 = c[i0], a1 = c[i0 + 1], a2 = c[i0 + 2], a3 = c[i0 + 3];
    sd[tid] = a0 + a1 + a2 + a3;
    __syncthreads();
    for (int off = 1; off < 1024; off <<= 1) {
        int v = (tid >= off) ? sd[tid - off] : 0;
        __syncthreads();
        sd[tid] += v;
        __syncthreads();
    }
    int base = tid ? sd[tid - 1] : 0;
    r[i0] = base; r[i0 + 1] = base + a0; r[i0 + 2] = base + a0 + a1; r[i0 + 3] = base + a0 + a1 + a2;
    if (tid == 1023) r[4096] = sd[1023];
}

// scatter into packed (col, val) CSR stream
__global__ void scatter_k(const int* __restrict__ rows, const int* __restrict__ cols,
                          const float* __restrict__ vals, const int* __restrict__ rp,
                          int* __restrict__ fill, int2* __restrict__ pcv)
{
    int i = blockIdx.x * 256 + threadIdx.x;     // 2*65536 exact
    int s = i >> 16;
    int r = rows[i];
    int pos = rp[s * 4097 + r] + atomicAdd(&fill[(s << 12) + r], 1);
    int2 e; e.x = cols[i]; e.y = __float_as_int(vals[i]);
    pcv[(s << 16) + pos] = e;
}

// ---------------- x0 build: state part (transpose hx) -----------------------
__global__ void x0s_k(const float* __restrict__ hx, float* __restrict__ x0s, int h)
{
    int i = blockIdx.x * 256 + threadIdx.x;     // 4096*512 quads exact
    int n = i >> 9, ql = i & 511;
    int bl = ql >> 4, fq = ql & 15;
    const f32x4 v = *(const f32x4*)(hx + (size_t)(h * HB + bl) * 262144 + (size_t)n * 64 + fq * 4);
    __builtin_nontemporal_store(v, (f32x4*)(x0s + (size_t)n * SROW + bl * 64 + fq * 4));
}

// ---------------- x0 build: input part --------------------------------------
__global__ void x0i_k(const float* __restrict__ in, float* __restrict__ x0i, int h)
{
    int i = blockIdx.x * 256 + threadIdx.x;     // 4096*32 exact
    int n = i >> 5, bl = i & 31;
    const f32x2 v = *(const f32x2*)(in + (size_t)(h * HB + bl) * 8192 + n * 2);
    __builtin_nontemporal_store(v, (f32x2*)(x0i + (size_t)n * IROW + bl * 2));
}

// ---------------- SpMM v5: LDS edge staging + 8-gather unroll ----------------
// mode 0 (step1, cheb=0): grid (8448, 2); sup = blockIdx.y.
//   main b<8192: [j:10][xcd:3], j=[phase:1][rowgrp:9], sub = xcd*2+phase.
//   input b>=8192: 256 blocks, 16 rows each.
// mode 1 (step2, cheb=1): grid (16896, 1).
//   main b<16384: phase = b>>12 (0..3): s = phase>>1, sub = xcd*2+(phase&1).
//   input b>=16384: 512 blocks: s = j>>8, 16 rows each.
// Per-phase XCD slice = 2 MB ~ L2. Edges staged in LDS (block rows contiguous).
__global__ __launch_bounds__(256) void spmm_k(
    const float* __restrict__ ss0, const float* __restrict__ si0,
    const float* __restrict__ ss1, const float* __restrict__ si1,
    float* __restrict__ ds0, float* __restrict__ di0,
    float* __restrict__ ds1, float* __restrict__ di1,
    const float* __restrict__ ps, const float* __restrict__ pi,
    const int* __restrict__ rp, const int2* __restrict__ pcv,
    int mode)
{
    __shared__ int2 eds[768];
    __shared__ int srp[17];
    const int b = blockIdx.x;
    const int tid = threadIdx.x;
    int s, sub = 0, rowgrp, lrow, o_, rsh, nrows;
    bool is_main;
    if (mode == 0) {
        s = blockIdx.y;
        if (b < 8192) {
            is_main = true;
            const int j = b >> 3;
            sub = (b & 7) * 2 + (j >> 9);
            rowgrp = j & 511;
        } else {
            is_main = false;
            rowgrp = b - 8192;
        }
    } else {
        if (b < 16384) {
            is_main = true;
            const int phase = b >> 12;
            s = phase >> 1;
            sub = (b & 7) * 2 + (phase & 1);
            rowgrp = (b >> 3) & 511;
        } else {
            is_main = false;
            const int j2 = b - 16384;
            s = j2 >> 8;
            rowgrp = j2 & 255;
        }
    }
    const float* __restrict__ x;
    float* __restrict__ dst;
    const float* __restrict__ prev;
    int R0;
    if (is_main) {
        nrows = 8; R0 = rowgrp * 8;
        lrow = ((tid >> 6) << 1) | ((tid >> 5) & 1);
        o_ = (sub * 32 + (tid & 31)) * 4;
        rsh = 11;
        x = s ? ss1 : ss0; dst = s ? ds1 : ds0; prev = ps;
    } else {
        nrows = 16; R0 = rowgrp * 16;
        lrow = ((tid >> 6) << 2) | ((tid >> 4) & 3);
        o_ = (tid & 15) * 4;
        rsh = 6;
        x = s ? si1 : si0; dst = s ? di1 : di0; prev = pi;
    }
    if (tid <= nrows) srp[tid] = rp[s * 4097 + R0 + tid];
    __syncthreads();
    const int ebase = srp[0];
    const int etot = srp[nrows] - ebase;
    for (int i = tid; i < etot; i += 256) eds[i] = pcv[(s << 16) + ebase + i];
    __syncthreads();
    const int p0 = srp[lrow] - ebase;
    const int cnt = srp[lrow + 1] - srp[lrow];

    f32x4 a0 = {0,0,0,0}, a1 = {0,0,0,0}, a2 = {0,0,0,0}, a3 = {0,0,0,0};
    int e = 0;
    for (; e + 8 <= cnt; e += 8) {
        const int2 E0 = eds[p0+e+0], E1 = eds[p0+e+1], E2 = eds[p0+e+2], E3 = eds[p0+e+3];
        const int2 E4 = eds[p0+e+4], E5 = eds[p0+e+5], E6 = eds[p0+e+6], E7 = eds[p0+e+7];
        const f32x4 x0v = *(const f32x4*)(x + ((size_t)E0.x << rsh) + o_);
        const f32x4 x1v = *(const f32x4*)(x + ((size_t)E1.x << rsh) + o_);
        const f32x4 x2v = *(const f32x4*)(x + ((size_t)E2.x << rsh) + o_);
        const f32x4 x3v = *(const f32x4*)(x + ((size_t)E3.x << rsh) + o_);
        const f32x4 x4v = *(const f32x4*)(x + ((size_t)E4.x << rsh) + o_);
        const f32x4 x5v = *(const f32x4*)(x + ((size_t)E5.x << rsh) + o_);
        const f32x4 x6v = *(const f32x4*)(x + ((size_t)E6.x << rsh) + o_);
        const f32x4 x7v = *(const f32x4*)(x + ((size_t)E7.x << rsh) + o_);
        a0 = fma4(__int_as_float(E0.y), x0v, a0);
        a1 = fma4(__int_as_float(E1.y), x1v, a1);
        a2 = fma4(__int_as_float(E2.y), x2v, a2);
        a3 = fma4(__int_as_float(E3.y), x3v, a3);
        a0 = fma4(__int_as_float(E4.y), x4v, a0);
        a1 = fma4(__int_as_float(E5.y), x5v, a1);
        a2 = fma4(__int_as_float(E6.y), x6v, a2);
        a3 = fma4(__int_as_float(E7.y), x7v, a3);
    }
    for (; e + 2 <= cnt; e += 2) {
        const int2 E0 = eds[p0+e], E1 = eds[p0+e+1];
        const f32x4 x0v = *(const f32x4*)(x + ((size_t)E0.x << rsh) + o_);
        const f32x4 x1v = *(const f32x4*)(x + ((size_t)E1.x << rsh) + o_);
        a0 = fma4(__int_as_float(E0.y), x0v, a0);
        a1 = fma4(__int_as_float(E1.y), x1v, a1);
    }
    if (e < cnt) {
        const int2 E0 = eds[p0+e];
        const f32x4 x0v = *(const f32x4*)(x + ((size_t)E0.x << rsh) + o_);
        a0 = fma4(__int_as_float(E0.y), x0v, a0);
    }
    f32x4 R;
    R.x = (a0.x + a1.x) + (a2.x + a3.x);
    R.y = (a0.y + a1.y) + (a2.y + a3.y);
    R.z = (a0.z + a1.z) + (a2.z + a3.z);
    R.w = (a0.w + a1.w) + (a2.w + a3.w);

    const size_t db = ((size_t)(R0 + lrow) << rsh) + o_;
    if (mode) {
        const f32x4 pv = __builtin_nontemporal_load((const f32x4*)(prev + db));
        R.x = 2.0f * R.x - pv.x; R.y = 2.0f * R.y - pv.y;
        R.z = 2.0f * R.z - pv.z; R.w = 2.0f * R.w - pv.w;
    }
    __builtin_nontemporal_store(R, (f32x4*)(dst + db));
}

// ------ mm staging: state+input f32 -> hi/lo bf16 packed LDS ----------------
__device__ __forceinline__ void stage_hilo(const float* __restrict__ xs, const float* __restrict__ xi,
                                           int n, int tid, uint* __restrict__ Bhi, uint* __restrict__ Blo)
{
    for (int i = tid; i < 480; i += 256) {      // zero K-pad words 165..179 per b-row
        int bl = i / 15, t = i - bl * 15;
        Bhi[bl * 180 + 165 + t] = 0u;
        Blo[bl * 180 + 165 + t] = 0u;
    }
    for (int i = tid; i < 2560; i += 256) {     // state: 5 m x 32 bl x 16 quads
        int m = i >> 9, rem = i & 511, bl = rem >> 4, fq = rem & 15;
        const f32x4 v = __builtin_nontemporal_load(
            (const f32x4*)(xs + (size_t)m * SLVL + (size_t)n * SROW + bl * 64 + fq * 4));
        const int base = bl * 180 + m * 33 + 1 + fq * 2;
        Bhi[base]     = pkhi2(v.x, v.y);
        Blo[base]     = pklo2(v.x, v.y);
        Bhi[base + 1] = pkhi2(v.z, v.w);
        Blo[base + 1] = pklo2(v.z, v.w);
    }
    for (int i = tid; i < 160; i += 256) {      // input: 5 m x 32 bl
        int m = i >> 5, bl = i & 31;
        const f32x2 v = __builtin_nontemporal_load(
            (const f32x2*)(xi + (size_t)m * ILVL + (size_t)n * IROW + bl * 2));
        Bhi[bl * 180 + m * 33] = pkhi2(v.x, v.y);
        Blo[bl * 180 + m * 33] = pklo2(v.x, v.y);
    }
}

#define MFMA(a, b, c) __builtin_amdgcn_mfma_f32_16x16x32_bf16(a, b, c, 0, 0, 0)

// ---------------- gconv1 matmul + sigmoid; u->out, r*hx->x0 state -----------
__global__ __launch_bounds__(256, 3) void mm_ru_k(const float* __restrict__ xs, const float* __restrict__ xi,
                                                  const ushort* __restrict__ whi, const ushort* __restrict__ wlo,
                                                  const float* __restrict__ bru, const float* __restrict__ hx,
                                                  float* __restrict__ uout, float* __restrict__ xs0s, int h)
{
    const int n = blockIdx.x;
    const int tid = threadIdx.x;
    const int lane = tid & 63, wave = tid >> 6;
    __shared__ uint Bhi[32 * 180];
    __shared__ uint Blo[32 * 180];

    stage_hilo(xs, xi, n, tid, Bhi, Blo);
    __syncthreads();

    const int ob = wave * 32 + (lane & 15);
    const int ksub = (lane >> 4) * 8;
    const int brow = lane & 15;
    const ushort* BH = (const ushort*)Bhi;
    const ushort* BL = (const ushort*)Blo;
    f32x4 acc[2][2] = {};

    #pragma unroll
    for (int ks = 0; ks < KSTEPS; ++ks) {
        const int ko = ks * 32 + ksub;
        short8 Ah0 = *(const short8*)(whi + (size_t)ob * KP + ko);
        short8 Ah1 = *(const short8*)(whi + (size_t)(ob + 16) * KP + ko);
        short8 Al0 = *(const short8*)(wlo + (size_t)ob * KP + ko);
        short8 Al1 = *(const short8*)(wlo + (size_t)(ob + 16) * KP + ko);
        short8 Bh0 = *(const short8*)(BH + brow * 360 + ko);
        short8 Bh1 = *(const short8*)(BH + (16 + brow) * 360 + ko);
        short8 Bl0 = *(const short8*)(BL + brow * 360 + ko);
        short8 Bl1 = *(const short8*)(BL + (16 + brow) * 360 + ko);
        acc[0][0] = MFMA(Ah0, Bh0, acc[0][0]);
        acc[0][1] = MFMA(Ah0, Bh1, acc[0][1]);
        acc[1][0] = MFMA(Ah1, Bh0, acc[1][0]);
        acc[1][1] = MFMA(Ah1, Bh1, acc[1][1]);
        acc[0][0] = MFMA(Ah0, Bl0, acc[0][0]);
        acc[0][1] = MFMA(Ah0, Bl1, acc[0][1]);
        acc[1][0] = MFMA(Ah1, Bl0, acc[1][0]);
        acc[1][1] = MFMA(Ah1, Bl1, acc[1][1]);
        acc[0][0] = MFMA(Al0, Bh0, acc[0][0]);
        acc[0][1] = MFMA(Al0, Bh1, acc[0][1]);
        acc[1][0] = MFMA(Al1, Bh0, acc[1][0]);
        acc[1][1] = MFMA(Al1, Bh1, acc[1][1]);
    }

    const int g = lane >> 4, bcol = lane & 15;
    #pragma unroll
    for (int t = 0; t < 2; ++t) {
        const int o = wave * 32 + t * 16 + g * 4;
        const float bb0 = bru[o], bb1 = bru[o + 1], bb2 = bru[o + 2], bb3 = bru[o + 3];
        #pragma unroll
        for (int bt = 0; bt < 2; ++bt) {
            const int bl = bt * 16 + bcol;
            float s0 = sigm(acc[t][bt][0] + bb0);
            float s1 = sigm(acc[t][bt][1] + bb1);
            float s2 = sigm(acc[t][bt][2] + bb2);
            float s3 = sigm(acc[t][bt][3] + bb3);
            if (o < 64) {   // r-part: r*hx -> x0 state (aligned f32x4)
                const f32x4 hxv = *(const f32x4*)(hx + (size_t)(h * HB + bl) * 262144 + (size_t)n * 64 + o);
                f32x4 rv;
                rv[0] = s0 * hxv[0]; rv[1] = s1 * hxv[1];
                rv[2] = s2 * hxv[2]; rv[3] = s3 * hxv[3];
                *(f32x4*)(xs0s + (size_t)n * SROW + bl * 64 + o) = rv;
            } else {        // u-part -> d_out (temporary storage)
                f32x4 uv = {s0, s1, s2, s3};
                *(f32x4*)(uout + (size_t)(h * HB + bl) * 262144 + (size_t)n * 64 + (o - 64)) = uv;
            }
        }
    }
}

// ---------------- gconv2 matmul + tanh + final GRU combine ------------------
__global__ __launch_bounds__(256, 3) void mm_c_k(const float* __restrict__ xs, const float* __restrict__ xi,
                                                 const ushort* __restrict__ whi, const ushort* __restrict__ wlo,
                                                 const float* __restrict__ bc, const float* __restrict__ hx,
                                                 float* __restrict__ out, int h)
{
    const int n = blockIdx.x;
    const int tid = threadIdx.x;
    const int lane = tid & 63, wave = tid >> 6;
    __shared__ uint Bhi[32 * 180];
    __shared__ uint Blo[32 * 180];

    stage_hilo(xs, xi, n, tid, Bhi, Blo);
    __syncthreads();

    const int ob = wave * 16 + (lane & 15);
    const int ksub = (lane >> 4) * 8;
    const int brow = lane & 15;
    const ushort* BH = (const ushort*)Bhi;
    const ushort* BL = (const ushort*)Blo;
    f32x4 acc[2] = {};

    #pragma unroll
    for (int ks = 0; ks < KSTEPS; ++ks) {
        const int ko = ks * 32 + ksub;
        short8 Ah = *(const short8*)(whi + (size_t)ob * KP + ko);
        short8 Al = *(const short8*)(wlo + (size_t)ob * KP + ko);
        short8 Bh0 = *(const short8*)(BH + brow * 360 + ko);
        short8 Bh1 = *(const short8*)(BH + (16 + brow) * 360 + ko);
        short8 Bl0 = *(const short8*)(BL + brow * 360 + ko);
        short8 Bl1 = *(const short8*)(BL + (16 + brow) * 360 + ko);
        acc[0] = MFMA(Ah, Bh0, acc[0]);
        acc[1] = MFMA(Ah, Bh1, acc[1]);
        acc[0] = MFMA(Ah, Bl0, acc[0]);
        acc[1] = MFMA(Ah, Bl1, acc[1]);
        acc[0] = MFMA(Al, Bh0, acc[0]);
        acc[1] = MFMA(Al, Bh1, acc[1]);
    }

    const int g = lane >> 4, bcol = lane & 15;
    const int o = wave * 16 + g * 4;
    const float bb0 = bc[o], bb1 = bc[o + 1], bb2 = bc[o + 2], bb3 = bc[o + 3];
    #pragma unroll
    for (int bt = 0; bt < 2; ++bt) {
        const int bl = bt * 16 + bcol;
        float c0 = tanh_fast(acc[bt][0] + bb0);
        float c1 = tanh_fast(acc[bt][1] + bb1);
        float c2 = tanh_fast(acc[bt][2] + bb2);
        float c3 = tanh_fast(acc[bt][3] + bb3);
        float* p = out + (size_t)(h * HB + bl) * 262144 + (size_t)n * 64 + o;
        const f32x4 hxv = *(const f32x4*)(hx + (size_t)(h * HB + bl) * 262144 + (size_t)n * 64 + o);
        f32x4 uv = *(const f32x4*)p;
        f32x4 ov;
        ov[0] = uv[0] * hxv[0] + (1.0f - uv[0]) * c0;
        ov[1] = uv[1] * hxv[1] + (1.0f - uv[1]) * c1;
        ov[2] = uv[2] * hxv[2] + (1.0f - uv[2]) * c2;
        ov[3] = uv[3] * hxv[3] + (1.0f - uv[3]) * c3;
        *(f32x4*)p = ov;
    }
}

// ---------------------------------------------------------------------------
extern "C" void kernel_launch(void* const* d_in, const int* in_sizes, int n_in,
                              void* d_out, int out_size, void* d_ws, size_t ws_size,
                              hipStream_t stream)
{
    (void)in_sizes; (void)n_in; (void)out_size; (void)ws_size;
    const float* inputs  = (const float*)d_in[0];
    const float* hx      = (const float*)d_in[1];
    const int*   sup_rows= (const int*)d_in[2];
    const int*   sup_cols= (const int*)d_in[3];
    const float* sup_vals= (const float*)d_in[4];
    const float* W_ru    = (const float*)d_in[5];
    const float* b_ru    = (const float*)d_in[6];
    const float* W_c     = (const float*)d_in[7];
    const float* b_c     = (const float*)d_in[8];
    float* out = (float*)d_out;

    char* ws = (char*)d_ws;
    float* xs = (float*)ws;                                 // 5 state levels: 167.8 MB
    float* xi = xs + 5ull * SLVL;                           // 5 input levels: 5.2 MB
    size_t off = (5ull * SLVL + 5ull * ILVL) * 4ull;        // 173,015,040
    ushort* wru_hi = (ushort*)(ws + off); off += 90112;
    ushort* wru_lo = (ushort*)(ws + off); off += 90112;
    ushort* wc_hi  = (ushort*)(ws + off); off += 45056;
    ushort* wc_lo  = (ushort*)(ws + off); off += 45056;
    int* row_ptr   = (int*)(ws + off);    off += 32800;
    int* cntfill   = (int*)(ws + off);    off += 65536;
    int2* pcv      = (int2*)(ws + off);   off += 1048576;   // packed (col,val) CSR

    #define XS(m) (xs + (size_t)(m) * SLVL)
    #define XI(m) (xi + (size_t)(m) * ILVL)
    int* fill = cntfill + 8192;

    zero_k<<<64, 256, 0, stream>>>(cntfill);
    wtbuild_k<<<264, 256, 0, stream>>>(W_ru, W_c, wru_hi, wru_lo, wc_hi, wc_lo);
    count_k<<<512, 256, 0, stream>>>(sup_rows, cntfill);
    scan_k<<<2, 1024, 0, stream>>>(cntfill, row_ptr);
    scatter_k<<<512, 256, 0, stream>>>(sup_rows, sup_cols, sup_vals, row_ptr, fill, pcv);

    for (int h = 0; h < 2; ++h) {
        x0s_k<<<8192, 256, 0, stream>>>(hx, XS(0), h);
        x0i_k<<<512, 256, 0, stream>>>(inputs, XI(0), h);
        // gconv1 diffusion: step1 (both sups read x0), step2 merged 4-phase
        spmm_k<<<dim3(8448, 2), 256, 0, stream>>>(XS(0), XI(0), XS(0), XI(0),
                                                  XS(1), XI(1), XS(3), XI(3),
                                                  XS(0), XI(0), row_ptr, pcv, 0);
        spmm_k<<<dim3(16896, 1), 256, 0, stream>>>(XS(1), XI(1), XS(3), XI(3),
                                                   XS(2), XI(2), XS(4), XI(4),
                                                   XS(0), XI(0), row_ptr, pcv, 1);
        // gconv1 matmul: u -> out, r*hx -> x0 state part (input part reused)
        mm_ru_k<<<NN, 256, 0, stream>>>(xs, xi, wru_hi, wru_lo, b_ru, hx, out, XS(0), h);
        // gconv2 diffusion (x0 = [inputs, r*hx])
        spmm_k<<<dim3(8448, 2), 256, 0, stream>>>(XS(0), XI(0), XS(0), XI(0),
                                                  XS(1), XI(1), XS(3), XI(3),
                                                  XS(0), XI(0), row_ptr, pcv, 0);
        spmm_k<<<dim3(16896, 1), 256, 0, stream>>>(XS(1), XI(1), XS(3), XI(3),
                                                   XS(2), XI(2), XS(4), XI(4),
                                                   XS(0), XI(0), row_ptr, pcv, 1);
        // gconv2 matmul + tanh + final GRU combine
        mm_c_k<<<NN, 256, 0, stream>>>(xs, xi, wc_hi, wc_lo, b_c, hx, out, h);
    }
    #undef XS
    #undef XI
}

// Round 9
// 914.194 us; speedup vs baseline: 2.0172x; 1.0658x over previous
//
#include <hip/hip_runtime.h>

typedef float f32x4 __attribute__((ext_vector_type(4)));
typedef float f32x2 __attribute__((ext_vector_type(2)));
typedef short short8 __attribute__((ext_vector_type(8)));

#define NN 4096
#define HB 32               // half batch
#define SROW 2048           // state f32 per node row (32 b x 64 f), 1<<11
#define IROW 64             // input f32 per node row (32 b x 2 f), 1<<6
#define SLVL 8388608ull     // f32 per state level (NN*SROW)
#define ILVL 262144ull      // f32 per input level (NN*IROW)
#define KP 352              // padded K (330 real)
#define KSTEPS 11

__device__ __forceinline__ ushort f2bf(float f){ uint i = __float_as_uint(f); return (ushort)((i + 0x7fffu + ((i >> 16) & 1u)) >> 16); }
__device__ __forceinline__ float bf2f(ushort u){ return __uint_as_float((uint)u << 16); }
__device__ __forceinline__ uint pkhi2(float a, float b){ return (uint)f2bf(a) | ((uint)f2bf(b) << 16); }
__device__ __forceinline__ float sigm(float x){ return 1.0f / (1.0f + __expf(-x)); }
__device__ __forceinline__ float tanh_fast(float x){
    x = fminf(20.0f, fmaxf(-20.0f, x));
    float t = __expf(-2.0f * x);
    return (1.0f - t) / (1.0f + t);
}
__device__ __forceinline__ f32x4 fma4(float v, f32x4 x, f32x4 a){
    a.x = fmaf(v, x.x, a.x); a.y = fmaf(v, x.y, a.y);
    a.z = fmaf(v, x.z, a.z); a.w = fmaf(v, x.w, a.w);
    return a;
}

// ---------------- zero scratch (cnt+fill), graph-capture-safe ---------------
__global__ void zero_k(int* __restrict__ p){ p[blockIdx.x * 256 + threadIdx.x] = 0; }

// ------- weight transform: Wt_hi/lo[o][k], k = m*66+f, bf16 hi/lo split -----
__global__ void wtbuild_k(const float* __restrict__ Wru, const float* __restrict__ Wc,
                          ushort* __restrict__ ru_hi, ushort* __restrict__ ru_lo,
                          ushort* __restrict__ c_hi,  ushort* __restrict__ c_lo)
{
    int idx = blockIdx.x * 256 + threadIdx.x;   // 192*352 exact
    float w = 0.0f;
    if (idx < 128 * KP) {
        int o = idx / KP, k = idx - o * KP;
        if (k < 330) { int m = k / 66, f = k - m * 66; w = Wru[(size_t)(f * 5 + m) * 128 + o]; }
        ushort hi = f2bf(w);
        ushort lo = f2bf(w - bf2f(hi));
        ru_hi[(size_t)o * KP + k] = hi;
        ru_lo[(size_t)o * KP + k] = lo;
    } else {
        int j = idx - 128 * KP;
        int o = j / KP, k = j - o * KP;
        if (k < 330) { int m = k / 66, f = k - m * 66; w = Wc[(size_t)(f * 5 + m) * 64 + o]; }
        ushort hi = f2bf(w);
        ushort lo = f2bf(w - bf2f(hi));
        c_hi[(size_t)o * KP + k] = hi;
        c_lo[(size_t)o * KP + k] = lo;
    }
}

// ---------------- CSR build ------------------------------------------------
__global__ void count_k(const int* __restrict__ rows, int* __restrict__ cnt)
{
    int i = blockIdx.x * 256 + threadIdx.x;     // 2*65536 exact
    int s = i >> 16;
    atomicAdd(&cnt[(s << 12) + rows[i]], 1);
}

__global__ __launch_bounds__(1024) void scan_k(const int* __restrict__ cnt, int* __restrict__ rp)
{
    int s = blockIdx.x;
    const int* c = cnt + (s << 12);
    int* r = rp + s * 4097;
    __shared__ int sd[1024];
    int tid = threadIdx.x;
    int i0 = tid * 4;
    int a0 = c[i0], a1 = c[i0 + 1], a2 = c[i0 + 2], a3 = c[i0 + 3];
    sd[tid] = a0 + a1 + a2 + a3;
    __syncthreads();
    for (int off = 1; off < 1024; off <<= 1) {
        int v = (tid >= off) ? sd[tid - off] : 0;
        __syncthreads();
        sd[tid] += v;
        __syncthreads();
    }
    int base = tid ? sd[tid - 1] : 0;
    r[i0] = base; r[i0 + 1] = base + a0; r[i0 + 2] = base + a0 + a1; r[i0 + 3] = base + a0 + a1 + a2;
    if (tid == 1023) r[4096] = sd[1023];
}

// scatter into packed (col, val) CSR stream
__global__ void scatter_k(const int* __restrict__ rows, const int* __restrict__ cols,
                          const float* __restrict__ vals, const int* __restrict__ rp,
                          int* __restrict__ fill, int2* __restrict__ pcv)
{
    int i = blockIdx.x * 256 + threadIdx.x;     // 2*65536 exact
    int s = i >> 16;
    int r = rows[i];
    int pos = rp[s * 4097 + r] + atomicAdd(&fill[(s << 12) + r], 1);
    int2 e; e.x = cols[i]; e.y = __float_as_int(vals[i]);
    pcv[(s << 16) + pos] = e;
}

// ---------------- x0 build: input part --------------------------------------
__global__ void x0i_k(const float* __restrict__ in, float* __restrict__ x0i, int h)
{
    int i = blockIdx.x * 256 + threadIdx.x;     // 4096*32 exact
    int n = i >> 5, bl = i & 31;
    const f32x2 v = *(const f32x2*)(in + (size_t)(h * HB + bl) * 8192 + n * 2);
    __builtin_nontemporal_store(v, (f32x2*)(x0i + (size_t)n * IROW + bl * 2));
}

// ---------------- SpMM v6: LDS edges, hx-direct source/prev modes -----------
// mode 0 (step1): grid (8448, 2), sup = blockIdx.y; main b<8192, input b>=8192.
// mode 1 (step2, cheb): grid (16896, 1); 4 phases main, 2x256 input blocks.
// hxsm/hxpm: state src/prev is hx-layout ([bl]*262144 + col*64 + f) instead of
// linear ([col]*2048 + q*4). Per-phase XCD slice stays ~2 MB (L2-resident).
__global__ __launch_bounds__(256) void spmm_k(
    const float* __restrict__ ss0, const float* __restrict__ si0,
    const float* __restrict__ ss1, const float* __restrict__ si1,
    float* __restrict__ ds0, float* __restrict__ di0,
    float* __restrict__ ds1, float* __restrict__ di1,
    const float* __restrict__ ps, const float* __restrict__ pi,
    const int* __restrict__ rp, const int2* __restrict__ pcv,
    int mode, int hxsm, int hxpm)
{
    __shared__ int2 eds[768];
    __shared__ int srp[17];
    const int b = blockIdx.x;
    const int tid = threadIdx.x;
    int s, sub = 0, rowgrp, lrow, o_, rsh, nrows;
    bool is_main;
    if (mode == 0) {
        s = blockIdx.y;
        if (b < 8192) {
            is_main = true;
            const int j = b >> 3;
            sub = (b & 7) * 2 + (j >> 9);
            rowgrp = j & 511;
        } else {
            is_main = false;
            rowgrp = b - 8192;
        }
    } else {
        if (b < 16384) {
            is_main = true;
            const int phase = b >> 12;
            s = phase >> 1;
            sub = (b & 7) * 2 + (phase & 1);
            rowgrp = (b >> 3) & 511;
        } else {
            is_main = false;
            const int j2 = b - 16384;
            s = j2 >> 8;
            rowgrp = j2 & 255;
        }
    }
    float* __restrict__ dst;
    const float* xb;            // per-lane gather base
    const float* pb;            // per-lane prev base
    int csh, psh;
    int R0;
    if (is_main) {
        nrows = 8; R0 = rowgrp * 8;
        lrow = ((tid >> 6) << 1) | ((tid >> 5) & 1);
        const int q = sub * 32 + (tid & 31);
        o_ = q * 4;
        rsh = 11;
        const int blq = q >> 4, fo = (q & 15) * 4;
        const float* xsrc = s ? ss1 : ss0;
        if (hxsm) { xb = xsrc + (size_t)blq * 262144 + fo; csh = 6; }
        else      { xb = xsrc + o_;                        csh = 11; }
        if (hxpm) { pb = ps + (size_t)blq * 262144 + fo;   psh = 6; }
        else      { pb = ps + o_;                          psh = 11; }
        dst = s ? ds1 : ds0;
    } else {
        nrows = 16; R0 = rowgrp * 16;
        lrow = ((tid >> 6) << 2) | ((tid >> 4) & 3);
        o_ = (tid & 15) * 4;
        rsh = 6;
        xb = (s ? si1 : si0) + o_; csh = 6;
        pb = pi + o_;              psh = 6;
        dst = s ? di1 : di0;
    }
    if (tid <= nrows) srp[tid] = rp[s * 4097 + R0 + tid];
    __syncthreads();
    const int ebase = srp[0];
    const int etot = srp[nrows] - ebase;
    for (int i = tid; i < etot; i += 256) eds[i] = pcv[(s << 16) + ebase + i];
    __syncthreads();
    const int p0 = srp[lrow] - ebase;
    const int cnt = srp[lrow + 1] - srp[lrow];

    f32x4 a0 = {0,0,0,0}, a1 = {0,0,0,0}, a2 = {0,0,0,0}, a3 = {0,0,0,0};
    int e = 0;
    for (; e + 8 <= cnt; e += 8) {
        const int2 E0 = eds[p0+e+0], E1 = eds[p0+e+1], E2 = eds[p0+e+2], E3 = eds[p0+e+3];
        const int2 E4 = eds[p0+e+4], E5 = eds[p0+e+5], E6 = eds[p0+e+6], E7 = eds[p0+e+7];
        const f32x4 x0v = *(const f32x4*)(xb + ((size_t)E0.x << csh));
        const f32x4 x1v = *(const f32x4*)(xb + ((size_t)E1.x << csh));
        const f32x4 x2v = *(const f32x4*)(xb + ((size_t)E2.x << csh));
        const f32x4 x3v = *(const f32x4*)(xb + ((size_t)E3.x << csh));
        const f32x4 x4v = *(const f32x4*)(xb + ((size_t)E4.x << csh));
        const f32x4 x5v = *(const f32x4*)(xb + ((size_t)E5.x << csh));
        const f32x4 x6v = *(const f32x4*)(xb + ((size_t)E6.x << csh));
        const f32x4 x7v = *(const f32x4*)(xb + ((size_t)E7.x << csh));
        a0 = fma4(__int_as_float(E0.y), x0v, a0);
        a1 = fma4(__int_as_float(E1.y), x1v, a1);
        a2 = fma4(__int_as_float(E2.y), x2v, a2);
        a3 = fma4(__int_as_float(E3.y), x3v, a3);
        a0 = fma4(__int_as_float(E4.y), x4v, a0);
        a1 = fma4(__int_as_float(E5.y), x5v, a1);
        a2 = fma4(__int_as_float(E6.y), x6v, a2);
        a3 = fma4(__int_as_float(E7.y), x7v, a3);
    }
    for (; e + 2 <= cnt; e += 2) {
        const int2 E0 = eds[p0+e], E1 = eds[p0+e+1];
        const f32x4 x0v = *(const f32x4*)(xb + ((size_t)E0.x << csh));
        const f32x4 x1v = *(const f32x4*)(xb + ((size_t)E1.x << csh));
        a0 = fma4(__int_as_float(E0.y), x0v, a0);
        a1 = fma4(__int_as_float(E1.y), x1v, a1);
    }
    if (e < cnt) {
        const int2 E0 = eds[p0+e];
        const f32x4 x0v = *(const f32x4*)(xb + ((size_t)E0.x << csh));
        a0 = fma4(__int_as_float(E0.y), x0v, a0);
    }
    f32x4 R;
    R.x = (a0.x + a1.x) + (a2.x + a3.x);
    R.y = (a0.y + a1.y) + (a2.y + a3.y);
    R.z = (a0.z + a1.z) + (a2.z + a3.z);
    R.w = (a0.w + a1.w) + (a2.w + a3.w);

    if (mode) {
        const f32x4 pv = __builtin_nontemporal_load((const f32x4*)(pb + ((size_t)(R0 + lrow) << psh)));
        R.x = 2.0f * R.x - pv.x; R.y = 2.0f * R.y - pv.y;
        R.z = 2.0f * R.z - pv.z; R.w = 2.0f * R.w - pv.w;
    }
    __builtin_nontemporal_store(R, (f32x4*)(dst + ((size_t)(R0 + lrow) << rsh) + o_));
}

// ------ mm staging: hi-plane only (bf16 of x); m=0 selectable source --------
__device__ __forceinline__ void stage_hi(const float* __restrict__ xs, const float* __restrict__ xi,
                                         const float* __restrict__ m0s, int m0hx,
                                         int n, int tid, uint* __restrict__ Bhi)
{
    for (int i = tid; i < 480; i += 256) {      // zero K-pad words 165..179 per b-row
        int bl = i / 15, t = i - bl * 15;
        Bhi[bl * 180 + 165 + t] = 0u;
    }
    for (int i = tid; i < 2560; i += 256) {     // state: 5 m x 32 bl x 16 quads
        int m = i >> 9, rem = i & 511, bl = rem >> 4, fq = rem & 15;
        const float* p;
        if (m == 0)
            p = m0hx ? m0s + (size_t)bl * 262144 + (size_t)n * 64 + fq * 4
                     : m0s + (size_t)n * SROW + bl * 64 + fq * 4;
        else
            p = xs + (size_t)m * SLVL + (size_t)n * SROW + bl * 64 + fq * 4;
        const f32x4 v = __builtin_nontemporal_load((const f32x4*)p);
        const int base = bl * 180 + m * 33 + 1 + fq * 2;
        Bhi[base]     = pkhi2(v.x, v.y);
        Bhi[base + 1] = pkhi2(v.z, v.w);
    }
    for (int i = tid; i < 160; i += 256) {      // input: 5 m x 32 bl
        int m = i >> 5, bl = i & 31;
        const f32x2 v = __builtin_nontemporal_load(
            (const f32x2*)(xi + (size_t)m * ILVL + (size_t)n * IROW + bl * 2));
        Bhi[bl * 180 + m * 33] = pkhi2(v.x, v.y);
    }
}

#define MFMA(a, b, c) __builtin_amdgcn_mfma_f32_16x16x32_bf16(a, b, c, 0, 0, 0)

// ---------------- gconv1 matmul + sigmoid; u->out, r*hx->x0 state -----------
// Precision: (W_hi + W_lo) x x_hi  == full-precision W times bf16-rounded x.
__global__ __launch_bounds__(256, 6) void mm_ru_k(const float* __restrict__ xs, const float* __restrict__ xi,
                                                  const ushort* __restrict__ whi, const ushort* __restrict__ wlo,
                                                  const float* __restrict__ bru, const float* __restrict__ hx,
                                                  float* __restrict__ uout, float* __restrict__ xs0s, int h)
{
    const int n = blockIdx.x;
    const int tid = threadIdx.x;
    const int lane = tid & 63, wave = tid >> 6;
    __shared__ uint Bhi[32 * 180];

    stage_hi(xs, xi, hx + (size_t)h * HB * 262144, 1, n, tid, Bhi);
    __syncthreads();

    const int ob = wave * 32 + (lane & 15);
    const int ksub = (lane >> 4) * 8;
    const int brow = lane & 15;
    const ushort* BH = (const ushort*)Bhi;
    f32x4 acc[2][2] = {};

    #pragma unroll
    for (int ks = 0; ks < KSTEPS; ++ks) {
        const int ko = ks * 32 + ksub;
        short8 Ah0 = *(const short8*)(whi + (size_t)ob * KP + ko);
        short8 Ah1 = *(const short8*)(whi + (size_t)(ob + 16) * KP + ko);
        short8 Al0 = *(const short8*)(wlo + (size_t)ob * KP + ko);
        short8 Al1 = *(const short8*)(wlo + (size_t)(ob + 16) * KP + ko);
        short8 Bh0 = *(const short8*)(BH + brow * 360 + ko);
        short8 Bh1 = *(const short8*)(BH + (16 + brow) * 360 + ko);
        acc[0][0] = MFMA(Ah0, Bh0, acc[0][0]);
        acc[0][1] = MFMA(Ah0, Bh1, acc[0][1]);
        acc[1][0] = MFMA(Ah1, Bh0, acc[1][0]);
        acc[1][1] = MFMA(Ah1, Bh1, acc[1][1]);
        acc[0][0] = MFMA(Al0, Bh0, acc[0][0]);
        acc[0][1] = MFMA(Al0, Bh1, acc[0][1]);
        acc[1][0] = MFMA(Al1, Bh0, acc[1][0]);
        acc[1][1] = MFMA(Al1, Bh1, acc[1][1]);
    }

    const int g = lane >> 4, bcol = lane & 15;
    #pragma unroll
    for (int t = 0; t < 2; ++t) {
        const int o = wave * 32 + t * 16 + g * 4;
        const float bb0 = bru[o], bb1 = bru[o + 1], bb2 = bru[o + 2], bb3 = bru[o + 3];
        #pragma unroll
        for (int bt = 0; bt < 2; ++bt) {
            const int bl = bt * 16 + bcol;
            float s0 = sigm(acc[t][bt][0] + bb0);
            float s1 = sigm(acc[t][bt][1] + bb1);
            float s2 = sigm(acc[t][bt][2] + bb2);
            float s3 = sigm(acc[t][bt][3] + bb3);
            if (o < 64) {   // r-part: r*hx -> x0 state (aligned f32x4)
                const f32x4 hxv = *(const f32x4*)(hx + (size_t)(h * HB + bl) * 262144 + (size_t)n * 64 + o);
                f32x4 rv;
                rv[0] = s0 * hxv[0]; rv[1] = s1 * hxv[1];
                rv[2] = s2 * hxv[2]; rv[3] = s3 * hxv[3];
                *(f32x4*)(xs0s + (size_t)n * SROW + bl * 64 + o) = rv;
            } else {        // u-part -> d_out (temporary storage)
                f32x4 uv = {s0, s1, s2, s3};
                *(f32x4*)(uout + (size_t)(h * HB + bl) * 262144 + (size_t)n * 64 + (o - 64)) = uv;
            }
        }
    }
}

// ---------------- gconv2 matmul + tanh + final GRU combine ------------------
__global__ __launch_bounds__(256, 6) void mm_c_k(const float* __restrict__ xs, const float* __restrict__ xi,
                                                 const ushort* __restrict__ whi, const ushort* __restrict__ wlo,
                                                 const float* __restrict__ bc, const float* __restrict__ hx,
                                                 float* __restrict__ out, int h)
{
    const int n = blockIdx.x;
    const int tid = threadIdx.x;
    const int lane = tid & 63, wave = tid >> 6;
    __shared__ uint Bhi[32 * 180];

    stage_hi(xs, xi, xs, 0, n, tid, Bhi);
    __syncthreads();

    const int ob = wave * 16 + (lane & 15);
    const int ksub = (lane >> 4) * 8;
    const int brow = lane & 15;
    const ushort* BH = (const ushort*)Bhi;
    f32x4 acc[2] = {};

    #pragma unroll
    for (int ks = 0; ks < KSTEPS; ++ks) {
        const int ko = ks * 32 + ksub;
        short8 Ah = *(const short8*)(whi + (size_t)ob * KP + ko);
        short8 Al = *(const short8*)(wlo + (size_t)ob * KP + ko);
        short8 Bh0 = *(const short8*)(BH + brow * 360 + ko);
        short8 Bh1 = *(const short8*)(BH + (16 + brow) * 360 + ko);
        acc[0] = MFMA(Ah, Bh0, acc[0]);
        acc[1] = MFMA(Ah, Bh1, acc[1]);
        acc[0] = MFMA(Al, Bh0, acc[0]);
        acc[1] = MFMA(Al, Bh1, acc[1]);
    }

    const int g = lane >> 4, bcol = lane & 15;
    const int o = wave * 16 + g * 4;
    const float bb0 = bc[o], bb1 = bc[o + 1], bb2 = bc[o + 2], bb3 = bc[o + 3];
    #pragma unroll
    for (int bt = 0; bt < 2; ++bt) {
        const int bl = bt * 16 + bcol;
        float c0 = tanh_fast(acc[bt][0] + bb0);
        float c1 = tanh_fast(acc[bt][1] + bb1);
        float c2 = tanh_fast(acc[bt][2] + bb2);
        float c3 = tanh_fast(acc[bt][3] + bb3);
        float* p = out + (size_t)(h * HB + bl) * 262144 + (size_t)n * 64 + o;
        const f32x4 hxv = *(const f32x4*)(hx + (size_t)(h * HB + bl) * 262144 + (size_t)n * 64 + o);
        f32x4 uv = *(const f32x4*)p;
        f32x4 ov;
        ov[0] = uv[0] * hxv[0] + (1.0f - uv[0]) * c0;
        ov[1] = uv[1] * hxv[1] + (1.0f - uv[1]) * c1;
        ov[2] = uv[2] * hxv[2] + (1.0f - uv[2]) * c2;
        ov[3] = uv[3] * hxv[3] + (1.0f - uv[3]) * c3;
        *(f32x4*)p = ov;
    }
}

// ---------------------------------------------------------------------------
extern "C" void kernel_launch(void* const* d_in, const int* in_sizes, int n_in,
                              void* d_out, int out_size, void* d_ws, size_t ws_size,
                              hipStream_t stream)
{
    (void)in_sizes; (void)n_in; (void)out_size; (void)ws_size;
    const float* inputs  = (const float*)d_in[0];
    const float* hx      = (const float*)d_in[1];
    const int*   sup_rows= (const int*)d_in[2];
    const int*   sup_cols= (const int*)d_in[3];
    const float* sup_vals= (const float*)d_in[4];
    const float* W_ru    = (const float*)d_in[5];
    const float* b_ru    = (const float*)d_in[6];
    const float* W_c     = (const float*)d_in[7];
    const float* b_c     = (const float*)d_in[8];
    float* out = (float*)d_out;

    char* ws = (char*)d_ws;
    float* xs = (float*)ws;                                 // 5 state levels: 167.8 MB
    float* xi = xs + 5ull * SLVL;                           // 5 input levels: 5.2 MB
    size_t off = (5ull * SLVL + 5ull * ILVL) * 4ull;        // 173,015,040
    ushort* wru_hi = (ushort*)(ws + off); off += 90112;
    ushort* wru_lo = (ushort*)(ws + off); off += 90112;
    ushort* wc_hi  = (ushort*)(ws + off); off += 45056;
    ushort* wc_lo  = (ushort*)(ws + off); off += 45056;
    int* row_ptr   = (int*)(ws + off);    off += 32800;
    int* cntfill   = (int*)(ws + off);    off += 65536;
    int2* pcv      = (int2*)(ws + off);   off += 1048576;   // packed (col,val) CSR

    #define XS(m) (xs + (size_t)(m) * SLVL)
    #define XI(m) (xi + (size_t)(m) * ILVL)
    int* fill = cntfill + 8192;

    zero_k<<<64, 256, 0, stream>>>(cntfill);
    wtbuild_k<<<264, 256, 0, stream>>>(W_ru, W_c, wru_hi, wru_lo, wc_hi, wc_lo);
    count_k<<<512, 256, 0, stream>>>(sup_rows, cntfill);
    scan_k<<<2, 1024, 0, stream>>>(cntfill, row_ptr);
    scatter_k<<<512, 256, 0, stream>>>(sup_rows, sup_cols, sup_vals, row_ptr, fill, pcv);

    for (int h = 0; h < 2; ++h) {
        const float* hxs = hx + (size_t)h * HB * 262144;
        x0i_k<<<512, 256, 0, stream>>>(inputs, XI(0), h);
        // gconv1 diffusion: step1 reads hx in place (hxsm); step2 prev = hx (hxpm)
        spmm_k<<<dim3(8448, 2), 256, 0, stream>>>(hxs, XI(0), hxs, XI(0),
                                                  XS(1), XI(1), XS(3), XI(3),
                                                  hxs, XI(0), row_ptr, pcv, 0, 1, 0);
        spmm_k<<<dim3(16896, 1), 256, 0, stream>>>(XS(1), XI(1), XS(3), XI(3),
                                                   XS(2), XI(2), XS(4), XI(4),
                                                   hxs, XI(0), row_ptr, pcv, 1, 0, 1);
        // gconv1 matmul: u -> out, r*hx -> x0 state part (m0 staged from hx)
        mm_ru_k<<<NN, 256, 0, stream>>>(xs, xi, wru_hi, wru_lo, b_ru, hx, out, XS(0), h);
        // gconv2 diffusion (x0 = [inputs, r*hx], all linear)
        spmm_k<<<dim3(8448, 2), 256, 0, stream>>>(XS(0), XI(0), XS(0), XI(0),
                                                  XS(1), XI(1), XS(3), XI(3),
                                                  XS(0), XI(0), row_ptr, pcv, 0, 0, 0);
        spmm_k<<<dim3(16896, 1), 256, 0, stream>>>(XS(1), XI(1), XS(3), XI(3),
                                                   XS(2), XI(2), XS(4), XI(4),
                                                   XS(0), XI(0), row_ptr, pcv, 1, 0, 0);
        // gconv2 matmul + tanh + final GRU combine
        mm_c_k<<<NN, 256, 0, stream>>>(xs, xi, wc_hi, wc_lo, b_c, hx, out, h);
    }
    #undef XS
    #undef XI
}

// Round 10
// 886.874 us; speedup vs baseline: 2.0793x; 1.0308x over previous
//
#include <hip/hip_runtime.h>

typedef float f32x4 __attribute__((ext_vector_type(4)));
typedef float f32x2 __attribute__((ext_vector_type(2)));
typedef short short8 __attribute__((ext_vector_type(8)));

#define NN 4096
#define HB 32               // half batch
#define SROW 2048           // state f32 per node row (32 b x 64 f), 1<<11
#define IROW 64             // input f32 per node row (32 b x 2 f), 1<<6
#define SLVL 8388608ull     // f32 per state level (NN*SROW)
#define ILVL 262144ull      // f32 per input level (NN*IROW)
#define KP 352              // padded K (330 real)
#define KSTEPS 11
#define NPB 8               // nodes per mm block

__device__ __forceinline__ ushort f2bf(float f){ uint i = __float_as_uint(f); return (ushort)((i + 0x7fffu + ((i >> 16) & 1u)) >> 16); }
__device__ __forceinline__ float bf2f(ushort u){ return __uint_as_float((uint)u << 16); }
__device__ __forceinline__ uint pkhi2(float a, float b){ return (uint)f2bf(a) | ((uint)f2bf(b) << 16); }
__device__ __forceinline__ float sigm(float x){ return 1.0f / (1.0f + __expf(-x)); }
__device__ __forceinline__ float tanh_fast(float x){
    x = fminf(20.0f, fmaxf(-20.0f, x));
    float t = __expf(-2.0f * x);
    return (1.0f - t) / (1.0f + t);
}
__device__ __forceinline__ f32x4 fma4(float v, f32x4 x, f32x4 a){
    a.x = fmaf(v, x.x, a.x); a.y = fmaf(v, x.y, a.y);
    a.z = fmaf(v, x.z, a.z); a.w = fmaf(v, x.w, a.w);
    return a;
}

// ---------------- zero scratch (cnt+fill), graph-capture-safe ---------------
__global__ void zero_k(int* __restrict__ p){ p[blockIdx.x * 256 + threadIdx.x] = 0; }

// ------- weight transform: Wt_hi/lo[o][k], k = m*66+f, bf16 hi/lo split -----
__global__ void wtbuild_k(const float* __restrict__ Wru, const float* __restrict__ Wc,
                          ushort* __restrict__ ru_hi, ushort* __restrict__ ru_lo,
                          ushort* __restrict__ c_hi,  ushort* __restrict__ c_lo)
{
    int idx = blockIdx.x * 256 + threadIdx.x;   // 192*352 exact
    float w = 0.0f;
    if (idx < 128 * KP) {
        int o = idx / KP, k = idx - o * KP;
        if (k < 330) { int m = k / 66, f = k - m * 66; w = Wru[(size_t)(f * 5 + m) * 128 + o]; }
        ushort hi = f2bf(w);
        ushort lo = f2bf(w - bf2f(hi));
        ru_hi[(size_t)o * KP + k] = hi;
        ru_lo[(size_t)o * KP + k] = lo;
    } else {
        int j = idx - 128 * KP;
        int o = j / KP, k = j - o * KP;
        if (k < 330) { int m = k / 66, f = k - m * 66; w = Wc[(size_t)(f * 5 + m) * 64 + o]; }
        ushort hi = f2bf(w);
        ushort lo = f2bf(w - bf2f(hi));
        c_hi[(size_t)o * KP + k] = hi;
        c_lo[(size_t)o * KP + k] = lo;
    }
}

// ---------------- CSR build ------------------------------------------------
__global__ void count_k(const int* __restrict__ rows, int* __restrict__ cnt)
{
    int i = blockIdx.x * 256 + threadIdx.x;     // 2*65536 exact
    int s = i >> 16;
    atomicAdd(&cnt[(s << 12) + rows[i]], 1);
}

__global__ __launch_bounds__(1024) void scan_k(const int* __restrict__ cnt, int* __restrict__ rp)
{
    int s = blockIdx.x;
    const int* c = cnt + (s << 12);
    int* r = rp + s * 4097;
    __shared__ int sd[1024];
    int tid = threadIdx.x;
    int i0 = tid * 4;
    int a0 = c[i0], a1 = c[i0 + 1], a2 = c[i0 + 2], a3 = c[i0 + 3];
    sd[tid] = a0 + a1 + a2 + a3;
    __syncthreads();
    for (int off = 1; off < 1024; off <<= 1) {
        int v = (tid >= off) ? sd[tid - off] : 0;
        __syncthreads();
        sd[tid] += v;
        __syncthreads();
    }
    int base = tid ? sd[tid - 1] : 0;
    r[i0] = base; r[i0 + 1] = base + a0; r[i0 + 2] = base + a0 + a1; r[i0 + 3] = base + a0 + a1 + a2;
    if (tid == 1023) r[4096] = sd[1023];
}

// scatter into packed (col, val) CSR stream
__global__ void scatter_k(const int* __restrict__ rows, const int* __restrict__ cols,
                          const float* __restrict__ vals, const int* __restrict__ rp,
                          int* __restrict__ fill, int2* __restrict__ pcv)
{
    int i = blockIdx.x * 256 + threadIdx.x;     // 2*65536 exact
    int s = i >> 16;
    int r = rows[i];
    int pos = rp[s * 4097 + r] + atomicAdd(&fill[(s << 12) + r], 1);
    int2 e; e.x = cols[i]; e.y = __float_as_int(vals[i]);
    pcv[(s << 16) + pos] = e;
}

// ---------------- x0 build: input part --------------------------------------
__global__ void x0i_k(const float* __restrict__ in, float* __restrict__ x0i, int h)
{
    int i = blockIdx.x * 256 + threadIdx.x;     // 4096*32 exact
    int n = i >> 5, bl = i & 31;
    const f32x2 v = *(const f32x2*)(in + (size_t)(h * HB + bl) * 8192 + n * 2);
    __builtin_nontemporal_store(v, (f32x2*)(x0i + (size_t)n * IROW + bl * 2));
}

// ---------------- SpMM v6: LDS edges, hx-direct source/prev modes -----------
__global__ __launch_bounds__(256) void spmm_k(
    const float* __restrict__ ss0, const float* __restrict__ si0,
    const float* __restrict__ ss1, const float* __restrict__ si1,
    float* __restrict__ ds0, float* __restrict__ di0,
    float* __restrict__ ds1, float* __restrict__ di1,
    const float* __restrict__ ps, const float* __restrict__ pi,
    const int* __restrict__ rp, const int2* __restrict__ pcv,
    int mode, int hxsm, int hxpm)
{
    __shared__ int2 eds[768];
    __shared__ int srp[17];
    const int b = blockIdx.x;
    const int tid = threadIdx.x;
    int s, sub = 0, rowgrp, lrow, o_, rsh, nrows;
    bool is_main;
    if (mode == 0) {
        s = blockIdx.y;
        if (b < 8192) {
            is_main = true;
            const int j = b >> 3;
            sub = (b & 7) * 2 + (j >> 9);
            rowgrp = j & 511;
        } else {
            is_main = false;
            rowgrp = b - 8192;
        }
    } else {
        if (b < 16384) {
            is_main = true;
            const int phase = b >> 12;
            s = phase >> 1;
            sub = (b & 7) * 2 + (phase & 1);
            rowgrp = (b >> 3) & 511;
        } else {
            is_main = false;
            const int j2 = b - 16384;
            s = j2 >> 8;
            rowgrp = j2 & 255;
        }
    }
    float* __restrict__ dst;
    const float* xb;
    const float* pb;
    int csh, psh;
    int R0;
    if (is_main) {
        nrows = 8; R0 = rowgrp * 8;
        lrow = ((tid >> 6) << 1) | ((tid >> 5) & 1);
        const int q = sub * 32 + (tid & 31);
        o_ = q * 4;
        rsh = 11;
        const int blq = q >> 4, fo = (q & 15) * 4;
        const float* xsrc = s ? ss1 : ss0;
        if (hxsm) { xb = xsrc + (size_t)blq * 262144 + fo; csh = 6; }
        else      { xb = xsrc + o_;                        csh = 11; }
        if (hxpm) { pb = ps + (size_t)blq * 262144 + fo;   psh = 6; }
        else      { pb = ps + o_;                          psh = 11; }
        dst = s ? ds1 : ds0;
    } else {
        nrows = 16; R0 = rowgrp * 16;
        lrow = ((tid >> 6) << 2) | ((tid >> 4) & 3);
        o_ = (tid & 15) * 4;
        rsh = 6;
        xb = (s ? si1 : si0) + o_; csh = 6;
        pb = pi + o_;              psh = 6;
        dst = s ? di1 : di0;
    }
    if (tid <= nrows) srp[tid] = rp[s * 4097 + R0 + tid];
    __syncthreads();
    const int ebase = srp[0];
    const int etot = srp[nrows] - ebase;
    for (int i = tid; i < etot; i += 256) eds[i] = pcv[(s << 16) + ebase + i];
    __syncthreads();
    const int p0 = srp[lrow] - ebase;
    const int cnt = srp[lrow + 1] - srp[lrow];

    f32x4 a0 = {0,0,0,0}, a1 = {0,0,0,0}, a2 = {0,0,0,0}, a3 = {0,0,0,0};
    int e = 0;
    for (; e + 8 <= cnt; e += 8) {
        const int2 E0 = eds[p0+e+0], E1 = eds[p0+e+1], E2 = eds[p0+e+2], E3 = eds[p0+e+3];
        const int2 E4 = eds[p0+e+4], E5 = eds[p0+e+5], E6 = eds[p0+e+6], E7 = eds[p0+e+7];
        const f32x4 x0v = *(const f32x4*)(xb + ((size_t)E0.x << csh));
        const f32x4 x1v = *(const f32x4*)(xb + ((size_t)E1.x << csh));
        const f32x4 x2v = *(const f32x4*)(xb + ((size_t)E2.x << csh));
        const f32x4 x3v = *(const f32x4*)(xb + ((size_t)E3.x << csh));
        const f32x4 x4v = *(const f32x4*)(xb + ((size_t)E4.x << csh));
        const f32x4 x5v = *(const f32x4*)(xb + ((size_t)E5.x << csh));
        const f32x4 x6v = *(const f32x4*)(xb + ((size_t)E6.x << csh));
        const f32x4 x7v = *(const f32x4*)(xb + ((size_t)E7.x << csh));
        a0 = fma4(__int_as_float(E0.y), x0v, a0);
        a1 = fma4(__int_as_float(E1.y), x1v, a1);
        a2 = fma4(__int_as_float(E2.y), x2v, a2);
        a3 = fma4(__int_as_float(E3.y), x3v, a3);
        a0 = fma4(__int_as_float(E4.y), x4v, a0);
        a1 = fma4(__int_as_float(E5.y), x5v, a1);
        a2 = fma4(__int_as_float(E6.y), x6v, a2);
        a3 = fma4(__int_as_float(E7.y), x7v, a3);
    }
    for (; e + 2 <= cnt; e += 2) {
        const int2 E0 = eds[p0+e], E1 = eds[p0+e+1];
        const f32x4 x0v = *(const f32x4*)(xb + ((size_t)E0.x << csh));
        const f32x4 x1v = *(const f32x4*)(xb + ((size_t)E1.x << csh));
        a0 = fma4(__int_as_float(E0.y), x0v, a0);
        a1 = fma4(__int_as_float(E1.y), x1v, a1);
    }
    if (e < cnt) {
        const int2 E0 = eds[p0+e];
        const f32x4 x0v = *(const f32x4*)(xb + ((size_t)E0.x << csh));
        a0 = fma4(__int_as_float(E0.y), x0v, a0);
    }
    f32x4 R;
    R.x = (a0.x + a1.x) + (a2.x + a3.x);
    R.y = (a0.y + a1.y) + (a2.y + a3.y);
    R.z = (a0.z + a1.z) + (a2.z + a3.z);
    R.w = (a0.w + a1.w) + (a2.w + a3.w);

    if (mode) {
        const f32x4 pv = __builtin_nontemporal_load((const f32x4*)(pb + ((size_t)(R0 + lrow) << psh)));
        R.x = 2.0f * R.x - pv.x; R.y = 2.0f * R.y - pv.y;
        R.z = 2.0f * R.z - pv.z; R.w = 2.0f * R.w - pv.w;
    }
    __builtin_nontemporal_store(R, (f32x4*)(dst + ((size_t)(R0 + lrow) << rsh) + o_));
}

// ------ mm staging (NT-thread generic): x -> hi-plane bf16 LDS --------------
template<int NT>
__device__ __forceinline__ void stage_hi(const float* __restrict__ xs, const float* __restrict__ xi,
                                         const float* __restrict__ m0s, int m0hx,
                                         int n, int tid, uint* __restrict__ Bhi)
{
    for (int i = tid; i < 480; i += NT) {       // zero K-pad words 165..179 per b-row
        int bl = i / 15, t = i - bl * 15;
        Bhi[bl * 180 + 165 + t] = 0u;
    }
    for (int i = tid; i < 2560; i += NT) {      // state: 5 m x 32 bl x 16 quads
        int m = i >> 9, rem = i & 511, bl = rem >> 4, fq = rem & 15;
        const float* p;
        if (m == 0)
            p = m0hx ? m0s + (size_t)bl * 262144 + (size_t)n * 64 + fq * 4
                     : m0s + (size_t)n * SROW + bl * 64 + fq * 4;
        else
            p = xs + (size_t)m * SLVL + (size_t)n * SROW + bl * 64 + fq * 4;
        const f32x4 v = __builtin_nontemporal_load((const f32x4*)p);
        const int base = bl * 180 + m * 33 + 1 + fq * 2;
        Bhi[base]     = pkhi2(v.x, v.y);
        Bhi[base + 1] = pkhi2(v.z, v.w);
    }
    for (int i = tid; i < 160; i += NT) {       // input: 5 m x 32 bl
        int m = i >> 5, bl = i & 31;
        const f32x2 v = __builtin_nontemporal_load(
            (const f32x2*)(xi + (size_t)m * ILVL + (size_t)n * IROW + bl * 2));
        Bhi[bl * 180 + m * 33] = pkhi2(v.x, v.y);
    }
}

#define MFMA(a, b, c) __builtin_amdgcn_mfma_f32_16x16x32_bf16(a, b, c, 0, 0, 0)

// -------- gconv1 matmul: W resident in VGPRs, 8 nodes streamed per block ----
// 512 threads = 8 waves; wave w owns 16 output rows. A = 22 frags (88 VGPR)
// loaded once; per node: double-buffered B stage + 44 MFMA/wave.
__global__ __launch_bounds__(512, 4) void mm_ru_k(const float* __restrict__ xs, const float* __restrict__ xi,
                                                  const ushort* __restrict__ whi, const ushort* __restrict__ wlo,
                                                  const float* __restrict__ bru, const float* __restrict__ hx,
                                                  float* __restrict__ uout, float* __restrict__ xs0s, int h)
{
    const int tid = threadIdx.x;
    const int lane = tid & 63, wave = tid >> 6;
    __shared__ uint Bbuf[2][5760];
    const int n0 = blockIdx.x * NPB;
    const float* hxs = hx + (size_t)h * HB * 262144;

    const int ob = wave * 16 + (lane & 15);
    const int ksub = (lane >> 4) * 8;
    const int brow = lane & 15;
    short8 Ah[KSTEPS], Al[KSTEPS];
    #pragma unroll
    for (int ks = 0; ks < KSTEPS; ++ks) {
        Ah[ks] = *(const short8*)(whi + (size_t)ob * KP + ks * 32 + ksub);
        Al[ks] = *(const short8*)(wlo + (size_t)ob * KP + ks * 32 + ksub);
    }
    const int g = lane >> 4, bcol = lane & 15;
    const int o = wave * 16 + g * 4;
    const float bb0 = bru[o], bb1 = bru[o + 1], bb2 = bru[o + 2], bb3 = bru[o + 3];

    stage_hi<512>(xs, xi, hxs, 1, n0, tid, Bbuf[0]);

    for (int i = 0; i < NPB; ++i) {
        __syncthreads();
        if (i + 1 < NPB)
            stage_hi<512>(xs, xi, hxs, 1, n0 + i + 1, tid, Bbuf[(i + 1) & 1]);
        const ushort* BH = (const ushort*)Bbuf[i & 1];
        const int n = n0 + i;
        f32x4 acc[2] = {};
        #pragma unroll
        for (int ks = 0; ks < KSTEPS; ++ks) {
            const int ko = ks * 32 + ksub;
            short8 Bh0 = *(const short8*)(BH + brow * 360 + ko);
            short8 Bh1 = *(const short8*)(BH + (16 + brow) * 360 + ko);
            acc[0] = MFMA(Ah[ks], Bh0, acc[0]);
            acc[1] = MFMA(Ah[ks], Bh1, acc[1]);
            acc[0] = MFMA(Al[ks], Bh0, acc[0]);
            acc[1] = MFMA(Al[ks], Bh1, acc[1]);
        }
        #pragma unroll
        for (int bt = 0; bt < 2; ++bt) {
            const int bl = bt * 16 + bcol;
            float s0 = sigm(acc[bt][0] + bb0);
            float s1 = sigm(acc[bt][1] + bb1);
            float s2 = sigm(acc[bt][2] + bb2);
            float s3 = sigm(acc[bt][3] + bb3);
            if (wave < 4) {     // r-part: r*hx -> x0 state
                const f32x4 hxv = *(const f32x4*)(hx + (size_t)(h * HB + bl) * 262144 + (size_t)n * 64 + o);
                f32x4 rv;
                rv[0] = s0 * hxv[0]; rv[1] = s1 * hxv[1];
                rv[2] = s2 * hxv[2]; rv[3] = s3 * hxv[3];
                *(f32x4*)(xs0s + (size_t)n * SROW + bl * 64 + o) = rv;
            } else {            // u-part -> d_out (temporary storage)
                f32x4 uv = {s0, s1, s2, s3};
                *(f32x4*)(uout + (size_t)(h * HB + bl) * 262144 + (size_t)n * 64 + (o - 64)) = uv;
            }
        }
    }
}

// -------- gconv2 matmul: W resident, 8 nodes per block, 4 waves -------------
__global__ __launch_bounds__(256, 4) void mm_c_k(const float* __restrict__ xs, const float* __restrict__ xi,
                                                 const ushort* __restrict__ whi, const ushort* __restrict__ wlo,
                                                 const float* __restrict__ bc, const float* __restrict__ hx,
                                                 float* __restrict__ out, int h)
{
    const int tid = threadIdx.x;
    const int lane = tid & 63, wave = tid >> 6;
    __shared__ uint Bbuf[2][5760];
    const int n0 = blockIdx.x * NPB;

    const int ob = wave * 16 + (lane & 15);
    const int ksub = (lane >> 4) * 8;
    const int brow = lane & 15;
    short8 Ah[KSTEPS], Al[KSTEPS];
    #pragma unroll
    for (int ks = 0; ks < KSTEPS; ++ks) {
        Ah[ks] = *(const short8*)(whi + (size_t)ob * KP + ks * 32 + ksub);
        Al[ks] = *(const short8*)(wlo + (size_t)ob * KP + ks * 32 + ksub);
    }
    const int g = lane >> 4, bcol = lane & 15;
    const int o = wave * 16 + g * 4;
    const float bb0 = bc[o], bb1 = bc[o + 1], bb2 = bc[o + 2], bb3 = bc[o + 3];

    stage_hi<256>(xs, xi, xs, 0, n0, tid, Bbuf[0]);

    for (int i = 0; i < NPB; ++i) {
        __syncthreads();
        if (i + 1 < NPB)
            stage_hi<256>(xs, xi, xs, 0, n0 + i + 1, tid, Bbuf[(i + 1) & 1]);
        const ushort* BH = (const ushort*)Bbuf[i & 1];
        const int n = n0 + i;
        f32x4 acc[2] = {};
        #pragma unroll
        for (int ks = 0; ks < KSTEPS; ++ks) {
            const int ko = ks * 32 + ksub;
            short8 Bh0 = *(const short8*)(BH + brow * 360 + ko);
            short8 Bh1 = *(const short8*)(BH + (16 + brow) * 360 + ko);
            acc[0] = MFMA(Ah[ks], Bh0, acc[0]);
            acc[1] = MFMA(Ah[ks], Bh1, acc[1]);
            acc[0] = MFMA(Al[ks], Bh0, acc[0]);
            acc[1] = MFMA(Al[ks], Bh1, acc[1]);
        }
        #pragma unroll
        for (int bt = 0; bt < 2; ++bt) {
            const int bl = bt * 16 + bcol;
            float c0 = tanh_fast(acc[bt][0] + bb0);
            float c1 = tanh_fast(acc[bt][1] + bb1);
            float c2 = tanh_fast(acc[bt][2] + bb2);
            float c3 = tanh_fast(acc[bt][3] + bb3);
            float* p = out + (size_t)(h * HB + bl) * 262144 + (size_t)n * 64 + o;
            const f32x4 hxv = *(const f32x4*)(hx + (size_t)(h * HB + bl) * 262144 + (size_t)n * 64 + o);
            f32x4 uv = *(const f32x4*)p;
            f32x4 ov;
            ov[0] = uv[0] * hxv[0] + (1.0f - uv[0]) * c0;
            ov[1] = uv[1] * hxv[1] + (1.0f - uv[1]) * c1;
            ov[2] = uv[2] * hxv[2] + (1.0f - uv[2]) * c2;
            ov[3] = uv[3] * hxv[3] + (1.0f - uv[3]) * c3;
            *(f32x4*)p = ov;
        }
    }
}

// ---------------------------------------------------------------------------
extern "C" void kernel_launch(void* const* d_in, const int* in_sizes, int n_in,
                              void* d_out, int out_size, void* d_ws, size_t ws_size,
                              hipStream_t stream)
{
    (void)in_sizes; (void)n_in; (void)out_size; (void)ws_size;
    const float* inputs  = (const float*)d_in[0];
    const float* hx      = (const float*)d_in[1];
    const int*   sup_rows= (const int*)d_in[2];
    const int*   sup_cols= (const int*)d_in[3];
    const float* sup_vals= (const float*)d_in[4];
    const float* W_ru    = (const float*)d_in[5];
    const float* b_ru    = (const float*)d_in[6];
    const float* W_c     = (const float*)d_in[7];
    const float* b_c     = (const float*)d_in[8];
    float* out = (float*)d_out;

    char* ws = (char*)d_ws;
    float* xs = (float*)ws;                                 // 5 state levels: 167.8 MB
    float* xi = xs + 5ull * SLVL;                           // 5 input levels: 5.2 MB
    size_t off = (5ull * SLVL + 5ull * ILVL) * 4ull;        // 173,015,040
    ushort* wru_hi = (ushort*)(ws + off); off += 90112;
    ushort* wru_lo = (ushort*)(ws + off); off += 90112;
    ushort* wc_hi  = (ushort*)(ws + off); off += 45056;
    ushort* wc_lo  = (ushort*)(ws + off); off += 45056;
    int* row_ptr   = (int*)(ws + off);    off += 32800;
    int* cntfill   = (int*)(ws + off);    off += 65536;
    int2* pcv      = (int2*)(ws + off);   off += 1048576;   // packed (col,val) CSR

    #define XS(m) (xs + (size_t)(m) * SLVL)
    #define XI(m) (xi + (size_t)(m) * ILVL)
    int* fill = cntfill + 8192;

    zero_k<<<64, 256, 0, stream>>>(cntfill);
    wtbuild_k<<<264, 256, 0, stream>>>(W_ru, W_c, wru_hi, wru_lo, wc_hi, wc_lo);
    count_k<<<512, 256, 0, stream>>>(sup_rows, cntfill);
    scan_k<<<2, 1024, 0, stream>>>(cntfill, row_ptr);
    scatter_k<<<512, 256, 0, stream>>>(sup_rows, sup_cols, sup_vals, row_ptr, fill, pcv);

    for (int h = 0; h < 2; ++h) {
        const float* hxs = hx + (size_t)h * HB * 262144;
        x0i_k<<<512, 256, 0, stream>>>(inputs, XI(0), h);
        // gconv1 diffusion: step1 reads hx in place (hxsm); step2 prev = hx (hxpm)
        spmm_k<<<dim3(8448, 2), 256, 0, stream>>>(hxs, XI(0), hxs, XI(0),
                                                  XS(1), XI(1), XS(3), XI(3),
                                                  hxs, XI(0), row_ptr, pcv, 0, 1, 0);
        spmm_k<<<dim3(16896, 1), 256, 0, stream>>>(XS(1), XI(1), XS(3), XI(3),
                                                   XS(2), XI(2), XS(4), XI(4),
                                                   hxs, XI(0), row_ptr, pcv, 1, 0, 1);
        // gconv1 matmul: u -> out, r*hx -> x0 state part (m0 staged from hx)
        mm_ru_k<<<NN / NPB, 512, 0, stream>>>(xs, xi, wru_hi, wru_lo, b_ru, hx, out, XS(0), h);
        // gconv2 diffusion (x0 = [inputs, r*hx], all linear)
        spmm_k<<<dim3(8448, 2), 256, 0, stream>>>(XS(0), XI(0), XS(0), XI(0),
                                                  XS(1), XI(1), XS(3), XI(3),
                                                  XS(0), XI(0), row_ptr, pcv, 0, 0, 0);
        spmm_k<<<dim3(16896, 1), 256, 0, stream>>>(XS(1), XI(1), XS(3), XI(3),
                                                   XS(2), XI(2), XS(4), XI(4),
                                                   XS(0), XI(0), row_ptr, pcv, 1, 0, 0);
        // gconv2 matmul + tanh + final GRU combine
        mm_c_k<<<NN / NPB, 256, 0, stream>>>(xs, xi, wc_hi, wc_lo, b_c, hx, out, h);
    }
    #undef XS
    #undef XI
}

// Round 11
// 845.695 us; speedup vs baseline: 2.1806x; 1.0487x over previous
//
#include <hip/hip_runtime.h>

typedef float f32x4 __attribute__((ext_vector_type(4)));
typedef float f32x2 __attribute__((ext_vector_type(2)));
typedef short short8 __attribute__((ext_vector_type(8)));

#define NN 4096
#define HB 32               // half batch
#define SROW 2048           // state f32 per node row (32 b x 64 f), 1<<11
#define IROW 64             // input f32 per node row (32 b x 2 f), 1<<6
#define SLVL 8388608ull     // f32 per state level (NN*SROW)
#define ILVL 262144ull      // f32 per input level (NN*IROW)
#define KP 352              // padded K (330 real)
#define KSTEPS 11
#define NPB 8               // nodes per mm block

__device__ __forceinline__ ushort f2bf(float f){ uint i = __float_as_uint(f); return (ushort)((i + 0x7fffu + ((i >> 16) & 1u)) >> 16); }
__device__ __forceinline__ float bf2f(ushort u){ return __uint_as_float((uint)u << 16); }
__device__ __forceinline__ uint pkhi2(float a, float b){ return (uint)f2bf(a) | ((uint)f2bf(b) << 16); }
__device__ __forceinline__ float sigm(float x){ return 1.0f / (1.0f + __expf(-x)); }
__device__ __forceinline__ float tanh_fast(float x){
    x = fminf(20.0f, fmaxf(-20.0f, x));
    float t = __expf(-2.0f * x);
    return (1.0f - t) / (1.0f + t);
}
__device__ __forceinline__ f32x4 fma4(float v, f32x4 x, f32x4 a){
    a.x = fmaf(v, x.x, a.x); a.y = fmaf(v, x.y, a.y);
    a.z = fmaf(v, x.z, a.z); a.w = fmaf(v, x.w, a.w);
    return a;
}

// ---------------- zero scratch (cnt+fill), graph-capture-safe ---------------
__global__ void zero_k(int* __restrict__ p){ p[blockIdx.x * 256 + threadIdx.x] = 0; }

// ------- weight transform: Wt_hi/lo[o][k], k = m*66+f, bf16 hi/lo split -----
__global__ void wtbuild_k(const float* __restrict__ Wru, const float* __restrict__ Wc,
                          ushort* __restrict__ ru_hi, ushort* __restrict__ ru_lo,
                          ushort* __restrict__ c_hi,  ushort* __restrict__ c_lo)
{
    int idx = blockIdx.x * 256 + threadIdx.x;   // 192*352 exact
    float w = 0.0f;
    if (idx < 128 * KP) {
        int o = idx / KP, k = idx - o * KP;
        if (k < 330) { int m = k / 66, f = k - m * 66; w = Wru[(size_t)(f * 5 + m) * 128 + o]; }
        ushort hi = f2bf(w);
        ushort lo = f2bf(w - bf2f(hi));
        ru_hi[(size_t)o * KP + k] = hi;
        ru_lo[(size_t)o * KP + k] = lo;
    } else {
        int j = idx - 128 * KP;
        int o = j / KP, k = j - o * KP;
        if (k < 330) { int m = k / 66, f = k - m * 66; w = Wc[(size_t)(f * 5 + m) * 64 + o]; }
        ushort hi = f2bf(w);
        ushort lo = f2bf(w - bf2f(hi));
        c_hi[(size_t)o * KP + k] = hi;
        c_lo[(size_t)o * KP + k] = lo;
    }
}

// ---------------- CSR build ------------------------------------------------
__global__ void count_k(const int* __restrict__ rows, int* __restrict__ cnt)
{
    int i = blockIdx.x * 256 + threadIdx.x;     // 2*65536 exact
    int s = i >> 16;
    atomicAdd(&cnt[(s << 12) + rows[i]], 1);
}

__global__ __launch_bounds__(1024) void scan_k(const int* __restrict__ cnt, int* __restrict__ rp)
{
    int s = blockIdx.x;
    const int* c = cnt + (s << 12);
    int* r = rp + s * 4097;
    __shared__ int sd[1024];
    int tid = threadIdx.x;
    int i0 = tid * 4;
    int a0 = c[i0], a1 = c[i0 + 1], a2 = c[i0 + 2], a3 = c[i0 + 3];
    sd[tid] = a0 + a1 + a2 + a3;
    __syncthreads();
    for (int off = 1; off < 1024; off <<= 1) {
        int v = (tid >= off) ? sd[tid - off] : 0;
        __syncthreads();
        sd[tid] += v;
        __syncthreads();
    }
    int base = tid ? sd[tid - 1] : 0;
    r[i0] = base; r[i0 + 1] = base + a0; r[i0 + 2] = base + a0 + a1; r[i0 + 3] = base + a0 + a1 + a2;
    if (tid == 1023) r[4096] = sd[1023];
}

// scatter into packed (col, val) CSR stream
__global__ void scatter_k(const int* __restrict__ rows, const int* __restrict__ cols,
                          const float* __restrict__ vals, const int* __restrict__ rp,
                          int* __restrict__ fill, int2* __restrict__ pcv)
{
    int i = blockIdx.x * 256 + threadIdx.x;     // 2*65536 exact
    int s = i >> 16;
    int r = rows[i];
    int pos = rp[s * 4097 + r] + atomicAdd(&fill[(s << 12) + r], 1);
    int2 e; e.x = cols[i]; e.y = __float_as_int(vals[i]);
    pcv[(s << 16) + pos] = e;
}

// ---------------- x0 build: input part --------------------------------------
__global__ void x0i_k(const float* __restrict__ in, float* __restrict__ x0i, int h)
{
    int i = blockIdx.x * 256 + threadIdx.x;     // 4096*32 exact
    int n = i >> 5, bl = i & 31;
    const f32x2 v = *(const f32x2*)(in + (size_t)(h * HB + bl) * 8192 + n * 2);
    __builtin_nontemporal_store(v, (f32x2*)(x0i + (size_t)n * IROW + bl * 2));
}

// ---------------- SpMM v7: register edges + shfl broadcast, no LDS/barriers -
// main: half-wave (32 lanes) = one row x 32 quads; edges chunked 32/row into
// lane registers, broadcast via width-32 shfl. input: 16-lane group = one row
// x 16 quads, width-16 shfl. Waves fully independent.
__global__ __launch_bounds__(256) void spmm_k(
    const float* __restrict__ ss0, const float* __restrict__ si0,
    const float* __restrict__ ss1, const float* __restrict__ si1,
    float* __restrict__ ds0, float* __restrict__ di0,
    float* __restrict__ ds1, float* __restrict__ di1,
    const float* __restrict__ ps, const float* __restrict__ pi,
    const int* __restrict__ rp, const int2* __restrict__ pcv,
    int mode, int hxsm, int hxpm)
{
    const int b = blockIdx.x;
    const int tid = threadIdx.x;
    int s, sub = 0, rowgrp;
    bool is_main;
    if (mode == 0) {
        s = blockIdx.y;
        if (b < 8192) {
            is_main = true;
            const int j = b >> 3;
            sub = (b & 7) * 2 + (j >> 9);
            rowgrp = j & 511;
        } else {
            is_main = false;
            rowgrp = b - 8192;
        }
    } else {
        if (b < 16384) {
            is_main = true;
            const int phase = b >> 12;
            s = phase >> 1;
            sub = (b & 7) * 2 + (phase & 1);
            rowgrp = (b >> 3) & 511;
        } else {
            is_main = false;
            const int j2 = b - 16384;
            s = j2 >> 8;
            rowgrp = j2 & 255;
        }
    }
    const int2* __restrict__ es = pcv + (s << 16);
    const int* __restrict__ rps = rp + s * 4097;
    const int wave = tid >> 6, lane = tid & 63;

    float* __restrict__ dst;
    const float* xb;
    const float* pb;
    int csh, psh, rsh, r, o_, grp, gl, W;
    if (is_main) {
        grp = lane >> 5; gl = lane & 31; W = 32;
        r = rowgrp * 8 + wave * 2 + grp;
        const int q = sub * 32 + gl;
        o_ = q * 4;
        rsh = 11;
        const int blq = q >> 4, fo = (q & 15) * 4;
        const float* xsrc = s ? ss1 : ss0;
        if (hxsm) { xb = xsrc + (size_t)blq * 262144 + fo; csh = 6; }
        else      { xb = xsrc + o_;                        csh = 11; }
        if (hxpm) { pb = ps + (size_t)blq * 262144 + fo;   psh = 6; }
        else      { pb = ps + o_;                          psh = 11; }
        dst = s ? ds1 : ds0;
    } else {
        grp = lane >> 4; gl = lane & 15; W = 16;
        r = rowgrp * 16 + wave * 4 + grp;
        o_ = gl * 4;
        rsh = 6;
        xb = (s ? si1 : si0) + o_; csh = 6;
        pb = pi + o_;              psh = 6;
        dst = s ? di1 : di0;
    }
    const int pS = rps[r];
    const int cnt = rps[r + 1] - pS;

    f32x4 a0 = {0,0,0,0}, a1 = {0,0,0,0}, a2 = {0,0,0,0}, a3 = {0,0,0,0};
    for (int b2 = 0; b2 < cnt; b2 += W) {
        const int rem = cnt - b2;
        int2 E; E.x = 0; E.y = 0;
        if (gl < rem) E = es[pS + b2 + gl];
        const int n2 = rem < W ? rem : W;
        int j = 0;
        for (; j + 4 <= n2; j += 4) {
            const int c0 = __shfl(E.x, j + 0, W), v0 = __shfl(E.y, j + 0, W);
            const int c1 = __shfl(E.x, j + 1, W), v1 = __shfl(E.y, j + 1, W);
            const int c2 = __shfl(E.x, j + 2, W), v2 = __shfl(E.y, j + 2, W);
            const int c3 = __shfl(E.x, j + 3, W), v3 = __shfl(E.y, j + 3, W);
            const f32x4 x0v = *(const f32x4*)(xb + ((size_t)c0 << csh));
            const f32x4 x1v = *(const f32x4*)(xb + ((size_t)c1 << csh));
            const f32x4 x2v = *(const f32x4*)(xb + ((size_t)c2 << csh));
            const f32x4 x3v = *(const f32x4*)(xb + ((size_t)c3 << csh));
            a0 = fma4(__int_as_float(v0), x0v, a0);
            a1 = fma4(__int_as_float(v1), x1v, a1);
            a2 = fma4(__int_as_float(v2), x2v, a2);
            a3 = fma4(__int_as_float(v3), x3v, a3);
        }
        for (; j < n2; ++j) {
            const int c0 = __shfl(E.x, j, W), v0 = __shfl(E.y, j, W);
            const f32x4 x0v = *(const f32x4*)(xb + ((size_t)c0 << csh));
            a0 = fma4(__int_as_float(v0), x0v, a0);
        }
    }
    f32x4 R;
    R.x = (a0.x + a1.x) + (a2.x + a3.x);
    R.y = (a0.y + a1.y) + (a2.y + a3.y);
    R.z = (a0.z + a1.z) + (a2.z + a3.z);
    R.w = (a0.w + a1.w) + (a2.w + a3.w);

    if (mode) {
        const f32x4 pv = __builtin_nontemporal_load((const f32x4*)(pb + ((size_t)r << psh)));
        R.x = 2.0f * R.x - pv.x; R.y = 2.0f * R.y - pv.y;
        R.z = 2.0f * R.z - pv.z; R.w = 2.0f * R.w - pv.w;
    }
    __builtin_nontemporal_store(R, (f32x4*)(dst + ((size_t)r << rsh) + o_));
}

// ------ mm staging (NT-thread generic): x -> hi-plane bf16 LDS --------------
template<int NT>
__device__ __forceinline__ void stage_hi(const float* __restrict__ xs, const float* __restrict__ xi,
                                         const float* __restrict__ m0s, int m0hx,
                                         int n, int tid, uint* __restrict__ Bhi)
{
    for (int i = tid; i < 480; i += NT) {       // zero K-pad words 165..179 per b-row
        int bl = i / 15, t = i - bl * 15;
        Bhi[bl * 180 + 165 + t] = 0u;
    }
    for (int i = tid; i < 2560; i += NT) {      // state: 5 m x 32 bl x 16 quads
        int m = i >> 9, rem = i & 511, bl = rem >> 4, fq = rem & 15;
        const float* p;
        if (m == 0)
            p = m0hx ? m0s + (size_t)bl * 262144 + (size_t)n * 64 + fq * 4
                     : m0s + (size_t)n * SROW + bl * 64 + fq * 4;
        else
            p = xs + (size_t)m * SLVL + (size_t)n * SROW + bl * 64 + fq * 4;
        const f32x4 v = __builtin_nontemporal_load((const f32x4*)p);
        const int base = bl * 180 + m * 33 + 1 + fq * 2;
        Bhi[base]     = pkhi2(v.x, v.y);
        Bhi[base + 1] = pkhi2(v.z, v.w);
    }
    for (int i = tid; i < 160; i += NT) {       // input: 5 m x 32 bl
        int m = i >> 5, bl = i & 31;
        const f32x2 v = __builtin_nontemporal_load(
            (const f32x2*)(xi + (size_t)m * ILVL + (size_t)n * IROW + bl * 2));
        Bhi[bl * 180 + m * 33] = pkhi2(v.x, v.y);
    }
}

#define MFMA(a, b, c) __builtin_amdgcn_mfma_f32_16x16x32_bf16(a, b, c, 0, 0, 0)

// -------- gconv1 matmul: W resident in VGPRs, 8 nodes streamed per block ----
__global__ __launch_bounds__(512, 4) void mm_ru_k(const float* __restrict__ xs, const float* __restrict__ xi,
                                                  const ushort* __restrict__ whi, const ushort* __restrict__ wlo,
                                                  const float* __restrict__ bru, const float* __restrict__ hx,
                                                  float* __restrict__ uout, float* __restrict__ xs0s, int h)
{
    const int tid = threadIdx.x;
    const int lane = tid & 63, wave = tid >> 6;
    __shared__ uint Bbuf[2][5760];
    const int n0 = blockIdx.x * NPB;
    const float* hxs = hx + (size_t)h * HB * 262144;

    const int ob = wave * 16 + (lane & 15);
    const int ksub = (lane >> 4) * 8;
    const int brow = lane & 15;
    short8 Ah[KSTEPS], Al[KSTEPS];
    #pragma unroll
    for (int ks = 0; ks < KSTEPS; ++ks) {
        Ah[ks] = *(const short8*)(whi + (size_t)ob * KP + ks * 32 + ksub);
        Al[ks] = *(const short8*)(wlo + (size_t)ob * KP + ks * 32 + ksub);
    }
    const int g = lane >> 4, bcol = lane & 15;
    const int o = wave * 16 + g * 4;
    const float bb0 = bru[o], bb1 = bru[o + 1], bb2 = bru[o + 2], bb3 = bru[o + 3];

    stage_hi<512>(xs, xi, hxs, 1, n0, tid, Bbuf[0]);

    for (int i = 0; i < NPB; ++i) {
        __syncthreads();
        if (i + 1 < NPB)
            stage_hi<512>(xs, xi, hxs, 1, n0 + i + 1, tid, Bbuf[(i + 1) & 1]);
        const ushort* BH = (const ushort*)Bbuf[i & 1];
        const int n = n0 + i;
        f32x4 acc[2] = {};
        #pragma unroll
        for (int ks = 0; ks < KSTEPS; ++ks) {
            const int ko = ks * 32 + ksub;
            short8 Bh0 = *(const short8*)(BH + brow * 360 + ko);
            short8 Bh1 = *(const short8*)(BH + (16 + brow) * 360 + ko);
            acc[0] = MFMA(Ah[ks], Bh0, acc[0]);
            acc[1] = MFMA(Ah[ks], Bh1, acc[1]);
            acc[0] = MFMA(Al[ks], Bh0, acc[0]);
            acc[1] = MFMA(Al[ks], Bh1, acc[1]);
        }
        #pragma unroll
        for (int bt = 0; bt < 2; ++bt) {
            const int bl = bt * 16 + bcol;
            float s0 = sigm(acc[bt][0] + bb0);
            float s1 = sigm(acc[bt][1] + bb1);
            float s2 = sigm(acc[bt][2] + bb2);
            float s3 = sigm(acc[bt][3] + bb3);
            if (wave < 4) {     // r-part: r*hx -> x0 state
                const f32x4 hxv = *(const f32x4*)(hx + (size_t)(h * HB + bl) * 262144 + (size_t)n * 64 + o);
                f32x4 rv;
                rv[0] = s0 * hxv[0]; rv[1] = s1 * hxv[1];
                rv[2] = s2 * hxv[2]; rv[3] = s3 * hxv[3];
                *(f32x4*)(xs0s + (size_t)n * SROW + bl * 64 + o) = rv;
            } else {            // u-part -> d_out (temporary storage)
                f32x4 uv = {s0, s1, s2, s3};
                *(f32x4*)(uout + (size_t)(h * HB + bl) * 262144 + (size_t)n * 64 + (o - 64)) = uv;
            }
        }
    }
}

// -------- gconv2 matmul: W resident, 8 nodes per block, 4 waves -------------
__global__ __launch_bounds__(256, 4) void mm_c_k(const float* __restrict__ xs, const float* __restrict__ xi,
                                                 const ushort* __restrict__ whi, const ushort* __restrict__ wlo,
                                                 const float* __restrict__ bc, const float* __restrict__ hx,
                                                 float* __restrict__ out, int h)
{
    const int tid = threadIdx.x;
    const int lane = tid & 63, wave = tid >> 6;
    __shared__ uint Bbuf[2][5760];
    const int n0 = blockIdx.x * NPB;

    const int ob = wave * 16 + (lane & 15);
    const int ksub = (lane >> 4) * 8;
    const int brow = lane & 15;
    short8 Ah[KSTEPS], Al[KSTEPS];
    #pragma unroll
    for (int ks = 0; ks < KSTEPS; ++ks) {
        Ah[ks] = *(const short8*)(whi + (size_t)ob * KP + ks * 32 + ksub);
        Al[ks] = *(const short8*)(wlo + (size_t)ob * KP + ks * 32 + ksub);
    }
    const int g = lane >> 4, bcol = lane & 15;
    const int o = wave * 16 + g * 4;
    const float bb0 = bc[o], bb1 = bc[o + 1], bb2 = bc[o + 2], bb3 = bc[o + 3];

    stage_hi<256>(xs, xi, xs, 0, n0, tid, Bbuf[0]);

    for (int i = 0; i < NPB; ++i) {
        __syncthreads();
        if (i + 1 < NPB)
            stage_hi<256>(xs, xi, xs, 0, n0 + i + 1, tid, Bbuf[(i + 1) & 1]);
        const ushort* BH = (const ushort*)Bbuf[i & 1];
        const int n = n0 + i;
        f32x4 acc[2] = {};
        #pragma unroll
        for (int ks = 0; ks < KSTEPS; ++ks) {
            const int ko = ks * 32 + ksub;
            short8 Bh0 = *(const short8*)(BH + brow * 360 + ko);
            short8 Bh1 = *(const short8*)(BH + (16 + brow) * 360 + ko);
            acc[0] = MFMA(Ah[ks], Bh0, acc[0]);
            acc[1] = MFMA(Ah[ks], Bh1, acc[1]);
            acc[0] = MFMA(Al[ks], Bh0, acc[0]);
            acc[1] = MFMA(Al[ks], Bh1, acc[1]);
        }
        #pragma unroll
        for (int bt = 0; bt < 2; ++bt) {
            const int bl = bt * 16 + bcol;
            float c0 = tanh_fast(acc[bt][0] + bb0);
            float c1 = tanh_fast(acc[bt][1] + bb1);
            float c2 = tanh_fast(acc[bt][2] + bb2);
            float c3 = tanh_fast(acc[bt][3] + bb3);
            float* p = out + (size_t)(h * HB + bl) * 262144 + (size_t)n * 64 + o;
            const f32x4 hxv = *(const f32x4*)(hx + (size_t)(h * HB + bl) * 262144 + (size_t)n * 64 + o);
            f32x4 uv = *(const f32x4*)p;
            f32x4 ov;
            ov[0] = uv[0] * hxv[0] + (1.0f - uv[0]) * c0;
            ov[1] = uv[1] * hxv[1] + (1.0f - uv[1]) * c1;
            ov[2] = uv[2] * hxv[2] + (1.0f - uv[2]) * c2;
            ov[3] = uv[3] * hxv[3] + (1.0f - uv[3]) * c3;
            *(f32x4*)p = ov;
        }
    }
}

// ---------------------------------------------------------------------------
extern "C" void kernel_launch(void* const* d_in, const int* in_sizes, int n_in,
                              void* d_out, int out_size, void* d_ws, size_t ws_size,
                              hipStream_t stream)
{
    (void)in_sizes; (void)n_in; (void)out_size; (void)ws_size;
    const float* inputs  = (const float*)d_in[0];
    const float* hx      = (const float*)d_in[1];
    const int*   sup_rows= (const int*)d_in[2];
    const int*   sup_cols= (const int*)d_in[3];
    const float* sup_vals= (const float*)d_in[4];
    const float* W_ru    = (const float*)d_in[5];
    const float* b_ru    = (const float*)d_in[6];
    const float* W_c     = (const float*)d_in[7];
    const float* b_c     = (const float*)d_in[8];
    float* out = (float*)d_out;

    char* ws = (char*)d_ws;
    float* xs = (float*)ws;                                 // 5 state levels: 167.8 MB
    float* xi = xs + 5ull * SLVL;                           // 5 input levels: 5.2 MB
    size_t off = (5ull * SLVL + 5ull * ILVL) * 4ull;        // 173,015,040
    ushort* wru_hi = (ushort*)(ws + off); off += 90112;
    ushort* wru_lo = (ushort*)(ws + off); off += 90112;
    ushort* wc_hi  = (ushort*)(ws + off); off += 45056;
    ushort* wc_lo  = (ushort*)(ws + off); off += 45056;
    int* row_ptr   = (int*)(ws + off);    off += 32800;
    int* cntfill   = (int*)(ws + off);    off += 65536;
    int2* pcv      = (int2*)(ws + off);   off += 1048576;   // packed (col,val) CSR

    #define XS(m) (xs + (size_t)(m) * SLVL)
    #define XI(m) (xi + (size_t)(m) * ILVL)
    int* fill = cntfill + 8192;

    zero_k<<<64, 256, 0, stream>>>(cntfill);
    wtbuild_k<<<264, 256, 0, stream>>>(W_ru, W_c, wru_hi, wru_lo, wc_hi, wc_lo);
    count_k<<<512, 256, 0, stream>>>(sup_rows, cntfill);
    scan_k<<<2, 1024, 0, stream>>>(cntfill, row_ptr);
    scatter_k<<<512, 256, 0, stream>>>(sup_rows, sup_cols, sup_vals, row_ptr, fill, pcv);

    for (int h = 0; h < 2; ++h) {
        const float* hxs = hx + (size_t)h * HB * 262144;
        x0i_k<<<512, 256, 0, stream>>>(inputs, XI(0), h);
        // gconv1 diffusion: step1 reads hx in place (hxsm); step2 prev = hx (hxpm)
        spmm_k<<<dim3(8448, 2), 256, 0, stream>>>(hxs, XI(0), hxs, XI(0),
                                                  XS(1), XI(1), XS(3), XI(3),
                                                  hxs, XI(0), row_ptr, pcv, 0, 1, 0);
        spmm_k<<<dim3(16896, 1), 256, 0, stream>>>(XS(1), XI(1), XS(3), XI(3),
                                                   XS(2), XI(2), XS(4), XI(4),
                                                   hxs, XI(0), row_ptr, pcv, 1, 0, 1);
        // gconv1 matmul: u -> out, r*hx -> x0 state part (m0 staged from hx)
        mm_ru_k<<<NN / NPB, 512, 0, stream>>>(xs, xi, wru_hi, wru_lo, b_ru, hx, out, XS(0), h);
        // gconv2 diffusion (x0 = [inputs, r*hx], all linear)
        spmm_k<<<dim3(8448, 2), 256, 0, stream>>>(XS(0), XI(0), XS(0), XI(0),
                                                  XS(1), XI(1), XS(3), XI(3),
                                                  XS(0), XI(0), row_ptr, pcv, 0, 0, 0);
        spmm_k<<<dim3(16896, 1), 256, 0, stream>>>(XS(1), XI(1), XS(3), XI(3),
                                                   XS(2), XI(2), XS(4), XI(4),
                                                   XS(0), XI(0), row_ptr, pcv, 1, 0, 0);
        // gconv2 matmul + tanh + final GRU combine
        mm_c_k<<<NN / NPB, 256, 0, stream>>>(xs, xi, wc_hi, wc_lo, b_c, hx, out, h);
    }
    #undef XS
    #undef XI
}

// Round 12
// 746.469 us; speedup vs baseline: 2.4704x; 1.1329x over previous
//
#include <hip/hip_runtime.h>

typedef float f32x4 __attribute__((ext_vector_type(4)));
typedef float f32x2 __attribute__((ext_vector_type(2)));
typedef short short8 __attribute__((ext_vector_type(8)));

#define NN 4096
#define HB 32               // half batch
#define SROW 2048           // state f32 per node row (32 b x 64 f), 1<<11
#define IROW 64             // input f32 per node row (32 b x 2 f), 1<<6
#define SLVL 8388608ull     // f32 per state level (NN*SROW)
#define ILVL 262144ull      // f32 per input level (NN*IROW)
#define KP 352              // padded K (330 real)
#define KSTEPS 11
#define NPB 8               // nodes per mm block

__device__ __forceinline__ ushort f2bf(float f){ uint i = __float_as_uint(f); return (ushort)((i + 0x7fffu + ((i >> 16) & 1u)) >> 16); }
__device__ __forceinline__ float bf2f(ushort u){ return __uint_as_float((uint)u << 16); }
__device__ __forceinline__ uint pkhi2(float a, float b){ return (uint)f2bf(a) | ((uint)f2bf(b) << 16); }
__device__ __forceinline__ float sigm(float x){ return 1.0f / (1.0f + __expf(-x)); }
__device__ __forceinline__ float tanh_fast(float x){
    x = fminf(20.0f, fmaxf(-20.0f, x));
    float t = __expf(-2.0f * x);
    return (1.0f - t) / (1.0f + t);
}
__device__ __forceinline__ f32x4 fma4(float v, f32x4 x, f32x4 a){
    a.x = fmaf(v, x.x, a.x); a.y = fmaf(v, x.y, a.y);
    a.z = fmaf(v, x.z, a.z); a.w = fmaf(v, x.w, a.w);
    return a;
}

// ---------------- zero scratch (cnt+fill), graph-capture-safe ---------------
__global__ void zero_k(int* __restrict__ p){ p[blockIdx.x * 256 + threadIdx.x] = 0; }

// ------- weight transform: Wt_hi/lo[o][k], k = m*66+f, bf16 hi/lo split -----
__global__ void wtbuild_k(const float* __restrict__ Wru, const float* __restrict__ Wc,
                          ushort* __restrict__ ru_hi, ushort* __restrict__ ru_lo,
                          ushort* __restrict__ c_hi,  ushort* __restrict__ c_lo)
{
    int idx = blockIdx.x * 256 + threadIdx.x;   // 192*352 exact
    float w = 0.0f;
    if (idx < 128 * KP) {
        int o = idx / KP, k = idx - o * KP;
        if (k < 330) { int m = k / 66, f = k - m * 66; w = Wru[(size_t)(f * 5 + m) * 128 + o]; }
        ushort hi = f2bf(w);
        ushort lo = f2bf(w - bf2f(hi));
        ru_hi[(size_t)o * KP + k] = hi;
        ru_lo[(size_t)o * KP + k] = lo;
    } else {
        int j = idx - 128 * KP;
        int o = j / KP, k = j - o * KP;
        if (k < 330) { int m = k / 66, f = k - m * 66; w = Wc[(size_t)(f * 5 + m) * 64 + o]; }
        ushort hi = f2bf(w);
        ushort lo = f2bf(w - bf2f(hi));
        c_hi[(size_t)o * KP + k] = hi;
        c_lo[(size_t)o * KP + k] = lo;
    }
}

// ---------------- CSR build ------------------------------------------------
__global__ void count_k(const int* __restrict__ rows, int* __restrict__ cnt)
{
    int i = blockIdx.x * 256 + threadIdx.x;     // 2*65536 exact
    int s = i >> 16;
    atomicAdd(&cnt[(s << 12) + rows[i]], 1);
}

__global__ __launch_bounds__(1024) void scan_k(const int* __restrict__ cnt, int* __restrict__ rp)
{
    int s = blockIdx.x;
    const int* c = cnt + (s << 12);
    int* r = rp + s * 4097;
    __shared__ int sd[1024];
    int tid = threadIdx.x;
    int i0 = tid * 4;
    int a0 = c[i0], a1 = c[i0 + 1], a2 = c[i0 + 2], a3 = c[i0 + 3];
    sd[tid] = a0 + a1 + a2 + a3;
    __syncthreads();
    for (int off = 1; off < 1024; off <<= 1) {
        int v = (tid >= off) ? sd[tid - off] : 0;
        __syncthreads();
        sd[tid] += v;
        __syncthreads();
    }
    int base = tid ? sd[tid - 1] : 0;
    r[i0] = base; r[i0 + 1] = base + a0; r[i0 + 2] = base + a0 + a1; r[i0 + 3] = base + a0 + a1 + a2;
    if (tid == 1023) r[4096] = sd[1023];
}

// scatter into packed (col, val) CSR stream
__global__ void scatter_k(const int* __restrict__ rows, const int* __restrict__ cols,
                          const float* __restrict__ vals, const int* __restrict__ rp,
                          int* __restrict__ fill, int2* __restrict__ pcv)
{
    int i = blockIdx.x * 256 + threadIdx.x;     // 2*65536 exact
    int s = i >> 16;
    int r = rows[i];
    int pos = rp[s * 4097 + r] + atomicAdd(&fill[(s << 12) + r], 1);
    int2 e; e.x = cols[i]; e.y = __float_as_int(vals[i]);
    pcv[(s << 16) + pos] = e;
}

// ---------------- x0 build: input part --------------------------------------
__global__ void x0i_k(const float* __restrict__ in, float* __restrict__ x0i, int h)
{
    int i = blockIdx.x * 256 + threadIdx.x;     // 4096*32 exact
    int n = i >> 5, bl = i & 31;
    const f32x2 v = *(const f32x2*)(in + (size_t)(h * HB + bl) * 8192 + n * 2);
    *(f32x2*)(x0i + (size_t)n * IROW + bl * 2) = v;
}

// ---------------- SpMM v8: register edges + shfl, cache-friendly ------------
__global__ __launch_bounds__(256) void spmm_k(
    const float* __restrict__ ss0, const float* __restrict__ si0,
    const float* __restrict__ ss1, const float* __restrict__ si1,
    float* __restrict__ ds0, float* __restrict__ di0,
    float* __restrict__ ds1, float* __restrict__ di1,
    const float* __restrict__ ps, const float* __restrict__ pi,
    const int* __restrict__ rp, const int2* __restrict__ pcv,
    int mode, int hxsm, int hxpm)
{
    const int b = blockIdx.x;
    const int tid = threadIdx.x;
    int s, sub = 0, rowgrp;
    bool is_main;
    if (mode == 0) {
        s = blockIdx.y;
        if (b < 8192) {
            is_main = true;
            const int j = b >> 3;
            sub = (b & 7) * 2 + (j >> 9);
            rowgrp = j & 511;
        } else {
            is_main = false;
            rowgrp = b - 8192;
        }
    } else {
        if (b < 16384) {
            is_main = true;
            const int phase = b >> 12;
            s = phase >> 1;
            sub = (b & 7) * 2 + (phase & 1);
            rowgrp = (b >> 3) & 511;
        } else {
            is_main = false;
            const int j2 = b - 16384;
            s = j2 >> 8;
            rowgrp = j2 & 255;
        }
    }
    const int2* __restrict__ es = pcv + (s << 16);
    const int* __restrict__ rps = rp + s * 4097;
    const int wave = tid >> 6, lane = tid & 63;

    float* __restrict__ dst;
    const float* xb;
    const float* pb;
    int csh, psh, rsh, r, o_, grp, gl, W;
    if (is_main) {
        grp = lane >> 5; gl = lane & 31; W = 32;
        r = rowgrp * 8 + wave * 2 + grp;
        const int q = sub * 32 + gl;
        o_ = q * 4;
        rsh = 11;
        const int blq = q >> 4, fo = (q & 15) * 4;
        const float* xsrc = s ? ss1 : ss0;
        if (hxsm) { xb = xsrc + (size_t)blq * 262144 + fo; csh = 6; }
        else      { xb = xsrc + o_;                        csh = 11; }
        if (hxpm) { pb = ps + (size_t)blq * 262144 + fo;   psh = 6; }
        else      { pb = ps + o_;                          psh = 11; }
        dst = s ? ds1 : ds0;
    } else {
        grp = lane >> 4; gl = lane & 15; W = 16;
        r = rowgrp * 16 + wave * 4 + grp;
        o_ = gl * 4;
        rsh = 6;
        xb = (s ? si1 : si0) + o_; csh = 6;
        pb = pi + o_;              psh = 6;
        dst = s ? di1 : di0;
    }
    const int pS = rps[r];
    const int cnt = rps[r + 1] - pS;

    f32x4 a0 = {0,0,0,0}, a1 = {0,0,0,0}, a2 = {0,0,0,0}, a3 = {0,0,0,0};
    for (int b2 = 0; b2 < cnt; b2 += W) {
        const int rem = cnt - b2;
        int2 E; E.x = 0; E.y = 0;
        if (gl < rem) E = es[pS + b2 + gl];
        const int n2 = rem < W ? rem : W;
        int j = 0;
        for (; j + 4 <= n2; j += 4) {
            const int c0 = __shfl(E.x, j + 0, W), v0 = __shfl(E.y, j + 0, W);
            const int c1 = __shfl(E.x, j + 1, W), v1 = __shfl(E.y, j + 1, W);
            const int c2 = __shfl(E.x, j + 2, W), v2 = __shfl(E.y, j + 2, W);
            const int c3 = __shfl(E.x, j + 3, W), v3 = __shfl(E.y, j + 3, W);
            const f32x4 x0v = *(const f32x4*)(xb + ((size_t)c0 << csh));
            const f32x4 x1v = *(const f32x4*)(xb + ((size_t)c1 << csh));
            const f32x4 x2v = *(const f32x4*)(xb + ((size_t)c2 << csh));
            const f32x4 x3v = *(const f32x4*)(xb + ((size_t)c3 << csh));
            a0 = fma4(__int_as_float(v0), x0v, a0);
            a1 = fma4(__int_as_float(v1), x1v, a1);
            a2 = fma4(__int_as_float(v2), x2v, a2);
            a3 = fma4(__int_as_float(v3), x3v, a3);
        }
        for (; j < n2; ++j) {
            const int c0 = __shfl(E.x, j, W), v0 = __shfl(E.y, j, W);
            const f32x4 x0v = *(const f32x4*)(xb + ((size_t)c0 << csh));
            a0 = fma4(__int_as_float(v0), x0v, a0);
        }
    }
    f32x4 R;
    R.x = (a0.x + a1.x) + (a2.x + a3.x);
    R.y = (a0.y + a1.y) + (a2.y + a3.y);
    R.z = (a0.z + a1.z) + (a2.z + a3.z);
    R.w = (a0.w + a1.w) + (a2.w + a3.w);

    if (mode) {
        const f32x4 pv = *(const f32x4*)(pb + ((size_t)r << psh));
        R.x = 2.0f * R.x - pv.x; R.y = 2.0f * R.y - pv.y;
        R.z = 2.0f * R.z - pv.z; R.w = 2.0f * R.w - pv.w;
    }
    *(f32x4*)(dst + ((size_t)r << rsh) + o_) = R;
}

// ------ mm staging (NT-thread generic): x -> hi-plane bf16 LDS --------------
template<int NT>
__device__ __forceinline__ void stage_hi(const float* __restrict__ xs, const float* __restrict__ xi,
                                         const float* __restrict__ m0s, int m0hx,
                                         int n, int tid, uint* __restrict__ Bhi)
{
    for (int i = tid; i < 480; i += NT) {       // zero K-pad words 165..179 per b-row
        int bl = i / 15, t = i - bl * 15;
        Bhi[bl * 180 + 165 + t] = 0u;
    }
    for (int i = tid; i < 2560; i += NT) {      // state: 5 m x 32 bl x 16 quads
        int m = i >> 9, rem = i & 511, bl = rem >> 4, fq = rem & 15;
        const float* p;
        if (m == 0)
            p = m0hx ? m0s + (size_t)bl * 262144 + (size_t)n * 64 + fq * 4
                     : m0s + (size_t)n * SROW + bl * 64 + fq * 4;
        else
            p = xs + (size_t)m * SLVL + (size_t)n * SROW + bl * 64 + fq * 4;
        const f32x4 v = *(const f32x4*)p;
        const int base = bl * 180 + m * 33 + 1 + fq * 2;
        Bhi[base]     = pkhi2(v.x, v.y);
        Bhi[base + 1] = pkhi2(v.z, v.w);
    }
    for (int i = tid; i < 160; i += NT) {       // input: 5 m x 32 bl
        int m = i >> 5, bl = i & 31;
        const f32x2 v = *(const f32x2*)(xi + (size_t)m * ILVL + (size_t)n * IROW + bl * 2);
        Bhi[bl * 180 + m * 33] = pkhi2(v.x, v.y);
    }
}

#define MFMA(a, b, c) __builtin_amdgcn_mfma_f32_16x16x32_bf16(a, b, c, 0, 0, 0)

// -------- gconv1 matmul: W resident in VGPRs, 8 nodes streamed per block ----
__global__ __launch_bounds__(512, 4) void mm_ru_k(const float* __restrict__ xs, const float* __restrict__ xi,
                                                  const ushort* __restrict__ whi, const ushort* __restrict__ wlo,
                                                  const float* __restrict__ bru, const float* __restrict__ hx,
                                                  float* __restrict__ uout, float* __restrict__ xs0s, int h)
{
    const int tid = threadIdx.x;
    const int lane = tid & 63, wave = tid >> 6;
    __shared__ uint Bbuf[2][5760];
    const int n0 = blockIdx.x * NPB;
    const float* hxs = hx + (size_t)h * HB * 262144;

    const int ob = wave * 16 + (lane & 15);
    const int ksub = (lane >> 4) * 8;
    const int brow = lane & 15;
    short8 Ah[KSTEPS], Al[KSTEPS];
    #pragma unroll
    for (int ks = 0; ks < KSTEPS; ++ks) {
        Ah[ks] = *(const short8*)(whi + (size_t)ob * KP + ks * 32 + ksub);
        Al[ks] = *(const short8*)(wlo + (size_t)ob * KP + ks * 32 + ksub);
    }
    const int g = lane >> 4, bcol = lane & 15;
    const int o = wave * 16 + g * 4;
    const float bb0 = bru[o], bb1 = bru[o + 1], bb2 = bru[o + 2], bb3 = bru[o + 3];

    stage_hi<512>(xs, xi, hxs, 1, n0, tid, Bbuf[0]);

    for (int i = 0; i < NPB; ++i) {
        __syncthreads();
        if (i + 1 < NPB)
            stage_hi<512>(xs, xi, hxs, 1, n0 + i + 1, tid, Bbuf[(i + 1) & 1]);
        const ushort* BH = (const ushort*)Bbuf[i & 1];
        const int n = n0 + i;
        f32x4 acc[2] = {};
        #pragma unroll
        for (int ks = 0; ks < KSTEPS; ++ks) {
            const int ko = ks * 32 + ksub;
            short8 Bh0 = *(const short8*)(BH + brow * 360 + ko);
            short8 Bh1 = *(const short8*)(BH + (16 + brow) * 360 + ko);
            acc[0] = MFMA(Ah[ks], Bh0, acc[0]);
            acc[1] = MFMA(Ah[ks], Bh1, acc[1]);
            acc[0] = MFMA(Al[ks], Bh0, acc[0]);
            acc[1] = MFMA(Al[ks], Bh1, acc[1]);
        }
        #pragma unroll
        for (int bt = 0; bt < 2; ++bt) {
            const int bl = bt * 16 + bcol;
            float s0 = sigm(acc[bt][0] + bb0);
            float s1 = sigm(acc[bt][1] + bb1);
            float s2 = sigm(acc[bt][2] + bb2);
            float s3 = sigm(acc[bt][3] + bb3);
            if (wave < 4) {     // r-part: r*hx -> x0 state
                const f32x4 hxv = *(const f32x4*)(hx + (size_t)(h * HB + bl) * 262144 + (size_t)n * 64 + o);
                f32x4 rv;
                rv[0] = s0 * hxv[0]; rv[1] = s1 * hxv[1];
                rv[2] = s2 * hxv[2]; rv[3] = s3 * hxv[3];
                *(f32x4*)(xs0s + (size_t)n * SROW + bl * 64 + o) = rv;
            } else {            // u-part -> d_out (temporary storage)
                f32x4 uv = {s0, s1, s2, s3};
                *(f32x4*)(uout + (size_t)(h * HB + bl) * 262144 + (size_t)n * 64 + (o - 64)) = uv;
            }
        }
    }
}

// -------- gconv2 matmul: W resident, 8 nodes per block, 4 waves -------------
__global__ __launch_bounds__(256, 4) void mm_c_k(const float* __restrict__ xs, const float* __restrict__ xi,
                                                 const ushort* __restrict__ whi, const ushort* __restrict__ wlo,
                                                 const float* __restrict__ bc, const float* __restrict__ hx,
                                                 float* __restrict__ out, int h)
{
    const int tid = threadIdx.x;
    const int lane = tid & 63, wave = tid >> 6;
    __shared__ uint Bbuf[2][5760];
    const int n0 = blockIdx.x * NPB;

    const int ob = wave * 16 + (lane & 15);
    const int ksub = (lane >> 4) * 8;
    const int brow = lane & 15;
    short8 Ah[KSTEPS], Al[KSTEPS];
    #pragma unroll
    for (int ks = 0; ks < KSTEPS; ++ks) {
        Ah[ks] = *(const short8*)(whi + (size_t)ob * KP + ks * 32 + ksub);
        Al[ks] = *(const short8*)(wlo + (size_t)ob * KP + ks * 32 + ksub);
    }
    const int g = lane >> 4, bcol = lane & 15;
    const int o = wave * 16 + g * 4;
    const float bb0 = bc[o], bb1 = bc[o + 1], bb2 = bc[o + 2], bb3 = bc[o + 3];

    stage_hi<256>(xs, xi, xs, 0, n0, tid, Bbuf[0]);

    for (int i = 0; i < NPB; ++i) {
        __syncthreads();
        if (i + 1 < NPB)
            stage_hi<256>(xs, xi, xs, 0, n0 + i + 1, tid, Bbuf[(i + 1) & 1]);
        const ushort* BH = (const ushort*)Bbuf[i & 1];
        const int n = n0 + i;
        f32x4 acc[2] = {};
        #pragma unroll
        for (int ks = 0; ks < KSTEPS; ++ks) {
            const int ko = ks * 32 + ksub;
            short8 Bh0 = *(const short8*)(BH + brow * 360 + ko);
            short8 Bh1 = *(const short8*)(BH + (16 + brow) * 360 + ko);
            acc[0] = MFMA(Ah[ks], Bh0, acc[0]);
            acc[1] = MFMA(Ah[ks], Bh1, acc[1]);
            acc[0] = MFMA(Al[ks], Bh0, acc[0]);
            acc[1] = MFMA(Al[ks], Bh1, acc[1]);
        }
        #pragma unroll
        for (int bt = 0; bt < 2; ++bt) {
            const int bl = bt * 16 + bcol;
            float c0 = tanh_fast(acc[bt][0] + bb0);
            float c1 = tanh_fast(acc[bt][1] + bb1);
            float c2 = tanh_fast(acc[bt][2] + bb2);
            float c3 = tanh_fast(acc[bt][3] + bb3);
            float* p = out + (size_t)(h * HB + bl) * 262144 + (size_t)n * 64 + o;
            const f32x4 hxv = *(const f32x4*)(hx + (size_t)(h * HB + bl) * 262144 + (size_t)n * 64 + o);
            f32x4 uv = *(const f32x4*)p;
            f32x4 ov;
            ov[0] = uv[0] * hxv[0] + (1.0f - uv[0]) * c0;
            ov[1] = uv[1] * hxv[1] + (1.0f - uv[1]) * c1;
            ov[2] = uv[2] * hxv[2] + (1.0f - uv[2]) * c2;
            ov[3] = uv[3] * hxv[3] + (1.0f - uv[3]) * c3;
            *(f32x4*)p = ov;
        }
    }
}

// ---------------------------------------------------------------------------
extern "C" void kernel_launch(void* const* d_in, const int* in_sizes, int n_in,
                              void* d_out, int out_size, void* d_ws, size_t ws_size,
                              hipStream_t stream)
{
    (void)in_sizes; (void)n_in; (void)out_size; (void)ws_size;
    const float* inputs  = (const float*)d_in[0];
    const float* hx      = (const float*)d_in[1];
    const int*   sup_rows= (const int*)d_in[2];
    const int*   sup_cols= (const int*)d_in[3];
    const float* sup_vals= (const float*)d_in[4];
    const float* W_ru    = (const float*)d_in[5];
    const float* b_ru    = (const float*)d_in[6];
    const float* W_c     = (const float*)d_in[7];
    const float* b_c     = (const float*)d_in[8];
    float* out = (float*)d_out;

    char* ws = (char*)d_ws;
    float* xs = (float*)ws;                                 // 5 state levels: 167.8 MB
    float* xi = xs + 5ull * SLVL;                           // 5 input levels: 5.2 MB
    size_t off = (5ull * SLVL + 5ull * ILVL) * 4ull;        // 173,015,040
    ushort* wru_hi = (ushort*)(ws + off); off += 90112;
    ushort* wru_lo = (ushort*)(ws + off); off += 90112;
    ushort* wc_hi  = (ushort*)(ws + off); off += 45056;
    ushort* wc_lo  = (ushort*)(ws + off); off += 45056;
    int* row_ptr   = (int*)(ws + off);    off += 32800;
    int* cntfill   = (int*)(ws + off);    off += 65536;
    int2* pcv      = (int2*)(ws + off);   off += 1048576;   // packed (col,val) CSR

    #define XS(m) (xs + (size_t)(m) * SLVL)
    #define XI(m) (xi + (size_t)(m) * ILVL)
    int* fill = cntfill + 8192;

    zero_k<<<64, 256, 0, stream>>>(cntfill);
    wtbuild_k<<<264, 256, 0, stream>>>(W_ru, W_c, wru_hi, wru_lo, wc_hi, wc_lo);
    count_k<<<512, 256, 0, stream>>>(sup_rows, cntfill);
    scan_k<<<2, 1024, 0, stream>>>(cntfill, row_ptr);
    scatter_k<<<512, 256, 0, stream>>>(sup_rows, sup_cols, sup_vals, row_ptr, fill, pcv);

    for (int h = 0; h < 2; ++h) {
        const float* hxs = hx + (size_t)h * HB * 262144;
        x0i_k<<<512, 256, 0, stream>>>(inputs, XI(0), h);
        // gconv1 diffusion: step1 reads hx in place (hxsm); step2 prev = hx (hxpm)
        spmm_k<<<dim3(8448, 2), 256, 0, stream>>>(hxs, XI(0), hxs, XI(0),
                                                  XS(1), XI(1), XS(3), XI(3),
                                                  hxs, XI(0), row_ptr, pcv, 0, 1, 0);
        spmm_k<<<dim3(16896, 1), 256, 0, stream>>>(XS(1), XI(1), XS(3), XI(3),
                                                   XS(2), XI(2), XS(4), XI(4),
                                                   hxs, XI(0), row_ptr, pcv, 1, 0, 1);
        // gconv1 matmul: u -> out, r*hx -> x0 state part (m0 staged from hx)
        mm_ru_k<<<NN / NPB, 512, 0, stream>>>(xs, xi, wru_hi, wru_lo, b_ru, hx, out, XS(0), h);
        // gconv2 diffusion (x0 = [inputs, r*hx], all linear)
        spmm_k<<<dim3(8448, 2), 256, 0, stream>>>(XS(0), XI(0), XS(0), XI(0),
                                                  XS(1), XI(1), XS(3), XI(3),
                                                  XS(0), XI(0), row_ptr, pcv, 0, 0, 0);
        spmm_k<<<dim3(16896, 1), 256, 0, stream>>>(XS(1), XI(1), XS(3), XI(3),
                                                   XS(2), XI(2), XS(4), XI(4),
                                                   XS(0), XI(0), row_ptr, pcv, 1, 0, 0);
        // gconv2 matmul + tanh + final GRU combine
        mm_c_k<<<NN / NPB, 256, 0, stream>>>(xs, xi, wc_hi, wc_lo, b_c, hx, out, h);
    }
    #undef XS
    #undef XI
}